// Round 7
// baseline (648.155 us; speedup 1.0000x reference)
//
#include <hip/hip_runtime.h>
#include <hip/hip_bf16.h>

// ---------------- problem constants ----------------
#define BB 32
#define C_IN 3
#define HW 64
#define V1 1024
#define CL2_F 128
#define V2 256
#define CL3_F 256
#define FC1_IN 16384

typedef unsigned short ushortT;
typedef __attribute__((ext_vector_type(8))) short bf16x8;
typedef __attribute__((ext_vector_type(8))) unsigned short u16x8;
typedef __attribute__((ext_vector_type(4))) float f32x4;

__device__ __forceinline__ float bfu2f(unsigned short u) {
  union { unsigned int i; float f; } x; x.i = ((unsigned)u) << 16; return x.f;
}
__device__ __forceinline__ unsigned short f2bf(float v) {
  union { float f; unsigned int i; } x; x.f = v;
  unsigned r = x.i + 0x7FFFu + ((x.i >> 16) & 1u);
  return (unsigned short)(r >> 16);
}
__device__ __forceinline__ void gload16(const ushortT* g, ushortT* l) {
  __builtin_amdgcn_global_load_lds((const __attribute__((address_space(1))) void*)g,
                                   (__attribute__((address_space(3))) void*)l, 16, 0, 0);
}

// ---------------- conv1 (5x5 pad2) + ReLU + 2x2 maxpool ----------------
__global__ __launch_bounds__(256) void conv_pool_k(const float* __restrict__ x,
                                                   const float* __restrict__ w,
                                                   const float* __restrict__ bias,
                                                   float* __restrict__ P) {
  __shared__ float xs[3][7][72];
  __shared__ float wl[64][76];
  const int b = blockIdx.x >> 5, ph = blockIdx.x & 31;
  const int t = threadIdx.x;
  for (int i = t; i < 64 * 75; i += 256) wl[i / 75][i % 75] = w[i];
  for (int i = t; i < 3 * 7 * 72; i += 256) {
    int col = i % 72, rr = (i / 72) % 7, ci = i / (72 * 7);
    int ih = 2 * ph - 2 + rr, iw = col - 2;
    float v = 0.f;
    if (ih >= 0 && ih < HW && iw >= 0 && iw < HW)
      v = x[((b * 3 + ci) * HW + ih) * HW + iw];
    xs[ci][rr][col] = v;
  }
  __syncthreads();
  const int co = t >> 2, pq = t & 3;
  float acc[8][2][2];
#pragma unroll
  for (int i = 0; i < 8; ++i)
#pragma unroll
    for (int a = 0; a < 2; ++a)
#pragma unroll
      for (int d = 0; d < 2; ++d) acc[i][a][d] = 0.f;
  for (int ci = 0; ci < 3; ++ci) {
#pragma unroll
    for (int kh = 0; kh < 5; ++kh) {
      float w5[5];
#pragma unroll
      for (int j = 0; j < 5; ++j) w5[j] = wl[co][ci * 25 + kh * 5 + j];
#pragma unroll
      for (int dy = 0; dy < 2; ++dy) {
        const int r = kh + dy;
        float in[20];
#pragma unroll
        for (int q4 = 0; q4 < 5; ++q4) {
          float4 v4 = *(const float4*)&xs[ci][r][16 * pq + q4 * 4];
          in[q4 * 4 + 0] = v4.x; in[q4 * 4 + 1] = v4.y;
          in[q4 * 4 + 2] = v4.z; in[q4 * 4 + 3] = v4.w;
        }
#pragma unroll
        for (int i = 0; i < 8; ++i)
#pragma unroll
          for (int dx = 0; dx < 2; ++dx)
#pragma unroll
            for (int kw = 0; kw < 5; ++kw)
              acc[i][dy][dx] += w5[kw] * in[2 * i + dx + kw];
      }
    }
  }
  const float bv = bias[co];
#pragma unroll
  for (int i = 0; i < 8; ++i) {
    float m = fmaxf(fmaxf(acc[i][0][0], acc[i][0][1]), fmaxf(acc[i][1][0], acc[i][1][1]));
    P[((size_t)(b * 64 + co) << 10) + (ph << 5) + pq * 8 + i] = fmaxf(m + bv, 0.f);
  }
}

// ---------------- BN stats (2-stage) ----------------
__global__ __launch_bounds__(256) void bn_part_k(const float* __restrict__ P,
                                                 float* __restrict__ buf) {
  int c = blockIdx.x, s = blockIdx.y;
  float s1 = 0.f, s2 = 0.f;
  for (int i = threadIdx.x; i < 4096; i += 256) {
    int b = s * 4 + (i >> 10), p = i & 1023;
    float v = P[((size_t)(b * 64 + c) << 10) + p];
    s1 += v; s2 += v * v;
  }
#pragma unroll
  for (int o = 32; o > 0; o >>= 1) { s1 += __shfl_down(s1, o); s2 += __shfl_down(s2, o); }
  __shared__ float sh[2][4];
  int wid = threadIdx.x >> 6;
  if ((threadIdx.x & 63) == 0) { sh[0][wid] = s1; sh[1][wid] = s2; }
  __syncthreads();
  if (threadIdx.x == 0) {
    buf[c * 8 + s] = sh[0][0] + sh[0][1] + sh[0][2] + sh[0][3];
    buf[512 + c * 8 + s] = sh[1][0] + sh[1][1] + sh[1][2] + sh[1][3];
  }
}
__global__ __launch_bounds__(64) void bn_comb_k(float* __restrict__ buf) {
  int c = threadIdx.x;
  float s1 = 0.f, s2 = 0.f;
#pragma unroll
  for (int s = 0; s < 8; ++s) { s1 += buf[c * 8 + s]; s2 += buf[512 + c * 8 + s]; }
  float mean = s1 / 32768.f;
  float var = s2 / 32768.f - mean * mean;
  buf[1024 + c] = mean;
  buf[1088 + c] = rsqrtf(var + 1e-5f);
}

// ---------------- gather + BN -> PG pair + CW(slot0, [c-oct][n][8]) ----------------
__global__ __launch_bounds__(256) void build_x0_k(const float* __restrict__ P,
                                                  const float* __restrict__ buf,
                                                  const int* __restrict__ ni,
                                                  const int* __restrict__ perm,
                                                  ushortT* __restrict__ PGh,
                                                  ushortT* __restrict__ PGl,
                                                  ushortT* __restrict__ CW0) {
  __shared__ float vals[64][33];
  __shared__ int qv[32];
  const int b = blockIdx.x >> 5, vc = blockIdx.x & 31;
  const int t = threadIdx.x;
  if (t < 32) {
    int pv = perm[vc * 32 + t];
    qv[t] = ni[2 * pv] * 32 + ni[2 * pv + 1];
  }
  __syncthreads();
  {
    int c = t & 63, vh = t >> 6;
    float mean = buf[1024 + c], rstd = buf[1088 + c];
    const float* pc = &P[((size_t)(b * 64 + c)) << 10];
#pragma unroll
    for (int j = 0; j < 8; ++j) {
      int vl = vh * 8 + j;
      vals[c][vl] = (pc[qv[vl]] - mean) * rstd;
    }
  }
  __syncthreads();
  {
    int c = t & 63, vo = t >> 6;
    u16x8 h8, l8;
#pragma unroll
    for (int j = 0; j < 8; ++j) {
      float f = vals[c][vo * 8 + j];
      unsigned short h = f2bf(f);
      h8[j] = h; l8[j] = f2bf(f - bfu2f(h));
    }
    size_t base = ((size_t)(vc * 4 + vo) * 2048 + b * 64 + c) * 8;
    *(u16x8*)&PGh[base] = h8;
    *(u16x8*)&PGl[base] = l8;
  }
  {  // CW0: c-octet co, n = b*1024 + v
    int co = t & 7, vl = t >> 3;
    u16x8 h8;
#pragma unroll
    for (int j = 0; j < 8; ++j) h8[j] = f2bf(vals[co * 8 + j][vl]);
    *(u16x8*)&CW0[((size_t)co * 32768 + b * 1024 + vc * 32 + vl) * 8] = h8;
  }
}

// ---------------- L split fp32 -> bf16 hi/lo, octet-grouped LG layout ----------
// LG[((k>>3)*V + n)*8 + (k&7)]  (L symmetric)
__global__ __launch_bounds__(256) void lsplit_k(const float* __restrict__ L,
                                                ushortT* __restrict__ Lh,
                                                ushortT* __restrict__ Ll, int V) {
  int id = blockIdx.x * 256 + threadIdx.x;  // V*V/8
  int n = id & (V - 1), koct = id / V * 8;
  u16x8 h8, l8;
#pragma unroll
  for (int j = 0; j < 8; ++j) {
    float v = L[(size_t)(koct + j) * V + n];
    unsigned short h = f2bf(v);
    h8[j] = h; l8[j] = f2bf(v - bfu2f(h));
  }
  size_t o = (size_t)id * 8;
  *(u16x8*)&Lh[o] = h8;
  *(u16x8*)&Ll[o] = l8;
}

// ---------------- W prep: WA[f][kq*Cc+c] (hi/lo) ----------------
__global__ __launch_bounds__(256) void wprep_k(const float* __restrict__ W,
                                               ushortT* __restrict__ WAh,
                                               ushortT* __restrict__ WAl, int Cc, int Nf) {
  int d = blockIdx.x * 256 + threadIdx.x;
  if (d >= Nf * 16 * Cc) return;
  int c = d % Cc, kq = (d / Cc) % 16, f = d / (16 * Cc);
  float v = W[(size_t)f * (Cc * 16) + c * 16 + kq];
  unsigned short h = f2bf(v);
  WAh[d] = h; WAl[d] = f2bf(v - bfu2f(h));
}

// ---------------- Chebyshev step: A via LDS dbuf, B (L) direct global->reg ----
// block 64x64, 4 waves of 32x32. MODE 0: out = L@x ; MODE 1: out = 2*(L@x)-prev
template <int MODE, int SWZ>
__global__ __launch_bounds__(256, 2) void cheb_step_k(
    int Mld, int Kd, int mt,
    const ushortT* __restrict__ Ah, const ushortT* __restrict__ Al,
    const ushortT* __restrict__ Lbh, const ushortT* __restrict__ Lbl,
    ushortT* __restrict__ Ph, ushortT* __restrict__ Pl,
    ushortT* __restrict__ CW, int CB, int CSH) {
  __shared__ ushortT sA[2][2][8][520];  // [buf][hi/lo][k-octet][m*8] (+16B pad)
  int bx, by;
  if (SWZ) {
    const int id = blockIdx.x;
    const int xcd = id & 7, pos = id >> 3;
    bx = (xcd & 3) * 8 + (pos & 7);
    by = (xcd >> 2) * 8 + (pos >> 3);
  } else {
    bx = blockIdx.x % mt;
    by = blockIdx.x / mt;
  }
  const int m0 = bx * 64, n0 = by * 64;
  const int t = threadIdx.x, lane = t & 63;
  const int wr = (t >> 6) >> 1, wc = (t >> 6) & 1;
  const int lm = lane & 15, lq = lane >> 4;
  const size_t bCol = (size_t)(n0 + wc * 32 + lm);

  f32x4 acc[2][2];
#pragma unroll
  for (int mi = 0; mi < 2; ++mi)
#pragma unroll
    for (int nj = 0; nj < 2; ++nj) acc[mi][nj] = (f32x4){0.f, 0.f, 0.f, 0.f};

#define STAGEA(buf, k0)                                                            \
  {                                                                                \
    const int koct = (k0) >> 3;                                                    \
    _Pragma("unroll") for (int i = 0; i < 2; ++i) {                                \
      const int slot = (t + i * 256) >> 6;                                         \
      const int ln = t & 63;                                                       \
      const size_t ga = ((size_t)(koct + slot) * Mld + m0 + ln) * 8;               \
      gload16(Ah + ga, &sA[buf][0][slot][0]);                                      \
      gload16(Al + ga, &sA[buf][1][slot][0]);                                      \
    }                                                                              \
  }

  STAGEA(0, 0);
  __syncthreads();
  for (int k0 = 0; k0 < Kd; k0 += 64) {
    const int cur = (k0 >> 6) & 1;
    if (k0 + 64 < Kd) STAGEA(cur ^ 1, k0 + 64);
    // B fragments direct from global (coalesced 256B segments, L2-resident)
    bf16x8 xbh[2][2], xbl[2][2];  // [ks][nj]
#pragma unroll
    for (int ks = 0; ks < 2; ++ks)
#pragma unroll
      for (int nj = 0; nj < 2; ++nj) {
        size_t o = ((size_t)((k0 >> 3) + ks * 4 + lq) * Kd + bCol + nj * 16) * 8;
        xbh[ks][nj] = *(const bf16x8*)(Lbh + o);
        xbl[ks][nj] = *(const bf16x8*)(Lbl + o);
      }
#pragma unroll
    for (int ks = 0; ks < 2; ++ks) {
      const int so = ks * 4 + lq;
      bf16x8 xah[2], xal[2];
#pragma unroll
      for (int mi = 0; mi < 2; ++mi) {
        const int r = (wr * 32 + mi * 16 + lm) * 8;
        xah[mi] = *(const bf16x8*)&sA[cur][0][so][r];
        xal[mi] = *(const bf16x8*)&sA[cur][1][so][r];
      }
#pragma unroll
      for (int mi = 0; mi < 2; ++mi)
#pragma unroll
        for (int nj = 0; nj < 2; ++nj) {
          acc[mi][nj] = __builtin_amdgcn_mfma_f32_16x16x32_bf16(xah[mi], xbh[ks][nj], acc[mi][nj], 0, 0, 0);
          acc[mi][nj] = __builtin_amdgcn_mfma_f32_16x16x32_bf16(xal[mi], xbh[ks][nj], acc[mi][nj], 0, 0, 0);
          acc[mi][nj] = __builtin_amdgcn_mfma_f32_16x16x32_bf16(xah[mi], xbl[ks][nj], acc[mi][nj], 0, 0, 0);
        }
    }
    __syncthreads();
  }
#undef STAGEA

  // ---- epilogue via LDS transpose: all global ops vectorized u16x8 ----
  float* fs = (float*)&sA[0][0][0][0];  // [64][65] f32 tile
#pragma unroll
  for (int mi = 0; mi < 2; ++mi)
#pragma unroll
    for (int nj = 0; nj < 2; ++nj)
#pragma unroll
      for (int j = 0; j < 4; ++j) {
        int gm_l = wr * 32 + mi * 16 + lq * 4 + j;
        int gn_l = wc * 32 + nj * 16 + lm;
        fs[gm_l * 65 + gn_l] = acc[mi][nj][j];
      }
  __syncthreads();

  // Phase A: Chebyshev combine + PG pair write
  const size_t noct0 = (size_t)(n0 >> 3);
#pragma unroll
  for (int r = 0; r < 2; ++r) {
    int id = t + r * 256;
    int gm_l = id >> 3, go = id & 7;
    size_t g = ((noct0 + go) * Mld + (m0 + gm_l)) * 8;
    float nv[8];
#pragma unroll
    for (int i = 0; i < 8; ++i) nv[i] = fs[gm_l * 65 + go * 8 + i];
    if (MODE == 1) {
      u16x8 ph = *(const u16x8*)&Ph[g];
      u16x8 pl = *(const u16x8*)&Pl[g];
#pragma unroll
      for (int i = 0; i < 8; ++i) nv[i] = 2.f * nv[i] - (bfu2f(ph[i]) + bfu2f(pl[i]));
    }
    u16x8 h8, l8;
#pragma unroll
    for (int i = 0; i < 8; ++i) {
      unsigned short h = f2bf(nv[i]);
      h8[i] = h; l8[i] = f2bf(nv[i] - bfu2f(h));
    }
    *(u16x8*)&Ph[g] = h8;
    *(u16x8*)&Pl[g] = l8;
    if (MODE == 1) {
#pragma unroll
      for (int i = 0; i < 8; ++i) fs[gm_l * 65 + go * 8 + i] = nv[i];
    }
  }
  __syncthreads();

  // Phase B: CW write ([c-octet][n][8] layout, coalesced u16x8)
  const int cBase = m0 & (CB - 1);
  const int bidx = m0 >> CSH;
  const size_t NNs = (size_t)Kd << 5;
#pragma unroll
  for (int r = 0; r < 2; ++r) {
    int id = t + r * 256;
    int gn_l = id & 63, coI = id >> 6;
    u16x8 h8;
#pragma unroll
    for (int i = 0; i < 8; ++i) h8[i] = f2bf(fs[(coI * 8 + i) * 65 + gn_l]);
    size_t cbase = ((size_t)((cBase >> 3) + coI) * NNs + (size_t)bidx * Kd + n0 + gn_l) * 8;
    *(u16x8*)&CW[cbase] = h8;
  }
}

// ---------------- weight apply: K-split via grid.z, partial outputs ----------
template <int Cc, int NSPL>
__global__ __launch_bounds__(256) void wapply_k(
    int NN, int ldw,
    const ushortT* __restrict__ WAh, const ushortT* __restrict__ WAl,
    const ushortT* __restrict__ cwBase, size_t cwN,
    float* __restrict__ OUT, size_t outStride) {
  constexpr int S = Cc / 2;
  constexpr int SPZ = S / NSPL;
  const int z = blockIdx.z;
  OUT += (size_t)z * outStride;
  const int m0 = blockIdx.x * 64, n0 = blockIdx.y * 128;
  const int t = threadIdx.x, lane = t & 63, wid = t >> 6;
  const int wr = wid >> 1, wc = wid & 1;
  const int lm = lane & 15, lq = lane >> 4;

  const size_t wBase = (size_t)(m0 + wr * 32 + lm) * ldw + lq * 8;
  const int nb = n0 + wc * 64 + lm;

  f32x4 acc[2][4];
#pragma unroll
  for (int mi = 0; mi < 2; ++mi)
#pragma unroll
    for (int nj = 0; nj < 4; ++nj) acc[mi][nj] = (f32x4){0.f, 0.f, 0.f, 0.f};

#pragma unroll 8
  for (int s = z * SPZ; s < (z + 1) * SPZ; ++s) {
    const int buf = (Cc == 64) ? (s >> 1) : (s >> 2);
    const int lo = (Cc == 64) ? ((s & 1) * 4) : ((s & 3) * 4);
    const ushortT* xb = cwBase + (size_t)buf * cwN;
    bf16x8 wh[2], wl[2], xf[4];
#pragma unroll
    for (int mi = 0; mi < 2; ++mi) {
      size_t o = wBase + (size_t)s * 32 + (size_t)mi * 16 * ldw;
      wh[mi] = *(const bf16x8*)(WAh + o);
      wl[mi] = *(const bf16x8*)(WAl + o);
    }
#pragma unroll
    for (int nj = 0; nj < 4; ++nj)
      xf[nj] = *(const bf16x8*)(xb + ((size_t)(lo + lq) * NN + nb + nj * 16) * 8);
#pragma unroll
    for (int mi = 0; mi < 2; ++mi)
#pragma unroll
      for (int nj = 0; nj < 4; ++nj) {
        acc[mi][nj] = __builtin_amdgcn_mfma_f32_16x16x32_bf16(wh[mi], xf[nj], acc[mi][nj], 0, 0, 0);
        acc[mi][nj] = __builtin_amdgcn_mfma_f32_16x16x32_bf16(wl[mi], xf[nj], acc[mi][nj], 0, 0, 0);
      }
  }

#pragma unroll
  for (int mi = 0; mi < 2; ++mi)
#pragma unroll
    for (int nj = 0; nj < 4; ++nj)
#pragma unroll
      for (int j = 0; j < 4; ++j) {
        int gm = m0 + wr * 32 + mi * 16 + lq * 4 + j;
        int gn = n0 + wc * 64 + nj * 16 + lm;
        OUT[(size_t)gm * NN + gn] = acc[mi][nj][j];
      }
}

// ---------------- gc1 epilogue: sum 2 partials -> PG2 pair + CW2 slot0 --------
__global__ __launch_bounds__(256) void relu_pool1_k(const float* __restrict__ OUT1P,
                                                    const float* __restrict__ b2,
                                                    ushortT* __restrict__ PG2h,
                                                    ushortT* __restrict__ PG2l,
                                                    ushortT* __restrict__ CW0) {
  __shared__ float sval[128][9];
  const int b = blockIdx.x >> 5, vc = blockIdx.x & 31;
  const int t = threadIdx.x;
  const size_t PS = (size_t)128 * 32768;  // partial stride
  {
    int f = t & 127, h = t >> 7;
    float bb = b2[f];
    const float* src = &OUT1P[(size_t)f * 32768 + b * 1024 + vc * 32];
#pragma unroll
    for (int i = 0; i < 4; ++i) {
      int v2l = h * 4 + i;
      float4 r0 = *(const float4*)&src[v2l * 4];
      float4 r1 = *(const float4*)&src[PS + v2l * 4];
      float s0 = r0.x + r1.x, s1 = r0.y + r1.y, s2 = r0.z + r1.z, s3 = r0.w + r1.w;
      float m = fmaxf(fmaxf(s0, s1), fmaxf(s2, s3));
      sval[f][v2l] = fmaxf(m + bb, 0.f);
    }
  }
  __syncthreads();
  if (t < 128) {
    int f = t;
    u16x8 h8, l8;
#pragma unroll
    for (int j = 0; j < 8; ++j) {
      float v = sval[f][j];
      unsigned short h = f2bf(v);
      h8[j] = h; l8[j] = f2bf(v - bfu2f(h));
    }
    size_t base = ((size_t)vc * 4096 + b * 128 + f) * 8;
    *(u16x8*)&PG2h[base] = h8;
    *(u16x8*)&PG2l[base] = l8;
  } else {
    int q = t - 128;
    int co = q & 15, v2l = q >> 4;
    u16x8 h8;
#pragma unroll
    for (int j = 0; j < 8; ++j) h8[j] = f2bf(sval[co * 8 + j][v2l]);
    *(u16x8*)&CW0[((size_t)co * 8192 + b * 256 + vc * 8 + v2l) * 8] = h8;
  }
}

// ---------------- gc2 epilogue: sum 4 partials -> At[b][f*64+v3] --------------
__global__ __launch_bounds__(256) void relu_pool2_k(const float* __restrict__ OUT2P,
                                                    const float* __restrict__ b3,
                                                    float* __restrict__ At) {
  int n = blockIdx.x * 256 + threadIdx.x;  // 524288
  int v3 = n & 63, f = (n >> 6) & 255, b = n >> 14;
  const size_t PS = (size_t)256 * 8192;
  size_t base = ((size_t)f * 32 + b) * 256 + v3 * 4;
  float4 r0 = *(const float4*)&OUT2P[base];
  float4 r1 = *(const float4*)&OUT2P[PS + base];
  float4 r2 = *(const float4*)&OUT2P[2 * PS + base];
  float4 r3 = *(const float4*)&OUT2P[3 * PS + base];
  float s0 = r0.x + r1.x + r2.x + r3.x;
  float s1 = r0.y + r1.y + r2.y + r3.y;
  float s2 = r0.z + r1.z + r2.z + r3.z;
  float s3 = r0.w + r1.w + r2.w + r3.w;
  float m = fmaxf(fmaxf(s0, s1), fmaxf(s2, s3));
  At[(size_t)b * FC1_IN + f * 64 + v3] = fmaxf(m + b3[f], 0.f);
}

// ---------------- fc1: LDS-tiled split-K ----------------
__global__ __launch_bounds__(256) void fc1_part_k(const float* __restrict__ At,
                                                  const float* __restrict__ W1,
                                                  float* __restrict__ part) {
  __shared__ float sWt[64][68];
  __shared__ float sA[64][33];
  const int jt = blockIdx.x, ks = blockIdx.y;
  const int j0 = jt * 64, kb = ks * 512;
  const int t = threadIdx.x;
  const int b = t & 31, jg = t >> 5;
  float acc[8] = {};
  for (int k0 = kb; k0 < kb + 512; k0 += 64) {
    __syncthreads();
    {
      int jr = t >> 2, kq = t & 3;
      const float* wp = &W1[(size_t)(j0 + jr) * FC1_IN + k0 + kq * 16];
#pragma unroll
      for (int i = 0; i < 4; ++i) {
        float4 w4 = *(const float4*)(wp + 4 * i);
        int kk = kq * 16 + 4 * i;
        sWt[kk + 0][jr] = w4.x; sWt[kk + 1][jr] = w4.y;
        sWt[kk + 2][jr] = w4.z; sWt[kk + 3][jr] = w4.w;
      }
    }
    {
      int br = t >> 3, ko = t & 7;
      const float* ap = &At[(size_t)br * FC1_IN + k0 + ko * 8];
      float4 a0 = *(const float4*)ap;
      float4 a1 = *(const float4*)(ap + 4);
      int kk = ko * 8;
      sA[kk + 0][br] = a0.x; sA[kk + 1][br] = a0.y; sA[kk + 2][br] = a0.z; sA[kk + 3][br] = a0.w;
      sA[kk + 4][br] = a1.x; sA[kk + 5][br] = a1.y; sA[kk + 6][br] = a1.z; sA[kk + 7][br] = a1.w;
    }
    __syncthreads();
#pragma unroll 8
    for (int kk = 0; kk < 64; ++kk) {
      float a = sA[kk][b];
      float wv[8];
      *(float4*)wv = *(const float4*)&sWt[kk][jg * 8];
      *(float4*)(wv + 4) = *(const float4*)&sWt[kk][jg * 8 + 4];
#pragma unroll
      for (int i = 0; i < 8; ++i) acc[i] += wv[i] * a;
    }
  }
#pragma unroll
  for (int i = 0; i < 8; ++i)
    part[((size_t)ks * 512 + j0 + jg * 8 + i) * 32 + b] = acc[i];
}

__global__ __launch_bounds__(256) void fc1_combine_k(const float* __restrict__ part,
                                                     const float* __restrict__ b1,
                                                     float* __restrict__ h) {
  int n = blockIdx.x * 256 + threadIdx.x;  // 16384
  int b = n >> 9, j = n & 511;
  float s = b1[j];
#pragma unroll
  for (int ks = 0; ks < 32; ++ks) s += part[((size_t)ks * 512 + j) * 32 + b];
  h[n] = fmaxf(s, 0.f);
}

__global__ __launch_bounds__(64) void fc2_k(const float* __restrict__ h,
                                            const float* __restrict__ W2,
                                            const float* __restrict__ b2f,
                                            float* __restrict__ out) {
  int n = blockIdx.x * 64 + threadIdx.x;  // 320
  if (n >= 320) return;
  int b = n / 10, o = n % 10;
  float s = b2f[o];
  const float* hp = h + b * 512;
  const float* wp = W2 + o * 512;
  for (int j = 0; j < 512; ++j) s += hp[j] * wp[j];
  out[n] = s;
}

// ---------------- launch ----------------
extern "C" void kernel_launch(void* const* d_in, const int* in_sizes, int n_in,
                              void* d_out, int out_size, void* d_ws, size_t ws_size,
                              hipStream_t stream) {
  const float* x      = (const float*)d_in[0];
  const float* conv1w = (const float*)d_in[1];
  const float* conv1b = (const float*)d_in[2];
  const float* L1     = (const float*)d_in[3];
  const float* L2     = (const float*)d_in[4];
  const int*   ni     = (const int*)d_in[5];
  const int*   perm   = (const int*)d_in[6];
  const float* k2w    = (const float*)d_in[7];
  const float* k2b    = (const float*)d_in[8];
  const float* k3w    = (const float*)d_in[9];
  const float* k3b    = (const float*)d_in[10];
  const float* fc1w   = (const float*)d_in[11];
  const float* fc1b   = (const float*)d_in[12];
  const float* fc2w   = (const float*)d_in[13];
  const float* fc2b   = (const float*)d_in[14];
  float* out = (float*)d_out;

  char* ws = (char*)d_ws;
  const size_t MB = 1024 * 1024;
  // ---- phase A/B layout ----
  float*   P    = (float*)(ws + 0);                   // 8MB (dead after build_x0)
  ushortT* cw1  = (ushortT*)(ws + 8 * MB);            // 16 x 4MB = 64MB
  const size_t CW1N = 2u * 1024 * 1024;
  ushortT* pgAh = (ushortT*)(ws + 72 * MB);
  ushortT* pgAl = (ushortT*)(ws + 76 * MB);
  ushortT* pgBh = (ushortT*)(ws + 80 * MB);
  ushortT* pgBl = (ushortT*)(ws + 84 * MB);
  float*   OUT1P = (float*)(ws + 88 * MB);            // 2 x 16MB partials
  ushortT* L1h  = (ushortT*)(ws + 121 * MB);
  ushortT* L1l  = (ushortT*)(ws + 123 * MB);
  ushortT* WA1h = (ushortT*)(ws + 125 * MB);          // 256KB
  ushortT* WA1l = (ushortT*)(ws + 125 * MB + 262144);
  float*   BNB  = (float*)(ws + 126 * MB);            // ~5KB
  // ---- phase C/D layout (over dead phase A/B regions) ----
  ushortT* cw2  = (ushortT*)(ws + 0);                 // 16 x 2MB = 32MB
  const size_t CW2N = 1024u * 1024;
  ushortT* pg2Ah = (ushortT*)(ws + 32 * MB);
  ushortT* pg2Al = (ushortT*)(ws + 34 * MB);
  ushortT* pg2Bh = (ushortT*)(ws + 36 * MB);
  ushortT* pg2Bl = (ushortT*)(ws + 38 * MB);
  float*   OUT2P = (float*)(ws + 40 * MB);            // 4 x 8MB partials
  ushortT* L2h  = (ushortT*)(ws + 73 * MB);
  ushortT* L2l  = (ushortT*)(ws + 73 * MB + 131072);
  ushortT* WA2h = (ushortT*)(ws + 74 * MB);           // 1MB
  ushortT* WA2l = (ushortT*)(ws + 75 * MB);
  float*   At   = (float*)(ws + 76 * MB);             // 2MB
  float*   PART = (float*)(ws + 78 * MB);             // 2MB
  float*   H    = (float*)(ws + 80 * MB);             // 64KB

  // ---- phase A ----
  conv_pool_k<<<1024, 256, 0, stream>>>(x, conv1w, conv1b, P);
  bn_part_k<<<dim3(64, 8), 256, 0, stream>>>(P, BNB);
  bn_comb_k<<<1, 64, 0, stream>>>(BNB);
  lsplit_k<<<512, 256, 0, stream>>>(L1, L1h, L1l, 1024);
  wprep_k<<<512, 256, 0, stream>>>(k2w, WA1h, WA1l, 64, 128);
  build_x0_k<<<1024, 256, 0, stream>>>(P, BNB, ni, perm, pgAh, pgAl, cw1 + 0 * CW1N);

  // ---- phase B: gc1 chain + K-split weight-apply ----
  cheb_step_k<0, 1><<<512, 256, 0, stream>>>(2048, 1024, 32, pgAh, pgAl, L1h, L1l,
                                             pgBh, pgBl, cw1 + 1 * CW1N, 64, 6);
  for (int k = 2; k < 16; ++k) {
    ushortT *ah, *al, *oh, *ol;
    if (k & 1) { ah = pgAh; al = pgAl; oh = pgBh; ol = pgBl; }
    else       { ah = pgBh; al = pgBl; oh = pgAh; ol = pgAl; }
    cheb_step_k<1, 1><<<512, 256, 0, stream>>>(2048, 1024, 32, ah, al, L1h, L1l,
                                               oh, ol, cw1 + (size_t)k * CW1N, 64, 6);
  }
  wapply_k<64, 2><<<dim3(2, 256, 2), 256, 0, stream>>>(32768, 1024, WA1h, WA1l,
                                                       cw1, CW1N, OUT1P, (size_t)128 * 32768);

  // ---- phase C: gc2 ----
  relu_pool1_k<<<1024, 256, 0, stream>>>(OUT1P, k2b, pg2Ah, pg2Al, cw2 + 0 * CW2N);
  lsplit_k<<<32, 256, 0, stream>>>(L2, L2h, L2l, 256);
  wprep_k<<<2048, 256, 0, stream>>>(k3w, WA2h, WA2l, 128, 256);

  cheb_step_k<0, 0><<<256, 256, 0, stream>>>(4096, 256, 64, pg2Ah, pg2Al, L2h, L2l,
                                             pg2Bh, pg2Bl, cw2 + 1 * CW2N, 128, 7);
  for (int k = 2; k < 16; ++k) {
    ushortT *ah, *al, *oh, *ol;
    if (k & 1) { ah = pg2Ah; al = pg2Al; oh = pg2Bh; ol = pg2Bl; }
    else       { ah = pg2Bh; al = pg2Bl; oh = pg2Ah; ol = pg2Al; }
    cheb_step_k<1, 0><<<256, 256, 0, stream>>>(4096, 256, 64, ah, al, L2h, L2l,
                                               oh, ol, cw2 + (size_t)k * CW2N, 128, 7);
  }
  wapply_k<128, 4><<<dim3(4, 64, 4), 256, 0, stream>>>(8192, 2048, WA2h, WA2l,
                                                       cw2, CW2N, OUT2P, (size_t)256 * 8192);

  // ---- phase D: fc ----
  relu_pool2_k<<<2048, 256, 0, stream>>>(OUT2P, k3b, At);
  fc1_part_k<<<dim3(8, 32), 256, 0, stream>>>(At, fc1w, PART);
  fc1_combine_k<<<64, 256, 0, stream>>>(PART, fc1b, H);
  fc2_k<<<5, 64, 0, stream>>>(H, fc2w, fc2b, out);
}

// Round 8
// 577.243 us; speedup vs baseline: 1.1228x; 1.1228x over previous
//
#include <hip/hip_runtime.h>
#include <hip/hip_bf16.h>

// ---------------- problem constants ----------------
#define BB 32
#define C_IN 3
#define HW 64
#define V1 1024
#define CL2_F 128
#define V2 256
#define CL3_F 256
#define FC1_IN 16384

typedef unsigned short ushortT;
typedef __attribute__((ext_vector_type(8))) short bf16x8;
typedef __attribute__((ext_vector_type(8))) unsigned short u16x8;
typedef __attribute__((ext_vector_type(4))) float f32x4;

__device__ __forceinline__ float bfu2f(unsigned short u) {
  union { unsigned int i; float f; } x; x.i = ((unsigned)u) << 16; return x.f;
}
__device__ __forceinline__ unsigned short f2bf(float v) {
  union { float f; unsigned int i; } x; x.f = v;
  unsigned r = x.i + 0x7FFFu + ((x.i >> 16) & 1u);
  return (unsigned short)(r >> 16);
}
__device__ __forceinline__ void gload16(const ushortT* g, ushortT* l) {
  __builtin_amdgcn_global_load_lds((const __attribute__((address_space(1))) void*)g,
                                   (__attribute__((address_space(3))) void*)l, 16, 0, 0);
}

// ---------------- conv1 (5x5 pad2) + ReLU + 2x2 maxpool ----------------
__global__ __launch_bounds__(256) void conv_pool_k(const float* __restrict__ x,
                                                   const float* __restrict__ w,
                                                   const float* __restrict__ bias,
                                                   float* __restrict__ P) {
  __shared__ float xs[3][7][72];
  __shared__ float wl[64][76];
  const int b = blockIdx.x >> 5, ph = blockIdx.x & 31;
  const int t = threadIdx.x;
  for (int i = t; i < 64 * 75; i += 256) wl[i / 75][i % 75] = w[i];
  for (int i = t; i < 3 * 7 * 72; i += 256) {
    int col = i % 72, rr = (i / 72) % 7, ci = i / (72 * 7);
    int ih = 2 * ph - 2 + rr, iw = col - 2;
    float v = 0.f;
    if (ih >= 0 && ih < HW && iw >= 0 && iw < HW)
      v = x[((b * 3 + ci) * HW + ih) * HW + iw];
    xs[ci][rr][col] = v;
  }
  __syncthreads();
  const int co = t >> 2, pq = t & 3;
  float acc[8][2][2];
#pragma unroll
  for (int i = 0; i < 8; ++i)
#pragma unroll
    for (int a = 0; a < 2; ++a)
#pragma unroll
      for (int d = 0; d < 2; ++d) acc[i][a][d] = 0.f;
  for (int ci = 0; ci < 3; ++ci) {
#pragma unroll
    for (int kh = 0; kh < 5; ++kh) {
      float w5[5];
#pragma unroll
      for (int j = 0; j < 5; ++j) w5[j] = wl[co][ci * 25 + kh * 5 + j];
#pragma unroll
      for (int dy = 0; dy < 2; ++dy) {
        const int r = kh + dy;
        float in[20];
#pragma unroll
        for (int q4 = 0; q4 < 5; ++q4) {
          float4 v4 = *(const float4*)&xs[ci][r][16 * pq + q4 * 4];
          in[q4 * 4 + 0] = v4.x; in[q4 * 4 + 1] = v4.y;
          in[q4 * 4 + 2] = v4.z; in[q4 * 4 + 3] = v4.w;
        }
#pragma unroll
        for (int i = 0; i < 8; ++i)
#pragma unroll
          for (int dx = 0; dx < 2; ++dx)
#pragma unroll
            for (int kw = 0; kw < 5; ++kw)
              acc[i][dy][dx] += w5[kw] * in[2 * i + dx + kw];
      }
    }
  }
  const float bv = bias[co];
#pragma unroll
  for (int i = 0; i < 8; ++i) {
    float m = fmaxf(fmaxf(acc[i][0][0], acc[i][0][1]), fmaxf(acc[i][1][0], acc[i][1][1]));
    P[((size_t)(b * 64 + co) << 10) + (ph << 5) + pq * 8 + i] = fmaxf(m + bv, 0.f);
  }
}

// ---------------- BN stats (2-stage) ----------------
__global__ __launch_bounds__(256) void bn_part_k(const float* __restrict__ P,
                                                 float* __restrict__ buf) {
  int c = blockIdx.x, s = blockIdx.y;
  float s1 = 0.f, s2 = 0.f;
  for (int i = threadIdx.x; i < 4096; i += 256) {
    int b = s * 4 + (i >> 10), p = i & 1023;
    float v = P[((size_t)(b * 64 + c) << 10) + p];
    s1 += v; s2 += v * v;
  }
#pragma unroll
  for (int o = 32; o > 0; o >>= 1) { s1 += __shfl_down(s1, o); s2 += __shfl_down(s2, o); }
  __shared__ float sh[2][4];
  int wid = threadIdx.x >> 6;
  if ((threadIdx.x & 63) == 0) { sh[0][wid] = s1; sh[1][wid] = s2; }
  __syncthreads();
  if (threadIdx.x == 0) {
    buf[c * 8 + s] = sh[0][0] + sh[0][1] + sh[0][2] + sh[0][3];
    buf[512 + c * 8 + s] = sh[1][0] + sh[1][1] + sh[1][2] + sh[1][3];
  }
}
__global__ __launch_bounds__(64) void bn_comb_k(float* __restrict__ buf) {
  int c = threadIdx.x;
  float s1 = 0.f, s2 = 0.f;
#pragma unroll
  for (int s = 0; s < 8; ++s) { s1 += buf[c * 8 + s]; s2 += buf[512 + c * 8 + s]; }
  float mean = s1 / 32768.f;
  float var = s2 / 32768.f - mean * mean;
  buf[1024 + c] = mean;
  buf[1088 + c] = rsqrtf(var + 1e-5f);
}

// ---------------- gather + BN -> PG pair + CW(slot0, [c-oct][n][8]) ----------------
__global__ __launch_bounds__(256) void build_x0_k(const float* __restrict__ P,
                                                  const float* __restrict__ buf,
                                                  const int* __restrict__ ni,
                                                  const int* __restrict__ perm,
                                                  ushortT* __restrict__ PGh,
                                                  ushortT* __restrict__ PGl,
                                                  ushortT* __restrict__ CW0) {
  __shared__ float vals[64][33];
  __shared__ int qv[32];
  const int b = blockIdx.x >> 5, vc = blockIdx.x & 31;
  const int t = threadIdx.x;
  if (t < 32) {
    int pv = perm[vc * 32 + t];
    qv[t] = ni[2 * pv] * 32 + ni[2 * pv + 1];
  }
  __syncthreads();
  {
    int c = t & 63, vh = t >> 6;
    float mean = buf[1024 + c], rstd = buf[1088 + c];
    const float* pc = &P[((size_t)(b * 64 + c)) << 10];
#pragma unroll
    for (int j = 0; j < 8; ++j) {
      int vl = vh * 8 + j;
      vals[c][vl] = (pc[qv[vl]] - mean) * rstd;
    }
  }
  __syncthreads();
  {
    int c = t & 63, vo = t >> 6;
    u16x8 h8, l8;
#pragma unroll
    for (int j = 0; j < 8; ++j) {
      float f = vals[c][vo * 8 + j];
      unsigned short h = f2bf(f);
      h8[j] = h; l8[j] = f2bf(f - bfu2f(h));
    }
    size_t base = ((size_t)(vc * 4 + vo) * 2048 + b * 64 + c) * 8;
    *(u16x8*)&PGh[base] = h8;
    *(u16x8*)&PGl[base] = l8;
  }
  {
    int co = t & 7, vl = t >> 3;
    u16x8 h8;
#pragma unroll
    for (int j = 0; j < 8; ++j) h8[j] = f2bf(vals[co * 8 + j][vl]);
    *(u16x8*)&CW0[((size_t)co * 32768 + b * 1024 + vc * 32 + vl) * 8] = h8;
  }
}

// ---------------- L split fp32 -> bf16 hi/lo, octet-grouped LG layout ----------
__global__ __launch_bounds__(256) void lsplit_k(const float* __restrict__ L,
                                                ushortT* __restrict__ Lh,
                                                ushortT* __restrict__ Ll, int V) {
  int id = blockIdx.x * 256 + threadIdx.x;
  int n = id & (V - 1), koct = id / V * 8;
  u16x8 h8, l8;
#pragma unroll
  for (int j = 0; j < 8; ++j) {
    float v = L[(size_t)(koct + j) * V + n];
    unsigned short h = f2bf(v);
    h8[j] = h; l8[j] = f2bf(v - bfu2f(h));
  }
  size_t o = (size_t)id * 8;
  *(u16x8*)&Lh[o] = h8;
  *(u16x8*)&Ll[o] = l8;
}

// ---------------- W prep: WA[f][kq*Cc+c] (hi/lo) ----------------
__global__ __launch_bounds__(256) void wprep_k(const float* __restrict__ W,
                                               ushortT* __restrict__ WAh,
                                               ushortT* __restrict__ WAl, int Cc, int Nf) {
  int d = blockIdx.x * 256 + threadIdx.x;
  if (d >= Nf * 16 * Cc) return;
  int c = d % Cc, kq = (d / Cc) % 16, f = d / (16 * Cc);
  float v = W[(size_t)f * (Cc * 16) + c * 16 + kq];
  unsigned short h = f2bf(v);
  WAh[d] = h; WAl[d] = f2bf(v - bfu2f(h));
}

// ---------------- Chebyshev step: A via LDS dbuf, B reg-double-buffered ----
// block 64x64, 4 waves of 32x32. MODE 0: out = L@x ; MODE 1: out = 2*(L@x)-prev
template <int MODE, int SWZ, int KD>
__global__ __launch_bounds__(256) void cheb_step_k(
    int Mld, int mt,
    const ushortT* __restrict__ Ah, const ushortT* __restrict__ Al,
    const ushortT* __restrict__ Lbh, const ushortT* __restrict__ Lbl,
    ushortT* __restrict__ Ph, ushortT* __restrict__ Pl,
    ushortT* __restrict__ CW, int CB, int CSH) {
  __shared__ ushortT sA[2][2][8][520];  // [buf][hi/lo][k-octet][m*8] (+16B pad)
  int bx, by;
  if (SWZ) {
    const int id = blockIdx.x;
    const int xcd = id & 7, pos = id >> 3;
    bx = (xcd & 3) * 8 + (pos & 7);
    by = (xcd >> 2) * 8 + (pos >> 3);
  } else {
    bx = blockIdx.x % mt;
    by = blockIdx.x / mt;
  }
  const int m0 = bx * 64, n0 = by * 64;
  const int t = threadIdx.x, lane = t & 63;
  const int wr = (t >> 6) >> 1, wc = (t >> 6) & 1;
  const int lm = lane & 15, lq = lane >> 4;
  const size_t bCol = (size_t)(n0 + wc * 32 + lm);

  f32x4 acc[2][2];
#pragma unroll
  for (int mi = 0; mi < 2; ++mi)
#pragma unroll
    for (int nj = 0; nj < 2; ++nj) acc[mi][nj] = (f32x4){0.f, 0.f, 0.f, 0.f};

  bf16x8 B0h[2][2], B0l[2][2], B1h[2][2], B1l[2][2];

#define STAGEA(buf, k0)                                                            \
  {                                                                                \
    const int koct = (k0) >> 3;                                                    \
    _Pragma("unroll") for (int i = 0; i < 2; ++i) {                                \
      const int slot = (t + i * 256) >> 6;                                         \
      const int ln = t & 63;                                                       \
      const size_t ga = ((size_t)(koct + slot) * Mld + m0 + ln) * 8;               \
      gload16(Ah + ga, &sA[buf][0][slot][0]);                                      \
      gload16(Al + ga, &sA[buf][1][slot][0]);                                      \
    }                                                                              \
  }

#define LOADB(Bh_, Bl_, k0)                                                        \
  {                                                                                \
    _Pragma("unroll") for (int ks = 0; ks < 2; ++ks)                               \
        _Pragma("unroll") for (int nj = 0; nj < 2; ++nj) {                         \
      size_t o = ((size_t)(((k0) >> 3) + ks * 4 + lq) * KD + bCol + nj * 16) * 8;  \
      Bh_[ks][nj] = *(const bf16x8*)(Lbh + o);                                     \
      Bl_[ks][nj] = *(const bf16x8*)(Lbl + o);                                     \
    }                                                                              \
  }

#define DOMFMA(Bh_, Bl_, cur)                                                      \
  {                                                                                \
    _Pragma("unroll") for (int ks = 0; ks < 2; ++ks) {                             \
      const int so = ks * 4 + lq;                                                  \
      bf16x8 xah[2], xal[2];                                                       \
      _Pragma("unroll") for (int mi = 0; mi < 2; ++mi) {                           \
        const int r = (wr * 32 + mi * 16 + lm) * 8;                                \
        xah[mi] = *(const bf16x8*)&sA[cur][0][so][r];                              \
        xal[mi] = *(const bf16x8*)&sA[cur][1][so][r];                              \
      }                                                                            \
      _Pragma("unroll") for (int mi = 0; mi < 2; ++mi)                             \
          _Pragma("unroll") for (int nj = 0; nj < 2; ++nj) {                       \
        acc[mi][nj] = __builtin_amdgcn_mfma_f32_16x16x32_bf16(xah[mi], Bh_[ks][nj],\
                                                              acc[mi][nj], 0, 0, 0);\
        acc[mi][nj] = __builtin_amdgcn_mfma_f32_16x16x32_bf16(xal[mi], Bh_[ks][nj],\
                                                              acc[mi][nj], 0, 0, 0);\
        acc[mi][nj] = __builtin_amdgcn_mfma_f32_16x16x32_bf16(xah[mi], Bl_[ks][nj],\
                                                              acc[mi][nj], 0, 0, 0);\
      }                                                                            \
    }                                                                              \
  }

  STAGEA(0, 0);
  LOADB(B0h, B0l, 0);
  __syncthreads();
#pragma unroll
  for (int k0 = 0; k0 < KD; k0 += 128) {
    // half 1: consume buf0/B0, prefetch buf1/B1 for k0+64 (always valid: KD%128==0)
    STAGEA(1, k0 + 64);
    LOADB(B1h, B1l, k0 + 64);
    DOMFMA(B0h, B0l, 0);
    __syncthreads();
    // half 2: consume buf1/B1, prefetch buf0/B0 for k0+128
    if (k0 + 128 < KD) {
      STAGEA(0, k0 + 128);
      LOADB(B0h, B0l, k0 + 128);
    }
    DOMFMA(B1h, B1l, 1);
    __syncthreads();
  }
#undef STAGEA
#undef LOADB
#undef DOMFMA

  // ---- epilogue via LDS transpose: all global ops vectorized u16x8 ----
  float* fs = (float*)&sA[0][0][0][0];  // [64][65] f32 tile
#pragma unroll
  for (int mi = 0; mi < 2; ++mi)
#pragma unroll
    for (int nj = 0; nj < 2; ++nj)
#pragma unroll
      for (int j = 0; j < 4; ++j) {
        int gm_l = wr * 32 + mi * 16 + lq * 4 + j;
        int gn_l = wc * 32 + nj * 16 + lm;
        fs[gm_l * 65 + gn_l] = acc[mi][nj][j];
      }
  __syncthreads();

  // Phase A: Chebyshev combine + PG pair write
  const size_t noct0 = (size_t)(n0 >> 3);
#pragma unroll
  for (int r = 0; r < 2; ++r) {
    int id = t + r * 256;
    int gm_l = id >> 3, go = id & 7;
    size_t g = ((noct0 + go) * Mld + (m0 + gm_l)) * 8;
    float nv[8];
#pragma unroll
    for (int i = 0; i < 8; ++i) nv[i] = fs[gm_l * 65 + go * 8 + i];
    if (MODE == 1) {
      u16x8 ph = *(const u16x8*)&Ph[g];
      u16x8 pl = *(const u16x8*)&Pl[g];
#pragma unroll
      for (int i = 0; i < 8; ++i) nv[i] = 2.f * nv[i] - (bfu2f(ph[i]) + bfu2f(pl[i]));
    }
    u16x8 h8, l8;
#pragma unroll
    for (int i = 0; i < 8; ++i) {
      unsigned short h = f2bf(nv[i]);
      h8[i] = h; l8[i] = f2bf(nv[i] - bfu2f(h));
    }
    *(u16x8*)&Ph[g] = h8;
    *(u16x8*)&Pl[g] = l8;
    if (MODE == 1) {
#pragma unroll
      for (int i = 0; i < 8; ++i) fs[gm_l * 65 + go * 8 + i] = nv[i];
    }
  }
  __syncthreads();

  // Phase B: CW write ([c-octet][n][8] layout, coalesced u16x8)
  const int cBase = m0 & (CB - 1);
  const int bidx = m0 >> CSH;
  const size_t NNs = (size_t)KD << 5;
#pragma unroll
  for (int r = 0; r < 2; ++r) {
    int id = t + r * 256;
    int gn_l = id & 63, coI = id >> 6;
    u16x8 h8;
#pragma unroll
    for (int i = 0; i < 8; ++i) h8[i] = f2bf(fs[(coI * 8 + i) * 65 + gn_l]);
    size_t cbase = ((size_t)((cBase >> 3) + coI) * NNs + (size_t)bidx * KD + n0 + gn_l) * 8;
    *(u16x8*)&CW[cbase] = h8;
  }
}

// ---------------- weight apply: K-split grid.z, 1-deep reg prefetch ----------
template <int Cc, int NSPL>
__global__ __launch_bounds__(256) void wapply_k(
    int NN, int ldw,
    const ushortT* __restrict__ WAh, const ushortT* __restrict__ WAl,
    const ushortT* __restrict__ cwBase, size_t cwN,
    float* __restrict__ OUT, size_t outStride) {
  constexpr int S = Cc / 2;
  constexpr int SPZ = S / NSPL;  // 16 for both configs
  const int z = blockIdx.z;
  OUT += (size_t)z * outStride;
  const int m0 = blockIdx.x * 64, n0 = blockIdx.y * 128;
  const int t = threadIdx.x, lane = t & 63, wid = t >> 6;
  const int wr = wid >> 1, wc = wid & 1;
  const int lm = lane & 15, lq = lane >> 4;

  const size_t wBase = (size_t)(m0 + wr * 32 + lm) * ldw + lq * 8;
  const int nb = n0 + wc * 64 + lm;
  const int s0 = z * SPZ;

  f32x4 acc[2][4];
#pragma unroll
  for (int mi = 0; mi < 2; ++mi)
#pragma unroll
    for (int nj = 0; nj < 4; ++nj) acc[mi][nj] = (f32x4){0.f, 0.f, 0.f, 0.f};

  bf16x8 wh[2][2], wl[2][2], xf[2][4];

#define LOADWX(b, s)                                                               \
  {                                                                                \
    const int buf_ = (Cc == 64) ? ((s) >> 1) : ((s) >> 2);                         \
    const int lo_ = (Cc == 64) ? (((s) & 1) * 4) : (((s) & 3) * 4);                \
    const ushortT* xb_ = cwBase + (size_t)buf_ * cwN;                              \
    _Pragma("unroll") for (int mi = 0; mi < 2; ++mi) {                             \
      size_t o = wBase + (size_t)(s)*32 + (size_t)mi * 16 * ldw;                   \
      wh[b][mi] = *(const bf16x8*)(WAh + o);                                       \
      wl[b][mi] = *(const bf16x8*)(WAl + o);                                       \
    }                                                                              \
    _Pragma("unroll") for (int nj = 0; nj < 4; ++nj)                               \
        xf[b][nj] = *(const bf16x8*)(xb_ + ((size_t)(lo_ + lq) * NN + nb + nj * 16) * 8); \
  }

  LOADWX(0, s0);
#pragma unroll
  for (int i = 0; i < SPZ; ++i) {
    if (i + 1 < SPZ) LOADWX((i + 1) & 1, s0 + i + 1);
    const int c_ = i & 1;
#pragma unroll
    for (int mi = 0; mi < 2; ++mi)
#pragma unroll
      for (int nj = 0; nj < 4; ++nj) {
        acc[mi][nj] = __builtin_amdgcn_mfma_f32_16x16x32_bf16(wh[c_][mi], xf[c_][nj], acc[mi][nj], 0, 0, 0);
        acc[mi][nj] = __builtin_amdgcn_mfma_f32_16x16x32_bf16(wl[c_][mi], xf[c_][nj], acc[mi][nj], 0, 0, 0);
      }
  }
#undef LOADWX

#pragma unroll
  for (int mi = 0; mi < 2; ++mi)
#pragma unroll
    for (int nj = 0; nj < 4; ++nj)
#pragma unroll
      for (int j = 0; j < 4; ++j) {
        int gm = m0 + wr * 32 + mi * 16 + lq * 4 + j;
        int gn = n0 + wc * 64 + nj * 16 + lm;
        OUT[(size_t)gm * NN + gn] = acc[mi][nj][j];
      }
}

// ---------------- gc1 epilogue: sum 2 partials -> PG2 pair + CW2 slot0 --------
__global__ __launch_bounds__(256) void relu_pool1_k(const float* __restrict__ OUT1P,
                                                    const float* __restrict__ b2,
                                                    ushortT* __restrict__ PG2h,
                                                    ushortT* __restrict__ PG2l,
                                                    ushortT* __restrict__ CW0) {
  __shared__ float sval[128][9];
  const int b = blockIdx.x >> 5, vc = blockIdx.x & 31;
  const int t = threadIdx.x;
  const size_t PS = (size_t)128 * 32768;
  {
    int f = t & 127, h = t >> 7;
    float bb = b2[f];
    const float* src = &OUT1P[(size_t)f * 32768 + b * 1024 + vc * 32];
#pragma unroll
    for (int i = 0; i < 4; ++i) {
      int v2l = h * 4 + i;
      float4 r0 = *(const float4*)&src[v2l * 4];
      float4 r1 = *(const float4*)&src[PS + v2l * 4];
      float s0 = r0.x + r1.x, s1 = r0.y + r1.y, s2 = r0.z + r1.z, s3 = r0.w + r1.w;
      float m = fmaxf(fmaxf(s0, s1), fmaxf(s2, s3));
      sval[f][v2l] = fmaxf(m + bb, 0.f);
    }
  }
  __syncthreads();
  if (t < 128) {
    int f = t;
    u16x8 h8, l8;
#pragma unroll
    for (int j = 0; j < 8; ++j) {
      float v = sval[f][j];
      unsigned short h = f2bf(v);
      h8[j] = h; l8[j] = f2bf(v - bfu2f(h));
    }
    size_t base = ((size_t)vc * 4096 + b * 128 + f) * 8;
    *(u16x8*)&PG2h[base] = h8;
    *(u16x8*)&PG2l[base] = l8;
  } else {
    int q = t - 128;
    int co = q & 15, v2l = q >> 4;
    u16x8 h8;
#pragma unroll
    for (int j = 0; j < 8; ++j) h8[j] = f2bf(sval[co * 8 + j][v2l]);
    *(u16x8*)&CW0[((size_t)co * 8192 + b * 256 + vc * 8 + v2l) * 8] = h8;
  }
}

// ---------------- gc2 epilogue: sum 4 partials -> At[b][f*64+v3] --------------
__global__ __launch_bounds__(256) void relu_pool2_k(const float* __restrict__ OUT2P,
                                                    const float* __restrict__ b3,
                                                    float* __restrict__ At) {
  int n = blockIdx.x * 256 + threadIdx.x;  // 524288
  int v3 = n & 63, f = (n >> 6) & 255, b = n >> 14;
  const size_t PS = (size_t)256 * 8192;
  size_t base = ((size_t)f * 32 + b) * 256 + v3 * 4;
  float4 r0 = *(const float4*)&OUT2P[base];
  float4 r1 = *(const float4*)&OUT2P[PS + base];
  float4 r2 = *(const float4*)&OUT2P[2 * PS + base];
  float4 r3 = *(const float4*)&OUT2P[3 * PS + base];
  float s0 = r0.x + r1.x + r2.x + r3.x;
  float s1 = r0.y + r1.y + r2.y + r3.y;
  float s2 = r0.z + r1.z + r2.z + r3.z;
  float s3 = r0.w + r1.w + r2.w + r3.w;
  float m = fmaxf(fmaxf(s0, s1), fmaxf(s2, s3));
  At[(size_t)b * FC1_IN + f * 64 + v3] = fmaxf(m + b3[f], 0.f);
}

// ---------------- fc1: LDS-tiled split-K ----------------
__global__ __launch_bounds__(256) void fc1_part_k(const float* __restrict__ At,
                                                  const float* __restrict__ W1,
                                                  float* __restrict__ part) {
  __shared__ float sWt[64][68];
  __shared__ float sA[64][33];
  const int jt = blockIdx.x, ks = blockIdx.y;
  const int j0 = jt * 64, kb = ks * 512;
  const int t = threadIdx.x;
  const int b = t & 31, jg = t >> 5;
  float acc[8] = {};
  for (int k0 = kb; k0 < kb + 512; k0 += 64) {
    __syncthreads();
    {
      int jr = t >> 2, kq = t & 3;
      const float* wp = &W1[(size_t)(j0 + jr) * FC1_IN + k0 + kq * 16];
#pragma unroll
      for (int i = 0; i < 4; ++i) {
        float4 w4 = *(const float4*)(wp + 4 * i);
        int kk = kq * 16 + 4 * i;
        sWt[kk + 0][jr] = w4.x; sWt[kk + 1][jr] = w4.y;
        sWt[kk + 2][jr] = w4.z; sWt[kk + 3][jr] = w4.w;
      }
    }
    {
      int br = t >> 3, ko = t & 7;
      const float* ap = &At[(size_t)br * FC1_IN + k0 + ko * 8];
      float4 a0 = *(const float4*)ap;
      float4 a1 = *(const float4*)(ap + 4);
      int kk = ko * 8;
      sA[kk + 0][br] = a0.x; sA[kk + 1][br] = a0.y; sA[kk + 2][br] = a0.z; sA[kk + 3][br] = a0.w;
      sA[kk + 4][br] = a1.x; sA[kk + 5][br] = a1.y; sA[kk + 6][br] = a1.z; sA[kk + 7][br] = a1.w;
    }
    __syncthreads();
#pragma unroll 8
    for (int kk = 0; kk < 64; ++kk) {
      float a = sA[kk][b];
      float wv[8];
      *(float4*)wv = *(const float4*)&sWt[kk][jg * 8];
      *(float4*)(wv + 4) = *(const float4*)&sWt[kk][jg * 8 + 4];
#pragma unroll
      for (int i = 0; i < 8; ++i) acc[i] += wv[i] * a;
    }
  }
#pragma unroll
  for (int i = 0; i < 8; ++i)
    part[((size_t)ks * 512 + j0 + jg * 8 + i) * 32 + b] = acc[i];
}

__global__ __launch_bounds__(256) void fc1_combine_k(const float* __restrict__ part,
                                                     const float* __restrict__ b1,
                                                     float* __restrict__ h) {
  int n = blockIdx.x * 256 + threadIdx.x;  // 16384
  int b = n >> 9, j = n & 511;
  float s = b1[j];
#pragma unroll
  for (int ks = 0; ks < 32; ++ks) s += part[((size_t)ks * 512 + j) * 32 + b];
  h[n] = fmaxf(s, 0.f);
}

__global__ __launch_bounds__(64) void fc2_k(const float* __restrict__ h,
                                            const float* __restrict__ W2,
                                            const float* __restrict__ b2f,
                                            float* __restrict__ out) {
  int n = blockIdx.x * 64 + threadIdx.x;  // 320
  if (n >= 320) return;
  int b = n / 10, o = n % 10;
  float s = b2f[o];
  const float* hp = h + b * 512;
  const float* wp = W2 + o * 512;
  for (int j = 0; j < 512; ++j) s += hp[j] * wp[j];
  out[n] = s;
}

// ---------------- launch ----------------
extern "C" void kernel_launch(void* const* d_in, const int* in_sizes, int n_in,
                              void* d_out, int out_size, void* d_ws, size_t ws_size,
                              hipStream_t stream) {
  const float* x      = (const float*)d_in[0];
  const float* conv1w = (const float*)d_in[1];
  const float* conv1b = (const float*)d_in[2];
  const float* L1     = (const float*)d_in[3];
  const float* L2     = (const float*)d_in[4];
  const int*   ni     = (const int*)d_in[5];
  const int*   perm   = (const int*)d_in[6];
  const float* k2w    = (const float*)d_in[7];
  const float* k2b    = (const float*)d_in[8];
  const float* k3w    = (const float*)d_in[9];
  const float* k3b    = (const float*)d_in[10];
  const float* fc1w   = (const float*)d_in[11];
  const float* fc1b   = (const float*)d_in[12];
  const float* fc2w   = (const float*)d_in[13];
  const float* fc2b   = (const float*)d_in[14];
  float* out = (float*)d_out;

  char* ws = (char*)d_ws;
  const size_t MB = 1024 * 1024;
  // ---- phase A/B layout ----
  float*   P    = (float*)(ws + 0);                   // 8MB (dead after build_x0)
  ushortT* cw1  = (ushortT*)(ws + 8 * MB);            // 16 x 4MB = 64MB
  const size_t CW1N = 2u * 1024 * 1024;
  ushortT* pgAh = (ushortT*)(ws + 72 * MB);
  ushortT* pgAl = (ushortT*)(ws + 76 * MB);
  ushortT* pgBh = (ushortT*)(ws + 80 * MB);
  ushortT* pgBl = (ushortT*)(ws + 84 * MB);
  float*   OUT1P = (float*)(ws + 88 * MB);            // 2 x 16MB partials
  ushortT* L1h  = (ushortT*)(ws + 121 * MB);
  ushortT* L1l  = (ushortT*)(ws + 123 * MB);
  ushortT* WA1h = (ushortT*)(ws + 125 * MB);          // 256KB
  ushortT* WA1l = (ushortT*)(ws + 125 * MB + 262144);
  float*   BNB  = (float*)(ws + 126 * MB);            // ~5KB
  // ---- phase C/D layout ----
  ushortT* cw2  = (ushortT*)(ws + 0);                 // 16 x 2MB = 32MB
  const size_t CW2N = 1024u * 1024;
  ushortT* pg2Ah = (ushortT*)(ws + 32 * MB);
  ushortT* pg2Al = (ushortT*)(ws + 34 * MB);
  ushortT* pg2Bh = (ushortT*)(ws + 36 * MB);
  ushortT* pg2Bl = (ushortT*)(ws + 38 * MB);
  float*   OUT2P = (float*)(ws + 40 * MB);            // 4 x 8MB partials
  ushortT* L2h  = (ushortT*)(ws + 73 * MB);
  ushortT* L2l  = (ushortT*)(ws + 73 * MB + 131072);
  ushortT* WA2h = (ushortT*)(ws + 74 * MB);           // 1MB
  ushortT* WA2l = (ushortT*)(ws + 75 * MB);
  float*   At   = (float*)(ws + 76 * MB);             // 2MB
  float*   PART = (float*)(ws + 78 * MB);             // 2MB
  float*   H    = (float*)(ws + 80 * MB);             // 64KB

  // ---- phase A ----
  conv_pool_k<<<1024, 256, 0, stream>>>(x, conv1w, conv1b, P);
  bn_part_k<<<dim3(64, 8), 256, 0, stream>>>(P, BNB);
  bn_comb_k<<<1, 64, 0, stream>>>(BNB);
  lsplit_k<<<512, 256, 0, stream>>>(L1, L1h, L1l, 1024);
  wprep_k<<<512, 256, 0, stream>>>(k2w, WA1h, WA1l, 64, 128);
  build_x0_k<<<1024, 256, 0, stream>>>(P, BNB, ni, perm, pgAh, pgAl, cw1 + 0 * CW1N);

  // ---- phase B: gc1 chain + K-split weight-apply ----
  cheb_step_k<0, 1, 1024><<<512, 256, 0, stream>>>(2048, 32, pgAh, pgAl, L1h, L1l,
                                                   pgBh, pgBl, cw1 + 1 * CW1N, 64, 6);
  for (int k = 2; k < 16; ++k) {
    ushortT *ah, *al, *oh, *ol;
    if (k & 1) { ah = pgAh; al = pgAl; oh = pgBh; ol = pgBl; }
    else       { ah = pgBh; al = pgBl; oh = pgAh; ol = pgAl; }
    cheb_step_k<1, 1, 1024><<<512, 256, 0, stream>>>(2048, 32, ah, al, L1h, L1l,
                                                     oh, ol, cw1 + (size_t)k * CW1N, 64, 6);
  }
  wapply_k<64, 2><<<dim3(2, 256, 2), 256, 0, stream>>>(32768, 1024, WA1h, WA1l,
                                                       cw1, CW1N, OUT1P, (size_t)128 * 32768);

  // ---- phase C: gc2 ----
  relu_pool1_k<<<1024, 256, 0, stream>>>(OUT1P, k2b, pg2Ah, pg2Al, cw2 + 0 * CW2N);
  lsplit_k<<<32, 256, 0, stream>>>(L2, L2h, L2l, 256);
  wprep_k<<<2048, 256, 0, stream>>>(k3w, WA2h, WA2l, 128, 256);

  cheb_step_k<0, 0, 256><<<256, 256, 0, stream>>>(4096, 64, pg2Ah, pg2Al, L2h, L2l,
                                                  pg2Bh, pg2Bl, cw2 + 1 * CW2N, 128, 7);
  for (int k = 2; k < 16; ++k) {
    ushortT *ah, *al, *oh, *ol;
    if (k & 1) { ah = pg2Ah; al = pg2Al; oh = pg2Bh; ol = pg2Bl; }
    else       { ah = pg2Bh; al = pg2Bl; oh = pg2Ah; ol = pg2Al; }
    cheb_step_k<1, 0, 256><<<256, 256, 0, stream>>>(4096, 64, ah, al, L2h, L2l,
                                                    oh, ol, cw2 + (size_t)k * CW2N, 128, 7);
  }
  wapply_k<128, 4><<<dim3(4, 64, 4), 256, 0, stream>>>(8192, 2048, WA2h, WA2l,
                                                       cw2, CW2N, OUT2P, (size_t)256 * 8192);

  // ---- phase D: fc ----
  relu_pool2_k<<<2048, 256, 0, stream>>>(OUT2P, k3b, At);
  fc1_part_k<<<dim3(8, 32), 256, 0, stream>>>(At, fc1w, PART);
  fc1_combine_k<<<64, 256, 0, stream>>>(PART, fc1b, H);
  fc2_k<<<5, 64, 0, stream>>>(H, fc2w, fc2b, out);
}

// Round 10
// 570.683 us; speedup vs baseline: 1.1358x; 1.0115x over previous
//
#include <hip/hip_runtime.h>
#include <hip/hip_bf16.h>

// ---------------- problem constants ----------------
#define BB 32
#define C_IN 3
#define HW 64
#define V1 1024
#define CL2_F 128
#define V2 256
#define CL3_F 256
#define FC1_IN 16384

typedef unsigned short ushortT;
typedef __attribute__((ext_vector_type(8))) short bf16x8;
typedef __attribute__((ext_vector_type(8))) unsigned short u16x8;
typedef __attribute__((ext_vector_type(4))) float f32x4;

__device__ __forceinline__ float bfu2f(unsigned short u) {
  union { unsigned int i; float f; } x; x.i = ((unsigned)u) << 16; return x.f;
}
__device__ __forceinline__ unsigned short f2bf(float v) {
  union { float f; unsigned int i; } x; x.f = v;
  unsigned r = x.i + 0x7FFFu + ((x.i >> 16) & 1u);
  return (unsigned short)(r >> 16);
}
__device__ __forceinline__ void gload16(const ushortT* g, ushortT* l) {
  __builtin_amdgcn_global_load_lds((const __attribute__((address_space(1))) void*)g,
                                   (__attribute__((address_space(3))) void*)l, 16, 0, 0);
}

// ---------------- conv1 (5x5 pad2) + ReLU + 2x2 maxpool ----------------
__global__ __launch_bounds__(256) void conv_pool_k(const float* __restrict__ x,
                                                   const float* __restrict__ w,
                                                   const float* __restrict__ bias,
                                                   float* __restrict__ P) {
  __shared__ float xs[3][7][72];
  __shared__ float wl[64][76];
  const int b = blockIdx.x >> 5, ph = blockIdx.x & 31;
  const int t = threadIdx.x;
  for (int i = t; i < 64 * 75; i += 256) wl[i / 75][i % 75] = w[i];
  for (int i = t; i < 3 * 7 * 72; i += 256) {
    int col = i % 72, rr = (i / 72) % 7, ci = i / (72 * 7);
    int ih = 2 * ph - 2 + rr, iw = col - 2;
    float v = 0.f;
    if (ih >= 0 && ih < HW && iw >= 0 && iw < HW)
      v = x[((b * 3 + ci) * HW + ih) * HW + iw];
    xs[ci][rr][col] = v;
  }
  __syncthreads();
  const int co = t >> 2, pq = t & 3;
  float acc[8][2][2];
#pragma unroll
  for (int i = 0; i < 8; ++i)
#pragma unroll
    for (int a = 0; a < 2; ++a)
#pragma unroll
      for (int d = 0; d < 2; ++d) acc[i][a][d] = 0.f;
  for (int ci = 0; ci < 3; ++ci) {
#pragma unroll
    for (int kh = 0; kh < 5; ++kh) {
      float w5[5];
#pragma unroll
      for (int j = 0; j < 5; ++j) w5[j] = wl[co][ci * 25 + kh * 5 + j];
#pragma unroll
      for (int dy = 0; dy < 2; ++dy) {
        const int r = kh + dy;
        float in[20];
#pragma unroll
        for (int q4 = 0; q4 < 5; ++q4) {
          float4 v4 = *(const float4*)&xs[ci][r][16 * pq + q4 * 4];
          in[q4 * 4 + 0] = v4.x; in[q4 * 4 + 1] = v4.y;
          in[q4 * 4 + 2] = v4.z; in[q4 * 4 + 3] = v4.w;
        }
#pragma unroll
        for (int i = 0; i < 8; ++i)
#pragma unroll
          for (int dx = 0; dx < 2; ++dx)
#pragma unroll
            for (int kw = 0; kw < 5; ++kw)
              acc[i][dy][dx] += w5[kw] * in[2 * i + dx + kw];
      }
    }
  }
  const float bv = bias[co];
#pragma unroll
  for (int i = 0; i < 8; ++i) {
    float m = fmaxf(fmaxf(acc[i][0][0], acc[i][0][1]), fmaxf(acc[i][1][0], acc[i][1][1]));
    P[((size_t)(b * 64 + co) << 10) + (ph << 5) + pq * 8 + i] = fmaxf(m + bv, 0.f);
  }
}

// ---------------- BN stats (2-stage) ----------------
__global__ __launch_bounds__(256) void bn_part_k(const float* __restrict__ P,
                                                 float* __restrict__ buf) {
  int c = blockIdx.x, s = blockIdx.y;
  float s1 = 0.f, s2 = 0.f;
  for (int i = threadIdx.x; i < 4096; i += 256) {
    int b = s * 4 + (i >> 10), p = i & 1023;
    float v = P[((size_t)(b * 64 + c) << 10) + p];
    s1 += v; s2 += v * v;
  }
#pragma unroll
  for (int o = 32; o > 0; o >>= 1) { s1 += __shfl_down(s1, o); s2 += __shfl_down(s2, o); }
  __shared__ float sh[2][4];
  int wid = threadIdx.x >> 6;
  if ((threadIdx.x & 63) == 0) { sh[0][wid] = s1; sh[1][wid] = s2; }
  __syncthreads();
  if (threadIdx.x == 0) {
    buf[c * 8 + s] = sh[0][0] + sh[0][1] + sh[0][2] + sh[0][3];
    buf[512 + c * 8 + s] = sh[1][0] + sh[1][1] + sh[1][2] + sh[1][3];
  }
}
__global__ __launch_bounds__(64) void bn_comb_k(float* __restrict__ buf) {
  int c = threadIdx.x;
  float s1 = 0.f, s2 = 0.f;
#pragma unroll
  for (int s = 0; s < 8; ++s) { s1 += buf[c * 8 + s]; s2 += buf[512 + c * 8 + s]; }
  float mean = s1 / 32768.f;
  float var = s2 / 32768.f - mean * mean;
  buf[1024 + c] = mean;
  buf[1088 + c] = rsqrtf(var + 1e-5f);
}

// ---------------- gather + BN -> PG pair + CW(slot0, [c-oct][n][8]) ----------------
__global__ __launch_bounds__(256) void build_x0_k(const float* __restrict__ P,
                                                  const float* __restrict__ buf,
                                                  const int* __restrict__ ni,
                                                  const int* __restrict__ perm,
                                                  ushortT* __restrict__ PGh,
                                                  ushortT* __restrict__ PGl,
                                                  ushortT* __restrict__ CW0) {
  __shared__ float vals[64][33];
  __shared__ int qv[32];
  const int b = blockIdx.x >> 5, vc = blockIdx.x & 31;
  const int t = threadIdx.x;
  if (t < 32) {
    int pv = perm[vc * 32 + t];
    qv[t] = ni[2 * pv] * 32 + ni[2 * pv + 1];
  }
  __syncthreads();
  {
    int c = t & 63, vh = t >> 6;
    float mean = buf[1024 + c], rstd = buf[1088 + c];
    const float* pc = &P[((size_t)(b * 64 + c)) << 10];
#pragma unroll
    for (int j = 0; j < 8; ++j) {
      int vl = vh * 8 + j;
      vals[c][vl] = (pc[qv[vl]] - mean) * rstd;
    }
  }
  __syncthreads();
  {
    int c = t & 63, vo = t >> 6;
    u16x8 h8, l8;
#pragma unroll
    for (int j = 0; j < 8; ++j) {
      float f = vals[c][vo * 8 + j];
      unsigned short h = f2bf(f);
      h8[j] = h; l8[j] = f2bf(f - bfu2f(h));
    }
    size_t base = ((size_t)(vc * 4 + vo) * 2048 + b * 64 + c) * 8;
    *(u16x8*)&PGh[base] = h8;
    *(u16x8*)&PGl[base] = l8;
  }
  {
    int co = t & 7, vl = t >> 3;
    u16x8 h8;
#pragma unroll
    for (int j = 0; j < 8; ++j) h8[j] = f2bf(vals[co * 8 + j][vl]);
    *(u16x8*)&CW0[((size_t)co * 32768 + b * 1024 + vc * 32 + vl) * 8] = h8;
  }
}

// ---------------- L split fp32 -> bf16 hi/lo, octet-grouped LG layout ----------
__global__ __launch_bounds__(256) void lsplit_k(const float* __restrict__ L,
                                                ushortT* __restrict__ Lh,
                                                ushortT* __restrict__ Ll, int V) {
  int id = blockIdx.x * 256 + threadIdx.x;
  int n = id & (V - 1), koct = id / V * 8;
  u16x8 h8, l8;
#pragma unroll
  for (int j = 0; j < 8; ++j) {
    float v = L[(size_t)(koct + j) * V + n];
    unsigned short h = f2bf(v);
    h8[j] = h; l8[j] = f2bf(v - bfu2f(h));
  }
  size_t o = (size_t)id * 8;
  *(u16x8*)&Lh[o] = h8;
  *(u16x8*)&Ll[o] = l8;
}

// ---------------- W prep: octet-grouped WB[koct][f][8], k = kq*Cc + c ----------
__global__ __launch_bounds__(256) void wprep_k(const float* __restrict__ W,
                                               ushortT* __restrict__ WAh,
                                               ushortT* __restrict__ WAl, int Cc, int Nf) {
  int d = blockIdx.x * 256 + threadIdx.x;
  if (d >= Nf * 16 * Cc) return;
  int j = d & 7;
  int f = (d >> 3) % Nf;
  int koct = d / (8 * Nf);
  int k = koct * 8 + j;
  int kq = k / Cc, c = k % Cc;
  float v = W[(size_t)f * (Cc * 16) + c * 16 + kq];
  unsigned short h = f2bf(v);
  WAh[d] = h; WAl[d] = f2bf(v - bfu2f(h));
}

// ---------------- Chebyshev step: 3-deep pipelined (vmcnt+lgkm drain + raw barrier)
// block 64x64, 4 waves of 32x32. MODE 0: out = L@x ; MODE 1: out = 2*(L@x)-prev
template <int MODE, int SWZ, int KD>
__global__ __launch_bounds__(256) void cheb_step_k(
    int Mld, int mt,
    const ushortT* __restrict__ Ah, const ushortT* __restrict__ Al,
    const ushortT* __restrict__ Lbh, const ushortT* __restrict__ Lbl,
    ushortT* __restrict__ Ph, ushortT* __restrict__ Pl,
    ushortT* __restrict__ CW, int CB, int CSH) {
  constexpr int NPH = KD / 64;  // phases (16 gc1, 4 gc2)
  __shared__ ushortT sA[3][2][8][520];  // 3 bufs x [hi/lo][k-octet][m*8] (+16B pad)
  int bx, by;
  if (SWZ) {
    const int id = blockIdx.x;
    const int xcd = id & 7, pos = id >> 3;
    bx = (xcd & 3) * 8 + (pos & 7);
    by = (xcd >> 2) * 8 + (pos >> 3);
  } else {
    bx = blockIdx.x % mt;
    by = blockIdx.x / mt;
  }
  const int m0 = bx * 64, n0 = by * 64;
  const int t = threadIdx.x, lane = t & 63;
  const int wr = (t >> 6) >> 1, wc = (t >> 6) & 1;
  const int lm = lane & 15, lq = lane >> 4;
  const size_t bCol = (size_t)(n0 + wc * 32 + lm);

  f32x4 acc[2][2];
#pragma unroll
  for (int mi = 0; mi < 2; ++mi)
#pragma unroll
    for (int nj = 0; nj < 2; ++nj) acc[mi][nj] = (f32x4){0.f, 0.f, 0.f, 0.f};

  bf16x8 Bh[2][2][2], Bl[2][2][2];  // [set][ks][nj]

  // 4 VMEM ops
#define STAGEA(buf, slot)                                                          \
  {                                                                                \
    const int koct = (slot) * 8;                                                   \
    _Pragma("unroll") for (int i = 0; i < 2; ++i) {                                \
      const int sl = (t + i * 256) >> 6;                                           \
      const int ln = t & 63;                                                       \
      const size_t ga = ((size_t)(koct + sl) * Mld + m0 + ln) * 8;                 \
      gload16(Ah + ga, &sA[buf][0][sl][0]);                                        \
      gload16(Al + ga, &sA[buf][1][sl][0]);                                        \
    }                                                                              \
  }

  // 8 VMEM ops
#define LOADB(set, slot)                                                           \
  {                                                                                \
    _Pragma("unroll") for (int ks = 0; ks < 2; ++ks)                               \
        _Pragma("unroll") for (int nj = 0; nj < 2; ++nj) {                         \
      size_t o = ((size_t)((slot) * 8 + ks * 4 + lq) * KD + bCol + nj * 16) * 8;   \
      Bh[set][ks][nj] = *(const bf16x8*)(Lbh + o);                                 \
      Bl[set][ks][nj] = *(const bf16x8*)(Lbl + o);                                 \
    }                                                                              \
  }

#define DOMFMA(buf, set)                                                           \
  {                                                                                \
    _Pragma("unroll") for (int ks = 0; ks < 2; ++ks) {                             \
      const int so = ks * 4 + lq;                                                  \
      bf16x8 xah[2], xal[2];                                                       \
      _Pragma("unroll") for (int mi = 0; mi < 2; ++mi) {                           \
        const int r = (wr * 32 + mi * 16 + lm) * 8;                                \
        xah[mi] = *(const bf16x8*)&sA[buf][0][so][r];                              \
        xal[mi] = *(const bf16x8*)&sA[buf][1][so][r];                              \
      }                                                                            \
      _Pragma("unroll") for (int mi = 0; mi < 2; ++mi)                             \
          _Pragma("unroll") for (int nj = 0; nj < 2; ++nj) {                       \
        acc[mi][nj] = __builtin_amdgcn_mfma_f32_16x16x32_bf16(xah[mi], Bh[set][ks][nj], \
                                                              acc[mi][nj], 0, 0, 0);\
        acc[mi][nj] = __builtin_amdgcn_mfma_f32_16x16x32_bf16(xal[mi], Bh[set][ks][nj], \
                                                              acc[mi][nj], 0, 0, 0);\
        acc[mi][nj] = __builtin_amdgcn_mfma_f32_16x16x32_bf16(xah[mi], Bl[set][ks][nj], \
                                                              acc[mi][nj], 0, 0, 0);\
      }                                                                            \
    }                                                                              \
  }

  // prologue: slots 0,1 staged; B slot 0 loaded
  STAGEA(0, 0);
  STAGEA(1, 1);
  LOADB(0, 0);
#pragma unroll
  for (int tt = 0; tt < NPH; ++tt) {
    // lgkmcnt(0): all ds_reads of the previous phase must retire BEFORE the
    // barrier, else another wave's re-stage of that buffer races them (R9 bug).
    asm volatile("s_waitcnt vmcnt(12) lgkmcnt(0)" ::: "memory");
    __builtin_amdgcn_s_barrier();
    STAGEA((tt + 2) % 3, (tt + 2) % NPH);   // dummy re-stage at tail: uniform counts
    LOADB((tt + 1) % 2, (tt + 1) % NPH);
    __builtin_amdgcn_s_setprio(1);
    DOMFMA(tt % 3, tt % 2);
    __builtin_amdgcn_s_setprio(0);
  }
  asm volatile("s_waitcnt vmcnt(0)" ::: "memory");
  __syncthreads();
#undef STAGEA
#undef LOADB
#undef DOMFMA

  // ---- epilogue via LDS transpose (fs aliases sA[0], 16.6KB) ----
  float* fs = (float*)&sA[0][0][0][0];  // [64][65] f32 tile
#pragma unroll
  for (int mi = 0; mi < 2; ++mi)
#pragma unroll
    for (int nj = 0; nj < 2; ++nj)
#pragma unroll
      for (int j = 0; j < 4; ++j) {
        int gm_l = wr * 32 + mi * 16 + lq * 4 + j;
        int gn_l = wc * 32 + nj * 16 + lm;
        fs[gm_l * 65 + gn_l] = acc[mi][nj][j];
      }
  __syncthreads();

  // Phase A: Chebyshev combine + PG pair write
  const size_t noct0 = (size_t)(n0 >> 3);
#pragma unroll
  for (int r = 0; r < 2; ++r) {
    int id = t + r * 256;
    int gm_l = id >> 3, go = id & 7;
    size_t g = ((noct0 + go) * Mld + (m0 + gm_l)) * 8;
    float nv[8];
#pragma unroll
    for (int i = 0; i < 8; ++i) nv[i] = fs[gm_l * 65 + go * 8 + i];
    if (MODE == 1) {
      u16x8 ph = *(const u16x8*)&Ph[g];
      u16x8 pl = *(const u16x8*)&Pl[g];
#pragma unroll
      for (int i = 0; i < 8; ++i) nv[i] = 2.f * nv[i] - (bfu2f(ph[i]) + bfu2f(pl[i]));
    }
    u16x8 h8, l8;
#pragma unroll
    for (int i = 0; i < 8; ++i) {
      unsigned short h = f2bf(nv[i]);
      h8[i] = h; l8[i] = f2bf(nv[i] - bfu2f(h));
    }
    *(u16x8*)&Ph[g] = h8;
    *(u16x8*)&Pl[g] = l8;
    if (MODE == 1) {
#pragma unroll
      for (int i = 0; i < 8; ++i) fs[gm_l * 65 + go * 8 + i] = nv[i];
    }
  }
  __syncthreads();

  // Phase B: CW write ([c-octet][n][8] layout, coalesced u16x8)
  const int cBase = m0 & (CB - 1);
  const int bidx = m0 >> CSH;
  const size_t NNs = (size_t)KD << 5;
#pragma unroll
  for (int r = 0; r < 2; ++r) {
    int id = t + r * 256;
    int gn_l = id & 63, coI = id >> 6;
    u16x8 h8;
#pragma unroll
    for (int i = 0; i < 8; ++i) h8[i] = f2bf(fs[(coI * 8 + i) * 65 + gn_l]);
    size_t cbase = ((size_t)((cBase >> 3) + coI) * NNs + (size_t)bidx * KD + n0 + gn_l) * 8;
    *(u16x8*)&CW[cbase] = h8;
  }
}

// ---------------- weight apply: 3-deep pipelined X via global_load_lds ----------
// W in octet-grouped layout WB[koct][Nf][8] -> coalesced W loads.
template <int Cc, int NSPL>
__global__ __launch_bounds__(256) void wapply_k(
    int NN, int Nf,
    const ushortT* __restrict__ WAh, const ushortT* __restrict__ WAl,
    const ushortT* __restrict__ cwBase, size_t cwN,
    float* __restrict__ OUT, size_t outStride) {
  constexpr int S = Cc / 2;
  constexpr int SPZ = S / NSPL;  // 16 for both configs
  constexpr int ROWU = 129 * 8;  // padded LDS row (128 cols + 1)
  __shared__ ushortT sX[3][4 * ROWU];  // 3 bufs x [4 koct][129 col][8]
  const int z = blockIdx.z;
  OUT += (size_t)z * outStride;
  const int m0 = blockIdx.x * 64, n0 = blockIdx.y * 128;
  const int t = threadIdx.x, lane = t & 63, wid = t >> 6;
  const int wr = wid >> 1, wc = wid & 1;
  const int lm = lane & 15, lq = lane >> 4;

  const int fIdx = m0 + wr * 32 + lm;  // f coordinate of W fragment rows
  const int s0 = z * SPZ;

  f32x4 acc[2][4];
#pragma unroll
  for (int mi = 0; mi < 2; ++mi)
#pragma unroll
    for (int nj = 0; nj < 4; ++nj) acc[mi][nj] = (f32x4){0.f, 0.f, 0.f, 0.f};

  bf16x8 wh[2][2], wl[2][2];  // [set][mi]

  // 2 VMEM ops: stage X slot into LDS buf (coalesced 1KB per wave)
#define STX(buf, s)                                                                \
  {                                                                                \
    const int buf_ = (Cc == 64) ? ((s) >> 1) : ((s) >> 2);                         \
    const int lo_ = (Cc == 64) ? (((s) & 1) * 4) : (((s) & 3) * 4);                \
    const ushortT* xb_ = cwBase + (size_t)buf_ * cwN;                              \
    _Pragma("unroll") for (int i = 0; i < 2; ++i) {                                \
      const int idx = t + i * 256;                                                 \
      const int octrow = idx >> 7, col = idx & 127;                                \
      const int chunk = idx >> 6;                                                  \
      const ushortT* src = xb_ + ((size_t)(lo_ + octrow) * NN + n0 + col) * 8;     \
      gload16(src, &sX[buf][octrow * ROWU + (chunk & 1) * 512]);                   \
    }                                                                              \
  }

  // 4 VMEM ops: W fragments, coalesced (lanes lm contiguous in f)
#define LDW(set, s)                                                                \
  {                                                                                \
    _Pragma("unroll") for (int mi = 0; mi < 2; ++mi) {                             \
      size_t o = ((size_t)((s)*4 + lq) * Nf + fIdx + mi * 16) * 8;                 \
      wh[set][mi] = *(const bf16x8*)(WAh + o);                                     \
      wl[set][mi] = *(const bf16x8*)(WAl + o);                                     \
    }                                                                              \
  }

#define XMFMA(buf, set)                                                            \
  {                                                                                \
    bf16x8 xf[4];                                                                  \
    _Pragma("unroll") for (int nj = 0; nj < 4; ++nj)                               \
        xf[nj] = *(const bf16x8*)&sX[buf][lq * ROWU + (wc * 64 + lm + nj * 16) * 8];\
    _Pragma("unroll") for (int mi = 0; mi < 2; ++mi)                               \
        _Pragma("unroll") for (int nj = 0; nj < 4; ++nj) {                         \
      acc[mi][nj] = __builtin_amdgcn_mfma_f32_16x16x32_bf16(wh[set][mi], xf[nj],   \
                                                            acc[mi][nj], 0, 0, 0); \
      acc[mi][nj] = __builtin_amdgcn_mfma_f32_16x16x32_bf16(wl[set][mi], xf[nj],   \
                                                            acc[mi][nj], 0, 0, 0); \
    }                                                                              \
  }

  STX(0, s0);
  STX(1, s0 + 1);
  LDW(0, s0);
#pragma unroll
  for (int tt = 0; tt < SPZ; ++tt) {
    asm volatile("s_waitcnt vmcnt(6) lgkmcnt(0)" ::: "memory");  // drain LDS reads (R9 fix)
    __builtin_amdgcn_s_barrier();
    STX((tt + 2) % 3, s0 + (tt + 2) % SPZ);
    LDW((tt + 1) % 2, s0 + (tt + 1) % SPZ);
    __builtin_amdgcn_s_setprio(1);
    XMFMA(tt % 3, tt % 2);
    __builtin_amdgcn_s_setprio(0);
  }
#undef STX
#undef LDW
#undef XMFMA

#pragma unroll
  for (int mi = 0; mi < 2; ++mi)
#pragma unroll
    for (int nj = 0; nj < 4; ++nj)
#pragma unroll
      for (int j = 0; j < 4; ++j) {
        int gm = m0 + wr * 32 + mi * 16 + lq * 4 + j;
        int gn = n0 + wc * 64 + nj * 16 + lm;
        OUT[(size_t)gm * NN + gn] = acc[mi][nj][j];
      }
}

// ---------------- gc1 epilogue: sum 2 partials -> PG2 pair + CW2 slot0 --------
__global__ __launch_bounds__(256) void relu_pool1_k(const float* __restrict__ OUT1P,
                                                    const float* __restrict__ b2,
                                                    ushortT* __restrict__ PG2h,
                                                    ushortT* __restrict__ PG2l,
                                                    ushortT* __restrict__ CW0) {
  __shared__ float sval[128][9];
  const int b = blockIdx.x >> 5, vc = blockIdx.x & 31;
  const int t = threadIdx.x;
  const size_t PS = (size_t)128 * 32768;
  {
    int f = t & 127, h = t >> 7;
    float bb = b2[f];
    const float* src = &OUT1P[(size_t)f * 32768 + b * 1024 + vc * 32];
#pragma unroll
    for (int i = 0; i < 4; ++i) {
      int v2l = h * 4 + i;
      float4 r0 = *(const float4*)&src[v2l * 4];
      float4 r1 = *(const float4*)&src[PS + v2l * 4];
      float s0 = r0.x + r1.x, s1 = r0.y + r1.y, s2 = r0.z + r1.z, s3 = r0.w + r1.w;
      float m = fmaxf(fmaxf(s0, s1), fmaxf(s2, s3));
      sval[f][v2l] = fmaxf(m + bb, 0.f);
    }
  }
  __syncthreads();
  if (t < 128) {
    int f = t;
    u16x8 h8, l8;
#pragma unroll
    for (int j = 0; j < 8; ++j) {
      float v = sval[f][j];
      unsigned short h = f2bf(v);
      h8[j] = h; l8[j] = f2bf(v - bfu2f(h));
    }
    size_t base = ((size_t)vc * 4096 + b * 128 + f) * 8;
    *(u16x8*)&PG2h[base] = h8;
    *(u16x8*)&PG2l[base] = l8;
  } else {
    int q = t - 128;
    int co = q & 15, v2l = q >> 4;
    u16x8 h8;
#pragma unroll
    for (int j = 0; j < 8; ++j) h8[j] = f2bf(sval[co * 8 + j][v2l]);
    *(u16x8*)&CW0[((size_t)co * 8192 + b * 256 + vc * 8 + v2l) * 8] = h8;
  }
}

// ---------------- gc2 epilogue: sum 4 partials -> At[b][f*64+v3] --------------
__global__ __launch_bounds__(256) void relu_pool2_k(const float* __restrict__ OUT2P,
                                                    const float* __restrict__ b3,
                                                    float* __restrict__ At) {
  int n = blockIdx.x * 256 + threadIdx.x;  // 524288
  int v3 = n & 63, f = (n >> 6) & 255, b = n >> 14;
  const size_t PS = (size_t)256 * 8192;
  size_t base = ((size_t)f * 32 + b) * 256 + v3 * 4;
  float4 r0 = *(const float4*)&OUT2P[base];
  float4 r1 = *(const float4*)&OUT2P[PS + base];
  float4 r2 = *(const float4*)&OUT2P[2 * PS + base];
  float4 r3 = *(const float4*)&OUT2P[3 * PS + base];
  float s0 = r0.x + r1.x + r2.x + r3.x;
  float s1 = r0.y + r1.y + r2.y + r3.y;
  float s2 = r0.z + r1.z + r2.z + r3.z;
  float s3 = r0.w + r1.w + r2.w + r3.w;
  float m = fmaxf(fmaxf(s0, s1), fmaxf(s2, s3));
  At[(size_t)b * FC1_IN + f * 64 + v3] = fmaxf(m + b3[f], 0.f);
}

// ---------------- fc1: LDS-tiled split-K ----------------
__global__ __launch_bounds__(256) void fc1_part_k(const float* __restrict__ At,
                                                  const float* __restrict__ W1,
                                                  float* __restrict__ part) {
  __shared__ float sWt[64][68];
  __shared__ float sA[64][33];
  const int jt = blockIdx.x, ks = blockIdx.y;
  const int j0 = jt * 64, kb = ks * 512;
  const int t = threadIdx.x;
  const int b = t & 31, jg = t >> 5;
  float acc[8] = {};
  for (int k0 = kb; k0 < kb + 512; k0 += 64) {
    __syncthreads();
    {
      int jr = t >> 2, kq = t & 3;
      const float* wp = &W1[(size_t)(j0 + jr) * FC1_IN + k0 + kq * 16];
#pragma unroll
      for (int i = 0; i < 4; ++i) {
        float4 w4 = *(const float4*)(wp + 4 * i);
        int kk = kq * 16 + 4 * i;
        sWt[kk + 0][jr] = w4.x; sWt[kk + 1][jr] = w4.y;
        sWt[kk + 2][jr] = w4.z; sWt[kk + 3][jr] = w4.w;
      }
    }
    {
      int br = t >> 3, ko = t & 7;
      const float* ap = &At[(size_t)br * FC1_IN + k0 + ko * 8];
      float4 a0 = *(const float4*)ap;
      float4 a1 = *(const float4*)(ap + 4);
      int kk = ko * 8;
      sA[kk + 0][br] = a0.x; sA[kk + 1][br] = a0.y; sA[kk + 2][br] = a0.z; sA[kk + 3][br] = a0.w;
      sA[kk + 4][br] = a1.x; sA[kk + 5][br] = a1.y; sA[kk + 6][br] = a1.z; sA[kk + 7][br] = a1.w;
    }
    __syncthreads();
#pragma unroll 8
    for (int kk = 0; kk < 64; ++kk) {
      float a = sA[kk][b];
      float wv[8];
      *(float4*)wv = *(const float4*)&sWt[kk][jg * 8];
      *(float4*)(wv + 4) = *(const float4*)&sWt[kk][jg * 8 + 4];
#pragma unroll
      for (int i = 0; i < 8; ++i) acc[i] += wv[i] * a;
    }
  }
#pragma unroll
  for (int i = 0; i < 8; ++i)
    part[((size_t)ks * 512 + j0 + jg * 8 + i) * 32 + b] = acc[i];
}

__global__ __launch_bounds__(256) void fc1_combine_k(const float* __restrict__ part,
                                                     const float* __restrict__ b1,
                                                     float* __restrict__ h) {
  int n = blockIdx.x * 256 + threadIdx.x;  // 16384
  int b = n >> 9, j = n & 511;
  float s = b1[j];
#pragma unroll
  for (int ks = 0; ks < 32; ++ks) s += part[((size_t)ks * 512 + j) * 32 + b];
  h[n] = fmaxf(s, 0.f);
}

__global__ __launch_bounds__(64) void fc2_k(const float* __restrict__ h,
                                            const float* __restrict__ W2,
                                            const float* __restrict__ b2f,
                                            float* __restrict__ out) {
  int n = blockIdx.x * 64 + threadIdx.x;  // 320
  if (n >= 320) return;
  int b = n / 10, o = n % 10;
  float s = b2f[o];
  const float* hp = h + b * 512;
  const float* wp = W2 + o * 512;
  for (int j = 0; j < 512; ++j) s += hp[j] * wp[j];
  out[n] = s;
}

// ---------------- launch ----------------
extern "C" void kernel_launch(void* const* d_in, const int* in_sizes, int n_in,
                              void* d_out, int out_size, void* d_ws, size_t ws_size,
                              hipStream_t stream) {
  const float* x      = (const float*)d_in[0];
  const float* conv1w = (const float*)d_in[1];
  const float* conv1b = (const float*)d_in[2];
  const float* L1     = (const float*)d_in[3];
  const float* L2     = (const float*)d_in[4];
  const int*   ni     = (const int*)d_in[5];
  const int*   perm   = (const int*)d_in[6];
  const float* k2w    = (const float*)d_in[7];
  const float* k2b    = (const float*)d_in[8];
  const float* k3w    = (const float*)d_in[9];
  const float* k3b    = (const float*)d_in[10];
  const float* fc1w   = (const float*)d_in[11];
  const float* fc1b   = (const float*)d_in[12];
  const float* fc2w   = (const float*)d_in[13];
  const float* fc2b   = (const float*)d_in[14];
  float* out = (float*)d_out;

  char* ws = (char*)d_ws;
  const size_t MB = 1024 * 1024;
  // ---- phase A/B layout ----
  float*   P    = (float*)(ws + 0);                   // 8MB (dead after build_x0)
  ushortT* cw1  = (ushortT*)(ws + 8 * MB);            // 16 x 4MB = 64MB
  const size_t CW1N = 2u * 1024 * 1024;
  ushortT* pgAh = (ushortT*)(ws + 72 * MB);
  ushortT* pgAl = (ushortT*)(ws + 76 * MB);
  ushortT* pgBh = (ushortT*)(ws + 80 * MB);
  ushortT* pgBl = (ushortT*)(ws + 84 * MB);
  float*   OUT1P = (float*)(ws + 88 * MB);            // 2 x 16MB partials
  ushortT* L1h  = (ushortT*)(ws + 121 * MB);
  ushortT* L1l  = (ushortT*)(ws + 123 * MB);
  ushortT* WA1h = (ushortT*)(ws + 125 * MB);          // 256KB
  ushortT* WA1l = (ushortT*)(ws + 125 * MB + 262144);
  float*   BNB  = (float*)(ws + 126 * MB);            // ~5KB
  // ---- phase C/D layout ----
  ushortT* cw2  = (ushortT*)(ws + 0);                 // 16 x 2MB = 32MB
  const size_t CW2N = 1024u * 1024;
  ushortT* pg2Ah = (ushortT*)(ws + 32 * MB);
  ushortT* pg2Al = (ushortT*)(ws + 34 * MB);
  ushortT* pg2Bh = (ushortT*)(ws + 36 * MB);
  ushortT* pg2Bl = (ushortT*)(ws + 38 * MB);
  float*   OUT2P = (float*)(ws + 40 * MB);            // 4 x 8MB partials
  ushortT* L2h  = (ushortT*)(ws + 73 * MB);
  ushortT* L2l  = (ushortT*)(ws + 73 * MB + 131072);
  ushortT* WA2h = (ushortT*)(ws + 74 * MB);           // 1MB
  ushortT* WA2l = (ushortT*)(ws + 75 * MB);
  float*   At   = (float*)(ws + 76 * MB);             // 2MB
  float*   PART = (float*)(ws + 78 * MB);             // 2MB
  float*   H    = (float*)(ws + 80 * MB);             // 64KB

  // ---- phase A ----
  conv_pool_k<<<1024, 256, 0, stream>>>(x, conv1w, conv1b, P);
  bn_part_k<<<dim3(64, 8), 256, 0, stream>>>(P, BNB);
  bn_comb_k<<<1, 64, 0, stream>>>(BNB);
  lsplit_k<<<512, 256, 0, stream>>>(L1, L1h, L1l, 1024);
  wprep_k<<<512, 256, 0, stream>>>(k2w, WA1h, WA1l, 64, 128);
  build_x0_k<<<1024, 256, 0, stream>>>(P, BNB, ni, perm, pgAh, pgAl, cw1 + 0 * CW1N);

  // ---- phase B: gc1 chain + K-split weight-apply ----
  cheb_step_k<0, 1, 1024><<<512, 256, 0, stream>>>(2048, 32, pgAh, pgAl, L1h, L1l,
                                                   pgBh, pgBl, cw1 + 1 * CW1N, 64, 6);
  for (int k = 2; k < 16; ++k) {
    ushortT *ah, *al, *oh, *ol;
    if (k & 1) { ah = pgAh; al = pgAl; oh = pgBh; ol = pgBl; }
    else       { ah = pgBh; al = pgBl; oh = pgAh; ol = pgAl; }
    cheb_step_k<1, 1, 1024><<<512, 256, 0, stream>>>(2048, 32, ah, al, L1h, L1l,
                                                     oh, ol, cw1 + (size_t)k * CW1N, 64, 6);
  }
  wapply_k<64, 2><<<dim3(2, 256, 2), 256, 0, stream>>>(32768, 128, WA1h, WA1l,
                                                       cw1, CW1N, OUT1P, (size_t)128 * 32768);

  // ---- phase C: gc2 ----
  relu_pool1_k<<<1024, 256, 0, stream>>>(OUT1P, k2b, pg2Ah, pg2Al, cw2 + 0 * CW2N);
  lsplit_k<<<32, 256, 0, stream>>>(L2, L2h, L2l, 256);
  wprep_k<<<2048, 256, 0, stream>>>(k3w, WA2h, WA2l, 128, 256);

  cheb_step_k<0, 0, 256><<<256, 256, 0, stream>>>(4096, 64, pg2Ah, pg2Al, L2h, L2l,
                                                  pg2Bh, pg2Bl, cw2 + 1 * CW2N, 128, 7);
  for (int k = 2; k < 16; ++k) {
    ushortT *ah, *al, *oh, *ol;
    if (k & 1) { ah = pg2Ah; al = pg2Al; oh = pg2Bh; ol = pg2Bl; }
    else       { ah = pg2Bh; al = pg2Bl; oh = pg2Ah; ol = pg2Al; }
    cheb_step_k<1, 0, 256><<<256, 256, 0, stream>>>(4096, 64, ah, al, L2h, L2l,
                                                    oh, ol, cw2 + (size_t)k * CW2N, 128, 7);
  }
  wapply_k<128, 4><<<dim3(4, 64, 4), 256, 0, stream>>>(8192, 256, WA2h, WA2l,
                                                       cw2, CW2N, OUT2P, (size_t)256 * 8192);

  // ---- phase D: fc ----
  relu_pool2_k<<<2048, 256, 0, stream>>>(OUT2P, k3b, At);
  fc1_part_k<<<dim3(8, 32), 256, 0, stream>>>(At, fc1w, PART);
  fc1_combine_k<<<64, 256, 0, stream>>>(PART, fc1b, H);
  fc2_k<<<5, 64, 0, stream>>>(H, fc2w, fc2b, out);
}

// Round 12
// 517.137 us; speedup vs baseline: 1.2534x; 1.1035x over previous
//
#include <hip/hip_runtime.h>
#include <hip/hip_bf16.h>

// ---------------- problem constants ----------------
#define BB 32
#define C_IN 3
#define HW 64
#define V1 1024
#define CL2_F 128
#define V2 256
#define CL3_F 256
#define FC1_IN 16384

typedef unsigned short ushortT;
typedef __attribute__((ext_vector_type(8))) short bf16x8;
typedef __attribute__((ext_vector_type(8))) unsigned short u16x8;
typedef __attribute__((ext_vector_type(4))) float f32x4;

__device__ __forceinline__ float bfu2f(unsigned short u) {
  union { unsigned int i; float f; } x; x.i = ((unsigned)u) << 16; return x.f;
}
__device__ __forceinline__ unsigned short f2bf(float v) {
  union { float f; unsigned int i; } x; x.f = v;
  unsigned r = x.i + 0x7FFFu + ((x.i >> 16) & 1u);
  return (unsigned short)(r >> 16);
}
__device__ __forceinline__ void gload16(const ushortT* g, ushortT* l) {
  __builtin_amdgcn_global_load_lds((const __attribute__((address_space(1))) void*)g,
                                   (__attribute__((address_space(3))) void*)l, 16, 0, 0);
}

// ---------------- conv1 (5x5 pad2) + ReLU + 2x2 maxpool ----------------
__global__ __launch_bounds__(256) void conv_pool_k(const float* __restrict__ x,
                                                   const float* __restrict__ w,
                                                   const float* __restrict__ bias,
                                                   float* __restrict__ P) {
  __shared__ float xs[3][7][72];
  __shared__ float wl[64][76];
  const int b = blockIdx.x >> 5, ph = blockIdx.x & 31;
  const int t = threadIdx.x;
  for (int i = t; i < 64 * 75; i += 256) wl[i / 75][i % 75] = w[i];
  for (int i = t; i < 3 * 7 * 72; i += 256) {
    int col = i % 72, rr = (i / 72) % 7, ci = i / (72 * 7);
    int ih = 2 * ph - 2 + rr, iw = col - 2;
    float v = 0.f;
    if (ih >= 0 && ih < HW && iw >= 0 && iw < HW)
      v = x[((b * 3 + ci) * HW + ih) * HW + iw];
    xs[ci][rr][col] = v;
  }
  __syncthreads();
  const int co = t >> 2, pq = t & 3;
  float acc[8][2][2];
#pragma unroll
  for (int i = 0; i < 8; ++i)
#pragma unroll
    for (int a = 0; a < 2; ++a)
#pragma unroll
      for (int d = 0; d < 2; ++d) acc[i][a][d] = 0.f;
  for (int ci = 0; ci < 3; ++ci) {
#pragma unroll
    for (int kh = 0; kh < 5; ++kh) {
      float w5[5];
#pragma unroll
      for (int j = 0; j < 5; ++j) w5[j] = wl[co][ci * 25 + kh * 5 + j];
#pragma unroll
      for (int dy = 0; dy < 2; ++dy) {
        const int r = kh + dy;
        float in[20];
#pragma unroll
        for (int q4 = 0; q4 < 5; ++q4) {
          float4 v4 = *(const float4*)&xs[ci][r][16 * pq + q4 * 4];
          in[q4 * 4 + 0] = v4.x; in[q4 * 4 + 1] = v4.y;
          in[q4 * 4 + 2] = v4.z; in[q4 * 4 + 3] = v4.w;
        }
#pragma unroll
        for (int i = 0; i < 8; ++i)
#pragma unroll
          for (int dx = 0; dx < 2; ++dx)
#pragma unroll
            for (int kw = 0; kw < 5; ++kw)
              acc[i][dy][dx] += w5[kw] * in[2 * i + dx + kw];
      }
    }
  }
  const float bv = bias[co];
#pragma unroll
  for (int i = 0; i < 8; ++i) {
    float m = fmaxf(fmaxf(acc[i][0][0], acc[i][0][1]), fmaxf(acc[i][1][0], acc[i][1][1]));
    P[((size_t)(b * 64 + co) << 10) + (ph << 5) + pq * 8 + i] = fmaxf(m + bv, 0.f);
  }
}

// ---------------- BN stats (2-stage) ----------------
__global__ __launch_bounds__(256) void bn_part_k(const float* __restrict__ P,
                                                 float* __restrict__ buf) {
  int c = blockIdx.x, s = blockIdx.y;
  float s1 = 0.f, s2 = 0.f;
  for (int i = threadIdx.x; i < 4096; i += 256) {
    int b = s * 4 + (i >> 10), p = i & 1023;
    float v = P[((size_t)(b * 64 + c) << 10) + p];
    s1 += v; s2 += v * v;
  }
#pragma unroll
  for (int o = 32; o > 0; o >>= 1) { s1 += __shfl_down(s1, o); s2 += __shfl_down(s2, o); }
  __shared__ float sh[2][4];
  int wid = threadIdx.x >> 6;
  if ((threadIdx.x & 63) == 0) { sh[0][wid] = s1; sh[1][wid] = s2; }
  __syncthreads();
  if (threadIdx.x == 0) {
    buf[c * 8 + s] = sh[0][0] + sh[0][1] + sh[0][2] + sh[0][3];
    buf[512 + c * 8 + s] = sh[1][0] + sh[1][1] + sh[1][2] + sh[1][3];
  }
}
__global__ __launch_bounds__(64) void bn_comb_k(float* __restrict__ buf) {
  int c = threadIdx.x;
  float s1 = 0.f, s2 = 0.f;
#pragma unroll
  for (int s = 0; s < 8; ++s) { s1 += buf[c * 8 + s]; s2 += buf[512 + c * 8 + s]; }
  float mean = s1 / 32768.f;
  float var = s2 / 32768.f - mean * mean;
  buf[1024 + c] = mean;
  buf[1088 + c] = rsqrtf(var + 1e-5f);
}

// ---------------- gather + BN -> PG pair + CW(slot0, [c-oct][n][8]) ----------------
__global__ __launch_bounds__(256) void build_x0_k(const float* __restrict__ P,
                                                  const float* __restrict__ buf,
                                                  const int* __restrict__ ni,
                                                  const int* __restrict__ perm,
                                                  ushortT* __restrict__ PGh,
                                                  ushortT* __restrict__ PGl,
                                                  ushortT* __restrict__ CW0) {
  __shared__ float vals[64][33];
  __shared__ int qv[32];
  const int b = blockIdx.x >> 5, vc = blockIdx.x & 31;
  const int t = threadIdx.x;
  if (t < 32) {
    int pv = perm[vc * 32 + t];
    qv[t] = ni[2 * pv] * 32 + ni[2 * pv + 1];
  }
  __syncthreads();
  {
    int c = t & 63, vh = t >> 6;
    float mean = buf[1024 + c], rstd = buf[1088 + c];
    const float* pc = &P[((size_t)(b * 64 + c)) << 10];
#pragma unroll
    for (int j = 0; j < 8; ++j) {
      int vl = vh * 8 + j;
      vals[c][vl] = (pc[qv[vl]] - mean) * rstd;
    }
  }
  __syncthreads();
  {
    int c = t & 63, vo = t >> 6;
    u16x8 h8, l8;
#pragma unroll
    for (int j = 0; j < 8; ++j) {
      float f = vals[c][vo * 8 + j];
      unsigned short h = f2bf(f);
      h8[j] = h; l8[j] = f2bf(f - bfu2f(h));
    }
    size_t base = ((size_t)(vc * 4 + vo) * 2048 + b * 64 + c) * 8;
    *(u16x8*)&PGh[base] = h8;
    *(u16x8*)&PGl[base] = l8;
  }
  {
    int co = t & 7, vl = t >> 3;
    u16x8 h8;
#pragma unroll
    for (int j = 0; j < 8; ++j) h8[j] = f2bf(vals[co * 8 + j][vl]);
    *(u16x8*)&CW0[((size_t)co * 32768 + b * 1024 + vc * 32 + vl) * 8] = h8;
  }
}

// ---------------- L split fp32 -> bf16 hi/lo, octet-grouped LG layout ----------
__global__ __launch_bounds__(256) void lsplit_k(const float* __restrict__ L,
                                                ushortT* __restrict__ Lh,
                                                ushortT* __restrict__ Ll, int V) {
  int id = blockIdx.x * 256 + threadIdx.x;
  int n = id & (V - 1), koct = id / V * 8;
  u16x8 h8, l8;
#pragma unroll
  for (int j = 0; j < 8; ++j) {
    float v = L[(size_t)(koct + j) * V + n];
    unsigned short h = f2bf(v);
    h8[j] = h; l8[j] = f2bf(v - bfu2f(h));
  }
  size_t o = (size_t)id * 8;
  *(u16x8*)&Lh[o] = h8;
  *(u16x8*)&Ll[o] = l8;
}

// ---------------- W prep: octet-grouped WB[koct][f][8], k = kq*Cc + c ----------
__global__ __launch_bounds__(256) void wprep_k(const float* __restrict__ W,
                                               ushortT* __restrict__ WAh,
                                               ushortT* __restrict__ WAl, int Cc, int Nf) {
  int d = blockIdx.x * 256 + threadIdx.x;
  if (d >= Nf * 16 * Cc) return;
  int j = d & 7;
  int f = (d >> 3) % Nf;
  int koct = d / (8 * Nf);
  int k = koct * 8 + j;
  int kq = k / Cc, c = k % Cc;
  float v = W[(size_t)f * (Cc * 16) + c * 16 + kq];
  unsigned short h = f2bf(v);
  WAh[d] = h; WAl[d] = f2bf(v - bfu2f(h));
}

// ---------------- gc1 Chebyshev step: 3-deep pipelined (R10-verified) ----------
template <int MODE, int SWZ, int KD>
__global__ __launch_bounds__(256) void cheb_step_k(
    int Mld, int mt,
    const ushortT* __restrict__ Ah, const ushortT* __restrict__ Al,
    const ushortT* __restrict__ Lbh, const ushortT* __restrict__ Lbl,
    ushortT* __restrict__ Ph, ushortT* __restrict__ Pl,
    ushortT* __restrict__ CW, int CB, int CSH) {
  constexpr int NPH = KD / 64;
  __shared__ ushortT sA[3][2][8][520];
  int bx, by;
  if (SWZ) {
    const int id = blockIdx.x;
    const int xcd = id & 7, pos = id >> 3;
    bx = (xcd & 3) * 8 + (pos & 7);
    by = (xcd >> 2) * 8 + (pos >> 3);
  } else {
    bx = blockIdx.x % mt;
    by = blockIdx.x / mt;
  }
  const int m0 = bx * 64, n0 = by * 64;
  const int t = threadIdx.x, lane = t & 63;
  const int wr = (t >> 6) >> 1, wc = (t >> 6) & 1;
  const int lm = lane & 15, lq = lane >> 4;
  const size_t bCol = (size_t)(n0 + wc * 32 + lm);

  f32x4 acc[2][2];
#pragma unroll
  for (int mi = 0; mi < 2; ++mi)
#pragma unroll
    for (int nj = 0; nj < 2; ++nj) acc[mi][nj] = (f32x4){0.f, 0.f, 0.f, 0.f};

  bf16x8 Bh[2][2][2], Bl[2][2][2];

#define STAGEA(buf, slot)                                                          \
  {                                                                                \
    const int koct = (slot) * 8;                                                   \
    _Pragma("unroll") for (int i = 0; i < 2; ++i) {                                \
      const int sl = (t + i * 256) >> 6;                                           \
      const int ln = t & 63;                                                       \
      const size_t ga = ((size_t)(koct + sl) * Mld + m0 + ln) * 8;                 \
      gload16(Ah + ga, &sA[buf][0][sl][0]);                                        \
      gload16(Al + ga, &sA[buf][1][sl][0]);                                        \
    }                                                                              \
  }

#define LOADB(set, slot)                                                           \
  {                                                                                \
    _Pragma("unroll") for (int ks = 0; ks < 2; ++ks)                               \
        _Pragma("unroll") for (int nj = 0; nj < 2; ++nj) {                         \
      size_t o = ((size_t)((slot) * 8 + ks * 4 + lq) * KD + bCol + nj * 16) * 8;   \
      Bh[set][ks][nj] = *(const bf16x8*)(Lbh + o);                                 \
      Bl[set][ks][nj] = *(const bf16x8*)(Lbl + o);                                 \
    }                                                                              \
  }

#define DOMFMA(buf, set)                                                           \
  {                                                                                \
    _Pragma("unroll") for (int ks = 0; ks < 2; ++ks) {                             \
      const int so = ks * 4 + lq;                                                  \
      bf16x8 xah[2], xal[2];                                                       \
      _Pragma("unroll") for (int mi = 0; mi < 2; ++mi) {                           \
        const int r = (wr * 32 + mi * 16 + lm) * 8;                                \
        xah[mi] = *(const bf16x8*)&sA[buf][0][so][r];                              \
        xal[mi] = *(const bf16x8*)&sA[buf][1][so][r];                              \
      }                                                                            \
      _Pragma("unroll") for (int mi = 0; mi < 2; ++mi)                             \
          _Pragma("unroll") for (int nj = 0; nj < 2; ++nj) {                       \
        acc[mi][nj] = __builtin_amdgcn_mfma_f32_16x16x32_bf16(xah[mi], Bh[set][ks][nj], \
                                                              acc[mi][nj], 0, 0, 0);\
        acc[mi][nj] = __builtin_amdgcn_mfma_f32_16x16x32_bf16(xal[mi], Bh[set][ks][nj], \
                                                              acc[mi][nj], 0, 0, 0);\
        acc[mi][nj] = __builtin_amdgcn_mfma_f32_16x16x32_bf16(xah[mi], Bl[set][ks][nj], \
                                                              acc[mi][nj], 0, 0, 0);\
      }                                                                            \
    }                                                                              \
  }

  STAGEA(0, 0);
  STAGEA(1, 1);
  LOADB(0, 0);
#pragma unroll
  for (int tt = 0; tt < NPH; ++tt) {
    asm volatile("s_waitcnt vmcnt(12) lgkmcnt(0)" ::: "memory");
    __builtin_amdgcn_s_barrier();
    STAGEA((tt + 2) % 3, (tt + 2) % NPH);
    LOADB((tt + 1) % 2, (tt + 1) % NPH);
    __builtin_amdgcn_s_setprio(1);
    DOMFMA(tt % 3, tt % 2);
    __builtin_amdgcn_s_setprio(0);
  }
  asm volatile("s_waitcnt vmcnt(0)" ::: "memory");
  __syncthreads();
#undef STAGEA
#undef LOADB
#undef DOMFMA

  float* fs = (float*)&sA[0][0][0][0];
#pragma unroll
  for (int mi = 0; mi < 2; ++mi)
#pragma unroll
    for (int nj = 0; nj < 2; ++nj)
#pragma unroll
      for (int j = 0; j < 4; ++j) {
        int gm_l = wr * 32 + mi * 16 + lq * 4 + j;
        int gn_l = wc * 32 + nj * 16 + lm;
        fs[gm_l * 65 + gn_l] = acc[mi][nj][j];
      }
  __syncthreads();

  const size_t noct0 = (size_t)(n0 >> 3);
#pragma unroll
  for (int r = 0; r < 2; ++r) {
    int id = t + r * 256;
    int gm_l = id >> 3, go = id & 7;
    size_t g = ((noct0 + go) * Mld + (m0 + gm_l)) * 8;
    float nv[8];
#pragma unroll
    for (int i = 0; i < 8; ++i) nv[i] = fs[gm_l * 65 + go * 8 + i];
    if (MODE == 1) {
      u16x8 ph = *(const u16x8*)&Ph[g];
      u16x8 pl = *(const u16x8*)&Pl[g];
#pragma unroll
      for (int i = 0; i < 8; ++i) nv[i] = 2.f * nv[i] - (bfu2f(ph[i]) + bfu2f(pl[i]));
    }
    u16x8 h8, l8;
#pragma unroll
    for (int i = 0; i < 8; ++i) {
      unsigned short h = f2bf(nv[i]);
      h8[i] = h; l8[i] = f2bf(nv[i] - bfu2f(h));
    }
    *(u16x8*)&Ph[g] = h8;
    *(u16x8*)&Pl[g] = l8;
    if (MODE == 1) {
#pragma unroll
      for (int i = 0; i < 8; ++i) fs[gm_l * 65 + go * 8 + i] = nv[i];
    }
  }
  __syncthreads();

  const int cBase = m0 & (CB - 1);
  const int bidx = m0 >> CSH;
  const size_t NNs = (size_t)KD << 5;
#pragma unroll
  for (int r = 0; r < 2; ++r) {
    int id = t + r * 256;
    int gn_l = id & 63, coI = id >> 6;
    u16x8 h8;
#pragma unroll
    for (int i = 0; i < 8; ++i) h8[i] = f2bf(fs[(coI * 8 + i) * 65 + gn_l]);
    size_t cbase = ((size_t)((cBase >> 3) + coI) * NNs + (size_t)bidx * KD + n0 + gn_l) * 8;
    *(u16x8*)&CW[cbase] = h8;
  }
}

// ---------------- gc2 FUSED chain: col-slab persistent, all 15 steps ----------
// Each block owns 16 cols (of 4096) x all 256 v; state (hi/lo, 2 slots) in LDS.
// No grid sync needed: the recurrence only couples the v dimension.
__global__ __launch_bounds__(256) void cheb2_slab_k(
    const ushortT* __restrict__ PG2h, const ushortT* __restrict__ PG2l,
    const ushortT* __restrict__ Lbh, const ushortT* __restrict__ Lbl,
    ushortT* __restrict__ cw, size_t cwN) {
  __shared__ ushortT stH[2][16][33 * 8];  // [slot][m][voct(pad 33)*8]
  __shared__ ushortT stL[2][16][33 * 8];
  const int m0 = blockIdx.x * 16;
  const int t = threadIdx.x, lane = t & 63, w = t >> 6;
  const int lm = lane & 15, lq = lane >> 4;
  const int n0w = w * 64;

  // load x0 (PG2 pair) into slot 0
  for (int i = t; i < 16 * 32; i += 256) {
    int m = i >> 5, voct = i & 31;
    size_t g = ((size_t)voct * 4096 + m0 + m) * 8;
    *(u16x8*)&stH[0][m][voct * 8] = *(const u16x8*)&PG2h[g];
    *(u16x8*)&stL[0][m][voct * 8] = *(const u16x8*)&PG2l[g];
  }
  __syncthreads();

  const int cb = (m0 & 127) >> 3;  // base f-octet
  const int bi = m0 >> 7;          // batch index

#pragma unroll 1
  for (int k = 1; k < 16; ++k) {
    const int sa = (k + 1) & 1;  // A slot (x_{k-1}): k=1 -> 0
    const int sw = k & 1;        // write slot (x_k over x_{k-2}): k=1 -> 1
    f32x4 acc[4];
#pragma unroll
    for (int nj = 0; nj < 4; ++nj) acc[nj] = (f32x4){0.f, 0.f, 0.f, 0.f};

#pragma unroll
    for (int ks = 0; ks < 8; ++ks) {
      const int koct = ks * 4 + lq;
      bf16x8 ah = *(const bf16x8*)&stH[sa][lm][koct * 8];
      bf16x8 al = *(const bf16x8*)&stL[sa][lm][koct * 8];
#pragma unroll
      for (int nj = 0; nj < 4; ++nj) {
        size_t o = ((size_t)koct * 256 + n0w + nj * 16 + lm) * 8;
        bf16x8 bh = *(const bf16x8*)(Lbh + o);
        bf16x8 bl = *(const bf16x8*)(Lbl + o);
        acc[nj] = __builtin_amdgcn_mfma_f32_16x16x32_bf16(ah, bh, acc[nj], 0, 0, 0);
        acc[nj] = __builtin_amdgcn_mfma_f32_16x16x32_bf16(al, bh, acc[nj], 0, 0, 0);
        acc[nj] = __builtin_amdgcn_mfma_f32_16x16x32_bf16(ah, bl, acc[nj], 0, 0, 0);
      }
    }

    // Chebyshev combine (prev = slot sw) + state write (slot sw), thread-local RAW
#pragma unroll
    for (int nj = 0; nj < 4; ++nj) {
      int n = n0w + nj * 16 + lm;
      int vo8 = (n >> 3) * 8 + (n & 7);
#pragma unroll
      for (int j = 0; j < 4; ++j) {
        int m = lq * 4 + j;
        float d = acc[nj][j];
        float nv;
        if (k > 1) nv = 2.f * d - (bfu2f(stH[sw][m][vo8]) + bfu2f(stL[sw][m][vo8]));
        else nv = d;
        unsigned short h = f2bf(nv);
        stH[sw][m][vo8] = h;
        stL[sw][m][vo8] = f2bf(nv - bfu2f(h));
      }
    }
    __syncthreads();  // state(sw) complete before CW transpose-read + next-step A reads

    // CW[k] write: coalesced u16x8 over v
    ushortT* CWk = cw + (size_t)k * cwN;
#pragma unroll
    for (int r = 0; r < 2; ++r) {
      int id = t + r * 256;
      int fo = id >> 8, v = id & 255;
      u16x8 h8;
#pragma unroll
      for (int j = 0; j < 8; ++j) h8[j] = stH[sw][fo * 8 + j][(v >> 3) * 8 + (v & 7)];
      *(u16x8*)&CWk[((size_t)(cb + fo) * 8192 + (size_t)bi * 256 + v) * 8] = h8;
    }
  }
}

// ---------------- weight apply: 3-deep pipelined X via global_load_lds ----------
template <int Cc, int NSPL>
__global__ __launch_bounds__(256) void wapply_k(
    int NN, int Nf,
    const ushortT* __restrict__ WAh, const ushortT* __restrict__ WAl,
    const ushortT* __restrict__ cwBase, size_t cwN,
    float* __restrict__ OUT, size_t outStride) {
  constexpr int S = Cc / 2;
  constexpr int SPZ = S / NSPL;
  constexpr int ROWU = 129 * 8;
  __shared__ ushortT sX[3][4 * ROWU];
  const int z = blockIdx.z;
  OUT += (size_t)z * outStride;
  const int m0 = blockIdx.x * 64, n0 = blockIdx.y * 128;
  const int t = threadIdx.x, lane = t & 63, wid = t >> 6;
  const int wr = wid >> 1, wc = wid & 1;
  const int lm = lane & 15, lq = lane >> 4;

  const int fIdx = m0 + wr * 32 + lm;
  const int s0 = z * SPZ;

  f32x4 acc[2][4];
#pragma unroll
  for (int mi = 0; mi < 2; ++mi)
#pragma unroll
    for (int nj = 0; nj < 4; ++nj) acc[mi][nj] = (f32x4){0.f, 0.f, 0.f, 0.f};

  bf16x8 wh[2][2], wl[2][2];

#define STX(buf, s)                                                                \
  {                                                                                \
    const int buf_ = (Cc == 64) ? ((s) >> 1) : ((s) >> 2);                         \
    const int lo_ = (Cc == 64) ? (((s) & 1) * 4) : (((s) & 3) * 4);                \
    const ushortT* xb_ = cwBase + (size_t)buf_ * cwN;                              \
    _Pragma("unroll") for (int i = 0; i < 2; ++i) {                                \
      const int idx = t + i * 256;                                                 \
      const int octrow = idx >> 7, col = idx & 127;                                \
      const int chunk = idx >> 6;                                                  \
      const ushortT* src = xb_ + ((size_t)(lo_ + octrow) * NN + n0 + col) * 8;     \
      gload16(src, &sX[buf][octrow * ROWU + (chunk & 1) * 512]);                   \
    }                                                                              \
  }

#define LDW(set, s)                                                                \
  {                                                                                \
    _Pragma("unroll") for (int mi = 0; mi < 2; ++mi) {                             \
      size_t o = ((size_t)((s)*4 + lq) * Nf + fIdx + mi * 16) * 8;                 \
      wh[set][mi] = *(const bf16x8*)(WAh + o);                                     \
      wl[set][mi] = *(const bf16x8*)(WAl + o);                                     \
    }                                                                              \
  }

#define XMFMA(buf, set)                                                            \
  {                                                                                \
    bf16x8 xf[4];                                                                  \
    _Pragma("unroll") for (int nj = 0; nj < 4; ++nj)                               \
        xf[nj] = *(const bf16x8*)&sX[buf][lq * ROWU + (wc * 64 + lm + nj * 16) * 8];\
    _Pragma("unroll") for (int mi = 0; mi < 2; ++mi)                               \
        _Pragma("unroll") for (int nj = 0; nj < 4; ++nj) {                         \
      acc[mi][nj] = __builtin_amdgcn_mfma_f32_16x16x32_bf16(wh[set][mi], xf[nj],   \
                                                            acc[mi][nj], 0, 0, 0); \
      acc[mi][nj] = __builtin_amdgcn_mfma_f32_16x16x32_bf16(wl[set][mi], xf[nj],   \
                                                            acc[mi][nj], 0, 0, 0); \
    }                                                                              \
  }

  STX(0, s0);
  STX(1, s0 + 1);
  LDW(0, s0);
#pragma unroll
  for (int tt = 0; tt < SPZ; ++tt) {
    asm volatile("s_waitcnt vmcnt(6) lgkmcnt(0)" ::: "memory");
    __builtin_amdgcn_s_barrier();
    STX((tt + 2) % 3, s0 + (tt + 2) % SPZ);
    LDW((tt + 1) % 2, s0 + (tt + 1) % SPZ);
    __builtin_amdgcn_s_setprio(1);
    XMFMA(tt % 3, tt % 2);
    __builtin_amdgcn_s_setprio(0);
  }
#undef STX
#undef LDW
#undef XMFMA

#pragma unroll
  for (int mi = 0; mi < 2; ++mi)
#pragma unroll
    for (int nj = 0; nj < 4; ++nj)
#pragma unroll
      for (int j = 0; j < 4; ++j) {
        int gm = m0 + wr * 32 + mi * 16 + lq * 4 + j;
        int gn = n0 + wc * 64 + nj * 16 + lm;
        OUT[(size_t)gm * NN + gn] = acc[mi][nj][j];
      }
}

// ---------------- gc1 epilogue: sum 2 partials -> PG2 pair + CW2 slot0 --------
__global__ __launch_bounds__(256) void relu_pool1_k(const float* __restrict__ OUT1P,
                                                    const float* __restrict__ b2,
                                                    ushortT* __restrict__ PG2h,
                                                    ushortT* __restrict__ PG2l,
                                                    ushortT* __restrict__ CW0) {
  __shared__ float sval[128][9];
  const int b = blockIdx.x >> 5, vc = blockIdx.x & 31;
  const int t = threadIdx.x;
  const size_t PS = (size_t)128 * 32768;
  {
    int f = t & 127, h = t >> 7;
    float bb = b2[f];
    const float* src = &OUT1P[(size_t)f * 32768 + b * 1024 + vc * 32];
#pragma unroll
    for (int i = 0; i < 4; ++i) {
      int v2l = h * 4 + i;
      float4 r0 = *(const float4*)&src[v2l * 4];
      float4 r1 = *(const float4*)&src[PS + v2l * 4];
      float s0 = r0.x + r1.x, s1 = r0.y + r1.y, s2 = r0.z + r1.z, s3 = r0.w + r1.w;
      float m = fmaxf(fmaxf(s0, s1), fmaxf(s2, s3));
      sval[f][v2l] = fmaxf(m + bb, 0.f);
    }
  }
  __syncthreads();
  if (t < 128) {
    int f = t;
    u16x8 h8, l8;
#pragma unroll
    for (int j = 0; j < 8; ++j) {
      float v = sval[f][j];
      unsigned short h = f2bf(v);
      h8[j] = h; l8[j] = f2bf(v - bfu2f(h));
    }
    size_t base = ((size_t)vc * 4096 + b * 128 + f) * 8;
    *(u16x8*)&PG2h[base] = h8;
    *(u16x8*)&PG2l[base] = l8;
  } else {
    int q = t - 128;
    int co = q & 15, v2l = q >> 4;
    u16x8 h8;
#pragma unroll
    for (int j = 0; j < 8; ++j) h8[j] = f2bf(sval[co * 8 + j][v2l]);
    *(u16x8*)&CW0[((size_t)co * 8192 + b * 256 + vc * 8 + v2l) * 8] = h8;
  }
}

// ---------------- gc2 epilogue: sum 4 partials -> At[b][f*64+v3] --------------
__global__ __launch_bounds__(256) void relu_pool2_k(const float* __restrict__ OUT2P,
                                                    const float* __restrict__ b3,
                                                    float* __restrict__ At) {
  int n = blockIdx.x * 256 + threadIdx.x;  // 524288
  int v3 = n & 63, f = (n >> 6) & 255, b = n >> 14;
  const size_t PS = (size_t)256 * 8192;
  size_t base = ((size_t)f * 32 + b) * 256 + v3 * 4;
  float4 r0 = *(const float4*)&OUT2P[base];
  float4 r1 = *(const float4*)&OUT2P[PS + base];
  float4 r2 = *(const float4*)&OUT2P[2 * PS + base];
  float4 r3 = *(const float4*)&OUT2P[3 * PS + base];
  float s0 = r0.x + r1.x + r2.x + r3.x;
  float s1 = r0.y + r1.y + r2.y + r3.y;
  float s2 = r0.z + r1.z + r2.z + r3.z;
  float s3 = r0.w + r1.w + r2.w + r3.w;
  float m = fmaxf(fmaxf(s0, s1), fmaxf(s2, s3));
  At[(size_t)b * FC1_IN + f * 64 + v3] = fmaxf(m + b3[f], 0.f);
}

// ---------------- fc1: LDS-tiled split-K ----------------
__global__ __launch_bounds__(256) void fc1_part_k(const float* __restrict__ At,
                                                  const float* __restrict__ W1,
                                                  float* __restrict__ part) {
  __shared__ float sWt[64][68];
  __shared__ float sA[64][33];
  const int jt = blockIdx.x, ks = blockIdx.y;
  const int j0 = jt * 64, kb = ks * 512;
  const int t = threadIdx.x;
  const int b = t & 31, jg = t >> 5;
  float acc[8] = {};
  for (int k0 = kb; k0 < kb + 512; k0 += 64) {
    __syncthreads();
    {
      int jr = t >> 2, kq = t & 3;
      const float* wp = &W1[(size_t)(j0 + jr) * FC1_IN + k0 + kq * 16];
#pragma unroll
      for (int i = 0; i < 4; ++i) {
        float4 w4 = *(const float4*)(wp + 4 * i);
        int kk = kq * 16 + 4 * i;
        sWt[kk + 0][jr] = w4.x; sWt[kk + 1][jr] = w4.y;
        sWt[kk + 2][jr] = w4.z; sWt[kk + 3][jr] = w4.w;
      }
    }
    {
      int br = t >> 3, ko = t & 7;
      const float* ap = &At[(size_t)br * FC1_IN + k0 + ko * 8];
      float4 a0 = *(const float4*)ap;
      float4 a1 = *(const float4*)(ap + 4);
      int kk = ko * 8;
      sA[kk + 0][br] = a0.x; sA[kk + 1][br] = a0.y; sA[kk + 2][br] = a0.z; sA[kk + 3][br] = a0.w;
      sA[kk + 4][br] = a1.x; sA[kk + 5][br] = a1.y; sA[kk + 6][br] = a1.z; sA[kk + 7][br] = a1.w;
    }
    __syncthreads();
#pragma unroll 8
    for (int kk = 0; kk < 64; ++kk) {
      float a = sA[kk][b];
      float wv[8];
      *(float4*)wv = *(const float4*)&sWt[kk][jg * 8];
      *(float4*)(wv + 4) = *(const float4*)&sWt[kk][jg * 8 + 4];
#pragma unroll
      for (int i = 0; i < 8; ++i) acc[i] += wv[i] * a;
    }
  }
#pragma unroll
  for (int i = 0; i < 8; ++i)
    part[((size_t)ks * 512 + j0 + jg * 8 + i) * 32 + b] = acc[i];
}

__global__ __launch_bounds__(256) void fc1_combine_k(const float* __restrict__ part,
                                                     const float* __restrict__ b1,
                                                     float* __restrict__ h) {
  int n = blockIdx.x * 256 + threadIdx.x;  // 16384
  int b = n >> 9, j = n & 511;
  float s = b1[j];
#pragma unroll
  for (int ks = 0; ks < 32; ++ks) s += part[((size_t)ks * 512 + j) * 32 + b];
  h[n] = fmaxf(s, 0.f);
}

__global__ __launch_bounds__(64) void fc2_k(const float* __restrict__ h,
                                            const float* __restrict__ W2,
                                            const float* __restrict__ b2f,
                                            float* __restrict__ out) {
  int n = blockIdx.x * 64 + threadIdx.x;  // 320
  if (n >= 320) return;
  int b = n / 10, o = n % 10;
  float s = b2f[o];
  const float* hp = h + b * 512;
  const float* wp = W2 + o * 512;
  for (int j = 0; j < 512; ++j) s += hp[j] * wp[j];
  out[n] = s;
}

// ---------------- launch ----------------
extern "C" void kernel_launch(void* const* d_in, const int* in_sizes, int n_in,
                              void* d_out, int out_size, void* d_ws, size_t ws_size,
                              hipStream_t stream) {
  const float* x      = (const float*)d_in[0];
  const float* conv1w = (const float*)d_in[1];
  const float* conv1b = (const float*)d_in[2];
  const float* L1     = (const float*)d_in[3];
  const float* L2     = (const float*)d_in[4];
  const int*   ni     = (const int*)d_in[5];
  const int*   perm   = (const int*)d_in[6];
  const float* k2w    = (const float*)d_in[7];
  const float* k2b    = (const float*)d_in[8];
  const float* k3w    = (const float*)d_in[9];
  const float* k3b    = (const float*)d_in[10];
  const float* fc1w   = (const float*)d_in[11];
  const float* fc1b   = (const float*)d_in[12];
  const float* fc2w   = (const float*)d_in[13];
  const float* fc2b   = (const float*)d_in[14];
  float* out = (float*)d_out;

  char* ws = (char*)d_ws;
  const size_t MB = 1024 * 1024;
  // ---- phase A/B layout ----
  float*   P    = (float*)(ws + 0);                   // 8MB (dead after build_x0)
  ushortT* cw1  = (ushortT*)(ws + 8 * MB);            // 16 x 4MB = 64MB
  const size_t CW1N = 2u * 1024 * 1024;
  ushortT* pgAh = (ushortT*)(ws + 72 * MB);
  ushortT* pgAl = (ushortT*)(ws + 76 * MB);
  ushortT* pgBh = (ushortT*)(ws + 80 * MB);
  ushortT* pgBl = (ushortT*)(ws + 84 * MB);
  float*   OUT1P = (float*)(ws + 88 * MB);            // 2 x 16MB partials
  ushortT* L1h  = (ushortT*)(ws + 121 * MB);
  ushortT* L1l  = (ushortT*)(ws + 123 * MB);
  ushortT* WA1h = (ushortT*)(ws + 125 * MB);          // 256KB
  ushortT* WA1l = (ushortT*)(ws + 125 * MB + 262144);
  float*   BNB  = (float*)(ws + 126 * MB);            // ~5KB
  // ---- phase C/D layout ----
  ushortT* cw2  = (ushortT*)(ws + 0);                 // 16 x 2MB = 32MB
  const size_t CW2N = 1024u * 1024;
  ushortT* pg2Ah = (ushortT*)(ws + 32 * MB);
  ushortT* pg2Al = (ushortT*)(ws + 34 * MB);
  float*   OUT2P = (float*)(ws + 40 * MB);            // 4 x 8MB partials
  ushortT* L2h  = (ushortT*)(ws + 73 * MB);
  ushortT* L2l  = (ushortT*)(ws + 73 * MB + 131072);
  ushortT* WA2h = (ushortT*)(ws + 74 * MB);           // 1MB
  ushortT* WA2l = (ushortT*)(ws + 75 * MB);
  float*   At   = (float*)(ws + 76 * MB);             // 2MB
  float*   PART = (float*)(ws + 78 * MB);             // 2MB
  float*   H    = (float*)(ws + 80 * MB);             // 64KB

  // ---- phase A ----
  conv_pool_k<<<1024, 256, 0, stream>>>(x, conv1w, conv1b, P);
  bn_part_k<<<dim3(64, 8), 256, 0, stream>>>(P, BNB);
  bn_comb_k<<<1, 64, 0, stream>>>(BNB);
  lsplit_k<<<512, 256, 0, stream>>>(L1, L1h, L1l, 1024);
  wprep_k<<<512, 256, 0, stream>>>(k2w, WA1h, WA1l, 64, 128);
  build_x0_k<<<1024, 256, 0, stream>>>(P, BNB, ni, perm, pgAh, pgAl, cw1 + 0 * CW1N);

  // ---- phase B: gc1 chain (per-step dispatches) + K-split weight-apply ----
  cheb_step_k<0, 1, 1024><<<512, 256, 0, stream>>>(2048, 32, pgAh, pgAl, L1h, L1l,
                                                   pgBh, pgBl, cw1 + 1 * CW1N, 64, 6);
  for (int k = 2; k < 16; ++k) {
    ushortT *ah, *al, *oh, *ol;
    if (k & 1) { ah = pgAh; al = pgAl; oh = pgBh; ol = pgBl; }
    else       { ah = pgBh; al = pgBl; oh = pgAh; ol = pgAl; }
    cheb_step_k<1, 1, 1024><<<512, 256, 0, stream>>>(2048, 32, ah, al, L1h, L1l,
                                                     oh, ol, cw1 + (size_t)k * CW1N, 64, 6);
  }
  wapply_k<64, 2><<<dim3(2, 256, 2), 256, 0, stream>>>(32768, 128, WA1h, WA1l,
                                                       cw1, CW1N, OUT1P, (size_t)128 * 32768);

  // ---- phase C: gc2 (fused slab chain, ONE dispatch) ----
  relu_pool1_k<<<1024, 256, 0, stream>>>(OUT1P, k2b, pg2Ah, pg2Al, cw2 + 0 * CW2N);
  lsplit_k<<<32, 256, 0, stream>>>(L2, L2h, L2l, 256);
  wprep_k<<<2048, 256, 0, stream>>>(k3w, WA2h, WA2l, 128, 256);

  cheb2_slab_k<<<256, 256, 0, stream>>>(pg2Ah, pg2Al, L2h, L2l, cw2, CW2N);

  wapply_k<128, 4><<<dim3(4, 64, 4), 256, 0, stream>>>(8192, 256, WA2h, WA2l,
                                                       cw2, CW2N, OUT2P, (size_t)256 * 8192);

  // ---- phase D: fc ----
  relu_pool2_k<<<2048, 256, 0, stream>>>(OUT2P, k3b, At);
  fc1_part_k<<<dim3(8, 32), 256, 0, stream>>>(At, fc1w, PART);
  fc1_combine_k<<<64, 256, 0, stream>>>(PART, fc1b, H);
  fc2_k<<<5, 64, 0, stream>>>(H, fc2w, fc2b, out);
}

// Round 13
// 508.623 us; speedup vs baseline: 1.2743x; 1.0167x over previous
//
#include <hip/hip_runtime.h>
#include <hip/hip_bf16.h>

// ---------------- problem constants ----------------
#define BB 32
#define C_IN 3
#define HW 64
#define V1 1024
#define CL2_F 128
#define V2 256
#define CL3_F 256
#define FC1_IN 16384

typedef unsigned short ushortT;
typedef __attribute__((ext_vector_type(8))) short bf16x8;
typedef __attribute__((ext_vector_type(8))) unsigned short u16x8;
typedef __attribute__((ext_vector_type(4))) float f32x4;

__device__ __forceinline__ float bfu2f(unsigned short u) {
  union { unsigned int i; float f; } x; x.i = ((unsigned)u) << 16; return x.f;
}
__device__ __forceinline__ unsigned short f2bf(float v) {
  union { float f; unsigned int i; } x; x.f = v;
  unsigned r = x.i + 0x7FFFu + ((x.i >> 16) & 1u);
  return (unsigned short)(r >> 16);
}
__device__ __forceinline__ void gload16(const ushortT* g, ushortT* l) {
  __builtin_amdgcn_global_load_lds((const __attribute__((address_space(1))) void*)g,
                                   (__attribute__((address_space(3))) void*)l, 16, 0, 0);
}

// ---------------- conv1 (5x5 pad2) + ReLU + 2x2 maxpool ----------------
__global__ __launch_bounds__(256) void conv_pool_k(const float* __restrict__ x,
                                                   const float* __restrict__ w,
                                                   const float* __restrict__ bias,
                                                   float* __restrict__ P) {
  __shared__ float xs[3][7][72];
  __shared__ float wl[64][76];
  const int b = blockIdx.x >> 5, ph = blockIdx.x & 31;
  const int t = threadIdx.x;
  for (int i = t; i < 64 * 75; i += 256) wl[i / 75][i % 75] = w[i];
  for (int i = t; i < 3 * 7 * 72; i += 256) {
    int col = i % 72, rr = (i / 72) % 7, ci = i / (72 * 7);
    int ih = 2 * ph - 2 + rr, iw = col - 2;
    float v = 0.f;
    if (ih >= 0 && ih < HW && iw >= 0 && iw < HW)
      v = x[((b * 3 + ci) * HW + ih) * HW + iw];
    xs[ci][rr][col] = v;
  }
  __syncthreads();
  const int co = t >> 2, pq = t & 3;
  float acc[8][2][2];
#pragma unroll
  for (int i = 0; i < 8; ++i)
#pragma unroll
    for (int a = 0; a < 2; ++a)
#pragma unroll
      for (int d = 0; d < 2; ++d) acc[i][a][d] = 0.f;
  for (int ci = 0; ci < 3; ++ci) {
#pragma unroll
    for (int kh = 0; kh < 5; ++kh) {
      float w5[5];
#pragma unroll
      for (int j = 0; j < 5; ++j) w5[j] = wl[co][ci * 25 + kh * 5 + j];
#pragma unroll
      for (int dy = 0; dy < 2; ++dy) {
        const int r = kh + dy;
        float in[20];
#pragma unroll
        for (int q4 = 0; q4 < 5; ++q4) {
          float4 v4 = *(const float4*)&xs[ci][r][16 * pq + q4 * 4];
          in[q4 * 4 + 0] = v4.x; in[q4 * 4 + 1] = v4.y;
          in[q4 * 4 + 2] = v4.z; in[q4 * 4 + 3] = v4.w;
        }
#pragma unroll
        for (int i = 0; i < 8; ++i)
#pragma unroll
          for (int dx = 0; dx < 2; ++dx)
#pragma unroll
            for (int kw = 0; kw < 5; ++kw)
              acc[i][dy][dx] += w5[kw] * in[2 * i + dx + kw];
      }
    }
  }
  const float bv = bias[co];
#pragma unroll
  for (int i = 0; i < 8; ++i) {
    float m = fmaxf(fmaxf(acc[i][0][0], acc[i][0][1]), fmaxf(acc[i][1][0], acc[i][1][1]));
    P[((size_t)(b * 64 + co) << 10) + (ph << 5) + pq * 8 + i] = fmaxf(m + bv, 0.f);
  }
}

// ---------------- BN stats (2-stage) ----------------
__global__ __launch_bounds__(256) void bn_part_k(const float* __restrict__ P,
                                                 float* __restrict__ buf) {
  int c = blockIdx.x, s = blockIdx.y;
  float s1 = 0.f, s2 = 0.f;
  for (int i = threadIdx.x; i < 4096; i += 256) {
    int b = s * 4 + (i >> 10), p = i & 1023;
    float v = P[((size_t)(b * 64 + c) << 10) + p];
    s1 += v; s2 += v * v;
  }
#pragma unroll
  for (int o = 32; o > 0; o >>= 1) { s1 += __shfl_down(s1, o); s2 += __shfl_down(s2, o); }
  __shared__ float sh[2][4];
  int wid = threadIdx.x >> 6;
  if ((threadIdx.x & 63) == 0) { sh[0][wid] = s1; sh[1][wid] = s2; }
  __syncthreads();
  if (threadIdx.x == 0) {
    buf[c * 8 + s] = sh[0][0] + sh[0][1] + sh[0][2] + sh[0][3];
    buf[512 + c * 8 + s] = sh[1][0] + sh[1][1] + sh[1][2] + sh[1][3];
  }
}
__global__ __launch_bounds__(64) void bn_comb_k(float* __restrict__ buf) {
  int c = threadIdx.x;
  float s1 = 0.f, s2 = 0.f;
#pragma unroll
  for (int s = 0; s < 8; ++s) { s1 += buf[c * 8 + s]; s2 += buf[512 + c * 8 + s]; }
  float mean = s1 / 32768.f;
  float var = s2 / 32768.f - mean * mean;
  buf[1024 + c] = mean;
  buf[1088 + c] = rsqrtf(var + 1e-5f);
}

// ---------------- gather + BN -> PG pair + CW(slot0, [c-oct][n][8]) ----------------
__global__ __launch_bounds__(256) void build_x0_k(const float* __restrict__ P,
                                                  const float* __restrict__ buf,
                                                  const int* __restrict__ ni,
                                                  const int* __restrict__ perm,
                                                  ushortT* __restrict__ PGh,
                                                  ushortT* __restrict__ PGl,
                                                  ushortT* __restrict__ CW0) {
  __shared__ float vals[64][33];
  __shared__ int qv[32];
  const int b = blockIdx.x >> 5, vc = blockIdx.x & 31;
  const int t = threadIdx.x;
  if (t < 32) {
    int pv = perm[vc * 32 + t];
    qv[t] = ni[2 * pv] * 32 + ni[2 * pv + 1];
  }
  __syncthreads();
  {
    int c = t & 63, vh = t >> 6;
    float mean = buf[1024 + c], rstd = buf[1088 + c];
    const float* pc = &P[((size_t)(b * 64 + c)) << 10];
#pragma unroll
    for (int j = 0; j < 8; ++j) {
      int vl = vh * 8 + j;
      vals[c][vl] = (pc[qv[vl]] - mean) * rstd;
    }
  }
  __syncthreads();
  {
    int c = t & 63, vo = t >> 6;
    u16x8 h8, l8;
#pragma unroll
    for (int j = 0; j < 8; ++j) {
      float f = vals[c][vo * 8 + j];
      unsigned short h = f2bf(f);
      h8[j] = h; l8[j] = f2bf(f - bfu2f(h));
    }
    size_t base = ((size_t)(vc * 4 + vo) * 2048 + b * 64 + c) * 8;
    *(u16x8*)&PGh[base] = h8;
    *(u16x8*)&PGl[base] = l8;
  }
  {
    int co = t & 7, vl = t >> 3;
    u16x8 h8;
#pragma unroll
    for (int j = 0; j < 8; ++j) h8[j] = f2bf(vals[co * 8 + j][vl]);
    *(u16x8*)&CW0[((size_t)co * 32768 + b * 1024 + vc * 32 + vl) * 8] = h8;
  }
}

// ---------------- L split fp32 -> bf16 hi/lo, octet-grouped LG layout ----------
__global__ __launch_bounds__(256) void lsplit_k(const float* __restrict__ L,
                                                ushortT* __restrict__ Lh,
                                                ushortT* __restrict__ Ll, int V) {
  int id = blockIdx.x * 256 + threadIdx.x;
  int n = id & (V - 1), koct = id / V * 8;
  u16x8 h8, l8;
#pragma unroll
  for (int j = 0; j < 8; ++j) {
    float v = L[(size_t)(koct + j) * V + n];
    unsigned short h = f2bf(v);
    h8[j] = h; l8[j] = f2bf(v - bfu2f(h));
  }
  size_t o = (size_t)id * 8;
  *(u16x8*)&Lh[o] = h8;
  *(u16x8*)&Ll[o] = l8;
}

// ---------------- W prep: octet-grouped WB[koct][f][8], k = kq*Cc + c ----------
__global__ __launch_bounds__(256) void wprep_k(const float* __restrict__ W,
                                               ushortT* __restrict__ WAh,
                                               ushortT* __restrict__ WAl, int Cc, int Nf) {
  int d = blockIdx.x * 256 + threadIdx.x;
  if (d >= Nf * 16 * Cc) return;
  int j = d & 7;
  int f = (d >> 3) % Nf;
  int koct = d / (8 * Nf);
  int k = koct * 8 + j;
  int kq = k / Cc, c = k % Cc;
  float v = W[(size_t)f * (Cc * 16) + c * 16 + kq];
  unsigned short h = f2bf(v);
  WAh[d] = h; WAl[d] = f2bf(v - bfu2f(h));
}

// ---------------- gc1 Chebyshev step: 3-deep pipelined (R10-verified) ----------
template <int MODE, int SWZ, int KD>
__global__ __launch_bounds__(256) void cheb_step_k(
    int Mld, int mt,
    const ushortT* __restrict__ Ah, const ushortT* __restrict__ Al,
    const ushortT* __restrict__ Lbh, const ushortT* __restrict__ Lbl,
    ushortT* __restrict__ Ph, ushortT* __restrict__ Pl,
    ushortT* __restrict__ CW, int CB, int CSH) {
  constexpr int NPH = KD / 64;
  __shared__ ushortT sA[3][2][8][520];
  int bx, by;
  if (SWZ) {
    const int id = blockIdx.x;
    const int xcd = id & 7, pos = id >> 3;
    bx = (xcd & 3) * 8 + (pos & 7);
    by = (xcd >> 2) * 8 + (pos >> 3);
  } else {
    bx = blockIdx.x % mt;
    by = blockIdx.x / mt;
  }
  const int m0 = bx * 64, n0 = by * 64;
  const int t = threadIdx.x, lane = t & 63;
  const int wr = (t >> 6) >> 1, wc = (t >> 6) & 1;
  const int lm = lane & 15, lq = lane >> 4;
  const size_t bCol = (size_t)(n0 + wc * 32 + lm);

  f32x4 acc[2][2];
#pragma unroll
  for (int mi = 0; mi < 2; ++mi)
#pragma unroll
    for (int nj = 0; nj < 2; ++nj) acc[mi][nj] = (f32x4){0.f, 0.f, 0.f, 0.f};

  bf16x8 Bh[2][2][2], Bl[2][2][2];

#define STAGEA(buf, slot)                                                          \
  {                                                                                \
    const int koct = (slot) * 8;                                                   \
    _Pragma("unroll") for (int i = 0; i < 2; ++i) {                                \
      const int sl = (t + i * 256) >> 6;                                           \
      const int ln = t & 63;                                                       \
      const size_t ga = ((size_t)(koct + sl) * Mld + m0 + ln) * 8;                 \
      gload16(Ah + ga, &sA[buf][0][sl][0]);                                        \
      gload16(Al + ga, &sA[buf][1][sl][0]);                                        \
    }                                                                              \
  }

#define LOADB(set, slot)                                                           \
  {                                                                                \
    _Pragma("unroll") for (int ks = 0; ks < 2; ++ks)                               \
        _Pragma("unroll") for (int nj = 0; nj < 2; ++nj) {                         \
      size_t o = ((size_t)((slot) * 8 + ks * 4 + lq) * KD + bCol + nj * 16) * 8;   \
      Bh[set][ks][nj] = *(const bf16x8*)(Lbh + o);                                 \
      Bl[set][ks][nj] = *(const bf16x8*)(Lbl + o);                                 \
    }                                                                              \
  }

#define DOMFMA(buf, set)                                                           \
  {                                                                                \
    _Pragma("unroll") for (int ks = 0; ks < 2; ++ks) {                             \
      const int so = ks * 4 + lq;                                                  \
      bf16x8 xah[2], xal[2];                                                       \
      _Pragma("unroll") for (int mi = 0; mi < 2; ++mi) {                           \
        const int r = (wr * 32 + mi * 16 + lm) * 8;                                \
        xah[mi] = *(const bf16x8*)&sA[buf][0][so][r];                              \
        xal[mi] = *(const bf16x8*)&sA[buf][1][so][r];                              \
      }                                                                            \
      _Pragma("unroll") for (int mi = 0; mi < 2; ++mi)                             \
          _Pragma("unroll") for (int nj = 0; nj < 2; ++nj) {                       \
        acc[mi][nj] = __builtin_amdgcn_mfma_f32_16x16x32_bf16(xah[mi], Bh[set][ks][nj], \
                                                              acc[mi][nj], 0, 0, 0);\
        acc[mi][nj] = __builtin_amdgcn_mfma_f32_16x16x32_bf16(xal[mi], Bh[set][ks][nj], \
                                                              acc[mi][nj], 0, 0, 0);\
        acc[mi][nj] = __builtin_amdgcn_mfma_f32_16x16x32_bf16(xah[mi], Bl[set][ks][nj], \
                                                              acc[mi][nj], 0, 0, 0);\
      }                                                                            \
    }                                                                              \
  }

  STAGEA(0, 0);
  STAGEA(1, 1);
  LOADB(0, 0);
#pragma unroll
  for (int tt = 0; tt < NPH; ++tt) {
    asm volatile("s_waitcnt vmcnt(12) lgkmcnt(0)" ::: "memory");
    __builtin_amdgcn_s_barrier();
    STAGEA((tt + 2) % 3, (tt + 2) % NPH);
    LOADB((tt + 1) % 2, (tt + 1) % NPH);
    __builtin_amdgcn_s_setprio(1);
    DOMFMA(tt % 3, tt % 2);
    __builtin_amdgcn_s_setprio(0);
  }
  asm volatile("s_waitcnt vmcnt(0)" ::: "memory");
  __syncthreads();
#undef STAGEA
#undef LOADB
#undef DOMFMA

  float* fs = (float*)&sA[0][0][0][0];
#pragma unroll
  for (int mi = 0; mi < 2; ++mi)
#pragma unroll
    for (int nj = 0; nj < 2; ++nj)
#pragma unroll
      for (int j = 0; j < 4; ++j) {
        int gm_l = wr * 32 + mi * 16 + lq * 4 + j;
        int gn_l = wc * 32 + nj * 16 + lm;
        fs[gm_l * 65 + gn_l] = acc[mi][nj][j];
      }
  __syncthreads();

  const size_t noct0 = (size_t)(n0 >> 3);
#pragma unroll
  for (int r = 0; r < 2; ++r) {
    int id = t + r * 256;
    int gm_l = id >> 3, go = id & 7;
    size_t g = ((noct0 + go) * Mld + (m0 + gm_l)) * 8;
    float nv[8];
#pragma unroll
    for (int i = 0; i < 8; ++i) nv[i] = fs[gm_l * 65 + go * 8 + i];
    if (MODE == 1) {
      u16x8 ph = *(const u16x8*)&Ph[g];
      u16x8 pl = *(const u16x8*)&Pl[g];
#pragma unroll
      for (int i = 0; i < 8; ++i) nv[i] = 2.f * nv[i] - (bfu2f(ph[i]) + bfu2f(pl[i]));
    }
    u16x8 h8, l8;
#pragma unroll
    for (int i = 0; i < 8; ++i) {
      unsigned short h = f2bf(nv[i]);
      h8[i] = h; l8[i] = f2bf(nv[i] - bfu2f(h));
    }
    *(u16x8*)&Ph[g] = h8;
    *(u16x8*)&Pl[g] = l8;
    if (MODE == 1) {
#pragma unroll
      for (int i = 0; i < 8; ++i) fs[gm_l * 65 + go * 8 + i] = nv[i];
    }
  }
  __syncthreads();

  const int cBase = m0 & (CB - 1);
  const int bidx = m0 >> CSH;
  const size_t NNs = (size_t)KD << 5;
#pragma unroll
  for (int r = 0; r < 2; ++r) {
    int id = t + r * 256;
    int gn_l = id & 63, coI = id >> 6;
    u16x8 h8;
#pragma unroll
    for (int i = 0; i < 8; ++i) h8[i] = f2bf(fs[(coI * 8 + i) * 65 + gn_l]);
    size_t cbase = ((size_t)((cBase >> 3) + coI) * NNs + (size_t)bidx * KD + n0 + gn_l) * 8;
    *(u16x8*)&CW[cbase] = h8;
  }
}

// ---------------- gc2 FUSED chain: col-slab persistent, 16 waves ----------
// Each block owns 16 cols (of 4096) x all 256 v; state (hi/lo, 2 slots) in LDS.
// 1024 threads: wave w owns n-slice [w*16, w*16+16). Same per-element MFMA order
// as the R12-verified 4-wave version -> bit-identical numerics.
__global__ __launch_bounds__(1024) void cheb2_slab_k(
    const ushortT* __restrict__ PG2h, const ushortT* __restrict__ PG2l,
    const ushortT* __restrict__ Lbh, const ushortT* __restrict__ Lbl,
    ushortT* __restrict__ cw, size_t cwN) {
  __shared__ ushortT stH[2][16][33 * 8];  // [slot][m][v(pad to 264)]
  __shared__ ushortT stL[2][16][33 * 8];
  const int m0 = blockIdx.x * 16;
  const int t = threadIdx.x, lane = t & 63, w = t >> 6;  // w in [0,16)
  const int lm = lane & 15, lq = lane >> 4;
  const int n0w = w * 16;

  // load x0 (PG2 pair) into slot 0
  if (t < 512) {
    int m = t >> 5, voct = t & 31;
    size_t g = ((size_t)voct * 4096 + m0 + m) * 8;
    *(u16x8*)&stH[0][m][voct * 8] = *(const u16x8*)&PG2h[g];
    *(u16x8*)&stL[0][m][voct * 8] = *(const u16x8*)&PG2l[g];
  }
  __syncthreads();

  const int cb = (m0 & 127) >> 3;  // base f-octet
  const int bi = m0 >> 7;          // batch index

#pragma unroll 1
  for (int k = 1; k < 16; ++k) {
    const int sa = (k + 1) & 1;  // A slot (x_{k-1})
    const int sw = k & 1;        // write slot (x_k over x_{k-2})
    f32x4 acc = (f32x4){0.f, 0.f, 0.f, 0.f};

#pragma unroll
    for (int ks = 0; ks < 8; ++ks) {
      const int koct = ks * 4 + lq;
      bf16x8 ah = *(const bf16x8*)&stH[sa][lm][koct * 8];
      bf16x8 al = *(const bf16x8*)&stL[sa][lm][koct * 8];
      size_t o = ((size_t)koct * 256 + n0w + lm) * 8;
      bf16x8 bh = *(const bf16x8*)(Lbh + o);
      bf16x8 bl = *(const bf16x8*)(Lbl + o);
      acc = __builtin_amdgcn_mfma_f32_16x16x32_bf16(ah, bh, acc, 0, 0, 0);
      acc = __builtin_amdgcn_mfma_f32_16x16x32_bf16(al, bh, acc, 0, 0, 0);
      acc = __builtin_amdgcn_mfma_f32_16x16x32_bf16(ah, bl, acc, 0, 0, 0);
    }

    // Chebyshev combine (prev = slot sw) + state write (slot sw), thread-local RAW
    {
      const int n = n0w + lm;
#pragma unroll
      for (int j = 0; j < 4; ++j) {
        int m = lq * 4 + j;
        float d = acc[j];
        float nv;
        if (k > 1) nv = 2.f * d - (bfu2f(stH[sw][m][n]) + bfu2f(stL[sw][m][n]));
        else nv = d;
        unsigned short h = f2bf(nv);
        stH[sw][m][n] = h;
        stL[sw][m][n] = f2bf(nv - bfu2f(h));
      }
    }
    __syncthreads();  // state(sw) complete before CW transpose-read + next-step A reads

    // CW[k] write: coalesced u16x8 over v
    ushortT* CWk = cw + (size_t)k * cwN;
    if (t < 512) {
      int fo = t >> 8, v = t & 255;
      u16x8 h8;
#pragma unroll
      for (int j = 0; j < 8; ++j) h8[j] = stH[sw][fo * 8 + j][v];
      *(u16x8*)&CWk[((size_t)(cb + fo) * 8192 + (size_t)bi * 256 + v) * 8] = h8;
    }
  }
}

// ---------------- weight apply: 3-deep pipelined X via global_load_lds ----------
template <int Cc, int NSPL>
__global__ __launch_bounds__(256) void wapply_k(
    int NN, int Nf,
    const ushortT* __restrict__ WAh, const ushortT* __restrict__ WAl,
    const ushortT* __restrict__ cwBase, size_t cwN,
    float* __restrict__ OUT, size_t outStride) {
  constexpr int S = Cc / 2;
  constexpr int SPZ = S / NSPL;
  constexpr int ROWU = 129 * 8;
  __shared__ ushortT sX[3][4 * ROWU];
  const int z = blockIdx.z;
  OUT += (size_t)z * outStride;
  const int m0 = blockIdx.x * 64, n0 = blockIdx.y * 128;
  const int t = threadIdx.x, lane = t & 63, wid = t >> 6;
  const int wr = wid >> 1, wc = wid & 1;
  const int lm = lane & 15, lq = lane >> 4;

  const int fIdx = m0 + wr * 32 + lm;
  const int s0 = z * SPZ;

  f32x4 acc[2][4];
#pragma unroll
  for (int mi = 0; mi < 2; ++mi)
#pragma unroll
    for (int nj = 0; nj < 4; ++nj) acc[mi][nj] = (f32x4){0.f, 0.f, 0.f, 0.f};

  bf16x8 wh[2][2], wl[2][2];

#define STX(buf, s)                                                                \
  {                                                                                \
    const int buf_ = (Cc == 64) ? ((s) >> 1) : ((s) >> 2);                         \
    const int lo_ = (Cc == 64) ? (((s) & 1) * 4) : (((s) & 3) * 4);                \
    const ushortT* xb_ = cwBase + (size_t)buf_ * cwN;                              \
    _Pragma("unroll") for (int i = 0; i < 2; ++i) {                                \
      const int idx = t + i * 256;                                                 \
      const int octrow = idx >> 7, col = idx & 127;                                \
      const int chunk = idx >> 6;                                                  \
      const ushortT* src = xb_ + ((size_t)(lo_ + octrow) * NN + n0 + col) * 8;     \
      gload16(src, &sX[buf][octrow * ROWU + (chunk & 1) * 512]);                   \
    }                                                                              \
  }

#define LDW(set, s)                                                                \
  {                                                                                \
    _Pragma("unroll") for (int mi = 0; mi < 2; ++mi) {                             \
      size_t o = ((size_t)((s)*4 + lq) * Nf + fIdx + mi * 16) * 8;                 \
      wh[set][mi] = *(const bf16x8*)(WAh + o);                                     \
      wl[set][mi] = *(const bf16x8*)(WAl + o);                                     \
    }                                                                              \
  }

#define XMFMA(buf, set)                                                            \
  {                                                                                \
    bf16x8 xf[4];                                                                  \
    _Pragma("unroll") for (int nj = 0; nj < 4; ++nj)                               \
        xf[nj] = *(const bf16x8*)&sX[buf][lq * ROWU + (wc * 64 + lm + nj * 16) * 8];\
    _Pragma("unroll") for (int mi = 0; mi < 2; ++mi)                               \
        _Pragma("unroll") for (int nj = 0; nj < 4; ++nj) {                         \
      acc[mi][nj] = __builtin_amdgcn_mfma_f32_16x16x32_bf16(wh[set][mi], xf[nj],   \
                                                            acc[mi][nj], 0, 0, 0); \
      acc[mi][nj] = __builtin_amdgcn_mfma_f32_16x16x32_bf16(wl[set][mi], xf[nj],   \
                                                            acc[mi][nj], 0, 0, 0); \
    }                                                                              \
  }

  STX(0, s0);
  STX(1, s0 + 1);
  LDW(0, s0);
#pragma unroll
  for (int tt = 0; tt < SPZ; ++tt) {
    asm volatile("s_waitcnt vmcnt(6) lgkmcnt(0)" ::: "memory");
    __builtin_amdgcn_s_barrier();
    STX((tt + 2) % 3, s0 + (tt + 2) % SPZ);
    LDW((tt + 1) % 2, s0 + (tt + 1) % SPZ);
    __builtin_amdgcn_s_setprio(1);
    XMFMA(tt % 3, tt % 2);
    __builtin_amdgcn_s_setprio(0);
  }
#undef STX
#undef LDW
#undef XMFMA

#pragma unroll
  for (int mi = 0; mi < 2; ++mi)
#pragma unroll
    for (int nj = 0; nj < 4; ++nj)
#pragma unroll
      for (int j = 0; j < 4; ++j) {
        int gm = m0 + wr * 32 + mi * 16 + lq * 4 + j;
        int gn = n0 + wc * 64 + nj * 16 + lm;
        OUT[(size_t)gm * NN + gn] = acc[mi][nj][j];
      }
}

// ---------------- gc1 epilogue: sum 2 partials -> PG2 pair + CW2 slot0 --------
__global__ __launch_bounds__(256) void relu_pool1_k(const float* __restrict__ OUT1P,
                                                    const float* __restrict__ b2,
                                                    ushortT* __restrict__ PG2h,
                                                    ushortT* __restrict__ PG2l,
                                                    ushortT* __restrict__ CW0) {
  __shared__ float sval[128][9];
  const int b = blockIdx.x >> 5, vc = blockIdx.x & 31;
  const int t = threadIdx.x;
  const size_t PS = (size_t)128 * 32768;
  {
    int f = t & 127, h = t >> 7;
    float bb = b2[f];
    const float* src = &OUT1P[(size_t)f * 32768 + b * 1024 + vc * 32];
#pragma unroll
    for (int i = 0; i < 4; ++i) {
      int v2l = h * 4 + i;
      float4 r0 = *(const float4*)&src[v2l * 4];
      float4 r1 = *(const float4*)&src[PS + v2l * 4];
      float s0 = r0.x + r1.x, s1 = r0.y + r1.y, s2 = r0.z + r1.z, s3 = r0.w + r1.w;
      float m = fmaxf(fmaxf(s0, s1), fmaxf(s2, s3));
      sval[f][v2l] = fmaxf(m + bb, 0.f);
    }
  }
  __syncthreads();
  if (t < 128) {
    int f = t;
    u16x8 h8, l8;
#pragma unroll
    for (int j = 0; j < 8; ++j) {
      float v = sval[f][j];
      unsigned short h = f2bf(v);
      h8[j] = h; l8[j] = f2bf(v - bfu2f(h));
    }
    size_t base = ((size_t)vc * 4096 + b * 128 + f) * 8;
    *(u16x8*)&PG2h[base] = h8;
    *(u16x8*)&PG2l[base] = l8;
  } else {
    int q = t - 128;
    int co = q & 15, v2l = q >> 4;
    u16x8 h8;
#pragma unroll
    for (int j = 0; j < 8; ++j) h8[j] = f2bf(sval[co * 8 + j][v2l]);
    *(u16x8*)&CW0[((size_t)co * 8192 + b * 256 + vc * 8 + v2l) * 8] = h8;
  }
}

// ---------------- gc2 epilogue: sum 4 partials -> At[b][f*64+v3] --------------
__global__ __launch_bounds__(256) void relu_pool2_k(const float* __restrict__ OUT2P,
                                                    const float* __restrict__ b3,
                                                    float* __restrict__ At) {
  int n = blockIdx.x * 256 + threadIdx.x;  // 524288
  int v3 = n & 63, f = (n >> 6) & 255, b = n >> 14;
  const size_t PS = (size_t)256 * 8192;
  size_t base = ((size_t)f * 32 + b) * 256 + v3 * 4;
  float4 r0 = *(const float4*)&OUT2P[base];
  float4 r1 = *(const float4*)&OUT2P[PS + base];
  float4 r2 = *(const float4*)&OUT2P[2 * PS + base];
  float4 r3 = *(const float4*)&OUT2P[3 * PS + base];
  float s0 = r0.x + r1.x + r2.x + r3.x;
  float s1 = r0.y + r1.y + r2.y + r3.y;
  float s2 = r0.z + r1.z + r2.z + r3.z;
  float s3 = r0.w + r1.w + r2.w + r3.w;
  float m = fmaxf(fmaxf(s0, s1), fmaxf(s2, s3));
  At[(size_t)b * FC1_IN + f * 64 + v3] = fmaxf(m + b3[f], 0.f);
}

// ---------------- fc1: LDS-tiled split-K ----------------
__global__ __launch_bounds__(256) void fc1_part_k(const float* __restrict__ At,
                                                  const float* __restrict__ W1,
                                                  float* __restrict__ part) {
  __shared__ float sWt[64][68];
  __shared__ float sA[64][33];
  const int jt = blockIdx.x, ks = blockIdx.y;
  const int j0 = jt * 64, kb = ks * 512;
  const int t = threadIdx.x;
  const int b = t & 31, jg = t >> 5;
  float acc[8] = {};
  for (int k0 = kb; k0 < kb + 512; k0 += 64) {
    __syncthreads();
    {
      int jr = t >> 2, kq = t & 3;
      const float* wp = &W1[(size_t)(j0 + jr) * FC1_IN + k0 + kq * 16];
#pragma unroll
      for (int i = 0; i < 4; ++i) {
        float4 w4 = *(const float4*)(wp + 4 * i);
        int kk = kq * 16 + 4 * i;
        sWt[kk + 0][jr] = w4.x; sWt[kk + 1][jr] = w4.y;
        sWt[kk + 2][jr] = w4.z; sWt[kk + 3][jr] = w4.w;
      }
    }
    {
      int br = t >> 3, ko = t & 7;
      const float* ap = &At[(size_t)br * FC1_IN + k0 + ko * 8];
      float4 a0 = *(const float4*)ap;
      float4 a1 = *(const float4*)(ap + 4);
      int kk = ko * 8;
      sA[kk + 0][br] = a0.x; sA[kk + 1][br] = a0.y; sA[kk + 2][br] = a0.z; sA[kk + 3][br] = a0.w;
      sA[kk + 4][br] = a1.x; sA[kk + 5][br] = a1.y; sA[kk + 6][br] = a1.z; sA[kk + 7][br] = a1.w;
    }
    __syncthreads();
#pragma unroll 8
    for (int kk = 0; kk < 64; ++kk) {
      float a = sA[kk][b];
      float wv[8];
      *(float4*)wv = *(const float4*)&sWt[kk][jg * 8];
      *(float4*)(wv + 4) = *(const float4*)&sWt[kk][jg * 8 + 4];
#pragma unroll
      for (int i = 0; i < 8; ++i) acc[i] += wv[i] * a;
    }
  }
#pragma unroll
  for (int i = 0; i < 8; ++i)
    part[((size_t)ks * 512 + j0 + jg * 8 + i) * 32 + b] = acc[i];
}

__global__ __launch_bounds__(256) void fc1_combine_k(const float* __restrict__ part,
                                                     const float* __restrict__ b1,
                                                     float* __restrict__ h) {
  int n = blockIdx.x * 256 + threadIdx.x;  // 16384
  int b = n >> 9, j = n & 511;
  float s = b1[j];
#pragma unroll
  for (int ks = 0; ks < 32; ++ks) s += part[((size_t)ks * 512 + j) * 32 + b];
  h[n] = fmaxf(s, 0.f);
}

__global__ __launch_bounds__(64) void fc2_k(const float* __restrict__ h,
                                            const float* __restrict__ W2,
                                            const float* __restrict__ b2f,
                                            float* __restrict__ out) {
  int n = blockIdx.x * 64 + threadIdx.x;  // 320
  if (n >= 320) return;
  int b = n / 10, o = n % 10;
  float s = b2f[o];
  const float* hp = h + b * 512;
  const float* wp = W2 + o * 512;
  for (int j = 0; j < 512; ++j) s += hp[j] * wp[j];
  out[n] = s;
}

// ---------------- launch ----------------
extern "C" void kernel_launch(void* const* d_in, const int* in_sizes, int n_in,
                              void* d_out, int out_size, void* d_ws, size_t ws_size,
                              hipStream_t stream) {
  const float* x      = (const float*)d_in[0];
  const float* conv1w = (const float*)d_in[1];
  const float* conv1b = (const float*)d_in[2];
  const float* L1     = (const float*)d_in[3];
  const float* L2     = (const float*)d_in[4];
  const int*   ni     = (const int*)d_in[5];
  const int*   perm   = (const int*)d_in[6];
  const float* k2w    = (const float*)d_in[7];
  const float* k2b    = (const float*)d_in[8];
  const float* k3w    = (const float*)d_in[9];
  const float* k3b    = (const float*)d_in[10];
  const float* fc1w   = (const float*)d_in[11];
  const float* fc1b   = (const float*)d_in[12];
  const float* fc2w   = (const float*)d_in[13];
  const float* fc2b   = (const float*)d_in[14];
  float* out = (float*)d_out;

  char* ws = (char*)d_ws;
  const size_t MB = 1024 * 1024;
  // ---- phase A/B layout ----
  float*   P    = (float*)(ws + 0);                   // 8MB (dead after build_x0)
  ushortT* cw1  = (ushortT*)(ws + 8 * MB);            // 16 x 4MB = 64MB
  const size_t CW1N = 2u * 1024 * 1024;
  ushortT* pgAh = (ushortT*)(ws + 72 * MB);
  ushortT* pgAl = (ushortT*)(ws + 76 * MB);
  ushortT* pgBh = (ushortT*)(ws + 80 * MB);
  ushortT* pgBl = (ushortT*)(ws + 84 * MB);
  float*   OUT1P = (float*)(ws + 88 * MB);            // 2 x 16MB partials
  ushortT* L1h  = (ushortT*)(ws + 121 * MB);
  ushortT* L1l  = (ushortT*)(ws + 123 * MB);
  ushortT* WA1h = (ushortT*)(ws + 125 * MB);          // 256KB
  ushortT* WA1l = (ushortT*)(ws + 125 * MB + 262144);
  float*   BNB  = (float*)(ws + 126 * MB);            // ~5KB
  // ---- phase C/D layout ----
  ushortT* cw2  = (ushortT*)(ws + 0);                 // 16 x 2MB = 32MB
  const size_t CW2N = 1024u * 1024;
  ushortT* pg2Ah = (ushortT*)(ws + 32 * MB);
  ushortT* pg2Al = (ushortT*)(ws + 34 * MB);
  float*   OUT2P = (float*)(ws + 40 * MB);            // 4 x 8MB partials
  ushortT* L2h  = (ushortT*)(ws + 73 * MB);
  ushortT* L2l  = (ushortT*)(ws + 73 * MB + 131072);
  ushortT* WA2h = (ushortT*)(ws + 74 * MB);           // 1MB
  ushortT* WA2l = (ushortT*)(ws + 75 * MB);
  float*   At   = (float*)(ws + 76 * MB);             // 2MB
  float*   PART = (float*)(ws + 78 * MB);             // 2MB
  float*   H    = (float*)(ws + 80 * MB);             // 64KB

  // ---- phase A ----
  conv_pool_k<<<1024, 256, 0, stream>>>(x, conv1w, conv1b, P);
  bn_part_k<<<dim3(64, 8), 256, 0, stream>>>(P, BNB);
  bn_comb_k<<<1, 64, 0, stream>>>(BNB);
  lsplit_k<<<512, 256, 0, stream>>>(L1, L1h, L1l, 1024);
  wprep_k<<<512, 256, 0, stream>>>(k2w, WA1h, WA1l, 64, 128);
  build_x0_k<<<1024, 256, 0, stream>>>(P, BNB, ni, perm, pgAh, pgAl, cw1 + 0 * CW1N);

  // ---- phase B: gc1 chain (per-step dispatches) + K-split weight-apply ----
  cheb_step_k<0, 1, 1024><<<512, 256, 0, stream>>>(2048, 32, pgAh, pgAl, L1h, L1l,
                                                   pgBh, pgBl, cw1 + 1 * CW1N, 64, 6);
  for (int k = 2; k < 16; ++k) {
    ushortT *ah, *al, *oh, *ol;
    if (k & 1) { ah = pgAh; al = pgAl; oh = pgBh; ol = pgBl; }
    else       { ah = pgBh; al = pgBl; oh = pgAh; ol = pgAl; }
    cheb_step_k<1, 1, 1024><<<512, 256, 0, stream>>>(2048, 32, ah, al, L1h, L1l,
                                                     oh, ol, cw1 + (size_t)k * CW1N, 64, 6);
  }
  wapply_k<64, 2><<<dim3(2, 256, 2), 256, 0, stream>>>(32768, 128, WA1h, WA1l,
                                                       cw1, CW1N, OUT1P, (size_t)128 * 32768);

  // ---- phase C: gc2 (fused slab chain, ONE dispatch, 16 waves/block) ----
  relu_pool1_k<<<1024, 256, 0, stream>>>(OUT1P, k2b, pg2Ah, pg2Al, cw2 + 0 * CW2N);
  lsplit_k<<<32, 256, 0, stream>>>(L2, L2h, L2l, 256);
  wprep_k<<<2048, 256, 0, stream>>>(k3w, WA2h, WA2l, 128, 256);

  cheb2_slab_k<<<256, 1024, 0, stream>>>(pg2Ah, pg2Al, L2h, L2l, cw2, CW2N);

  wapply_k<128, 4><<<dim3(4, 64, 4), 256, 0, stream>>>(8192, 256, WA2h, WA2l,
                                                       cw2, CW2N, OUT2P, (size_t)256 * 8192);

  // ---- phase D: fc ----
  relu_pool2_k<<<2048, 256, 0, stream>>>(OUT2P, k3b, At);
  fc1_part_k<<<dim3(8, 32), 256, 0, stream>>>(At, fc1w, PART);
  fc1_combine_k<<<64, 256, 0, stream>>>(PART, fc1b, H);
  fc2_k<<<5, 64, 0, stream>>>(H, fc2w, fc2b, out);
}

// Round 14
// 494.797 us; speedup vs baseline: 1.3099x; 1.0279x over previous
//
#include <hip/hip_runtime.h>
#include <hip/hip_bf16.h>

// ---------------- problem constants ----------------
#define BB 32
#define C_IN 3
#define HW 64
#define V1 1024
#define CL2_F 128
#define V2 256
#define CL3_F 256
#define FC1_IN 16384

typedef unsigned short ushortT;
typedef __attribute__((ext_vector_type(8))) short bf16x8;
typedef __attribute__((ext_vector_type(8))) unsigned short u16x8;
typedef __attribute__((ext_vector_type(4))) float f32x4;

__device__ __forceinline__ float bfu2f(unsigned short u) {
  union { unsigned int i; float f; } x; x.i = ((unsigned)u) << 16; return x.f;
}
__device__ __forceinline__ unsigned short f2bf(float v) {
  union { float f; unsigned int i; } x; x.f = v;
  unsigned r = x.i + 0x7FFFu + ((x.i >> 16) & 1u);
  return (unsigned short)(r >> 16);
}
__device__ __forceinline__ void gload16(const ushortT* g, ushortT* l) {
  __builtin_amdgcn_global_load_lds((const __attribute__((address_space(1))) void*)g,
                                   (__attribute__((address_space(3))) void*)l, 16, 0, 0);
}

// ---------------- conv1 (5x5 pad2) + ReLU + 2x2 maxpool ----------------
__global__ __launch_bounds__(256) void conv_pool_k(const float* __restrict__ x,
                                                   const float* __restrict__ w,
                                                   const float* __restrict__ bias,
                                                   float* __restrict__ P) {
  __shared__ float xs[3][7][72];
  __shared__ float wl[64][76];
  const int b = blockIdx.x >> 5, ph = blockIdx.x & 31;
  const int t = threadIdx.x;
  for (int i = t; i < 64 * 75; i += 256) wl[i / 75][i % 75] = w[i];
  for (int i = t; i < 3 * 7 * 72; i += 256) {
    int col = i % 72, rr = (i / 72) % 7, ci = i / (72 * 7);
    int ih = 2 * ph - 2 + rr, iw = col - 2;
    float v = 0.f;
    if (ih >= 0 && ih < HW && iw >= 0 && iw < HW)
      v = x[((b * 3 + ci) * HW + ih) * HW + iw];
    xs[ci][rr][col] = v;
  }
  __syncthreads();
  const int co = t >> 2, pq = t & 3;
  float acc[8][2][2];
#pragma unroll
  for (int i = 0; i < 8; ++i)
#pragma unroll
    for (int a = 0; a < 2; ++a)
#pragma unroll
      for (int d = 0; d < 2; ++d) acc[i][a][d] = 0.f;
  for (int ci = 0; ci < 3; ++ci) {
#pragma unroll
    for (int kh = 0; kh < 5; ++kh) {
      float w5[5];
#pragma unroll
      for (int j = 0; j < 5; ++j) w5[j] = wl[co][ci * 25 + kh * 5 + j];
#pragma unroll
      for (int dy = 0; dy < 2; ++dy) {
        const int r = kh + dy;
        float in[20];
#pragma unroll
        for (int q4 = 0; q4 < 5; ++q4) {
          float4 v4 = *(const float4*)&xs[ci][r][16 * pq + q4 * 4];
          in[q4 * 4 + 0] = v4.x; in[q4 * 4 + 1] = v4.y;
          in[q4 * 4 + 2] = v4.z; in[q4 * 4 + 3] = v4.w;
        }
#pragma unroll
        for (int i = 0; i < 8; ++i)
#pragma unroll
          for (int dx = 0; dx < 2; ++dx)
#pragma unroll
            for (int kw = 0; kw < 5; ++kw)
              acc[i][dy][dx] += w5[kw] * in[2 * i + dx + kw];
      }
    }
  }
  const float bv = bias[co];
#pragma unroll
  for (int i = 0; i < 8; ++i) {
    float m = fmaxf(fmaxf(acc[i][0][0], acc[i][0][1]), fmaxf(acc[i][1][0], acc[i][1][1]));
    P[((size_t)(b * 64 + co) << 10) + (ph << 5) + pq * 8 + i] = fmaxf(m + bv, 0.f);
  }
}

// ---------------- BN stats (2-stage) ----------------
__global__ __launch_bounds__(256) void bn_part_k(const float* __restrict__ P,
                                                 float* __restrict__ buf) {
  int c = blockIdx.x, s = blockIdx.y;
  float s1 = 0.f, s2 = 0.f;
  for (int i = threadIdx.x; i < 4096; i += 256) {
    int b = s * 4 + (i >> 10), p = i & 1023;
    float v = P[((size_t)(b * 64 + c) << 10) + p];
    s1 += v; s2 += v * v;
  }
#pragma unroll
  for (int o = 32; o > 0; o >>= 1) { s1 += __shfl_down(s1, o); s2 += __shfl_down(s2, o); }
  __shared__ float sh[2][4];
  int wid = threadIdx.x >> 6;
  if ((threadIdx.x & 63) == 0) { sh[0][wid] = s1; sh[1][wid] = s2; }
  __syncthreads();
  if (threadIdx.x == 0) {
    buf[c * 8 + s] = sh[0][0] + sh[0][1] + sh[0][2] + sh[0][3];
    buf[512 + c * 8 + s] = sh[1][0] + sh[1][1] + sh[1][2] + sh[1][3];
  }
}
__global__ __launch_bounds__(64) void bn_comb_k(float* __restrict__ buf) {
  int c = threadIdx.x;
  float s1 = 0.f, s2 = 0.f;
#pragma unroll
  for (int s = 0; s < 8; ++s) { s1 += buf[c * 8 + s]; s2 += buf[512 + c * 8 + s]; }
  float mean = s1 / 32768.f;
  float var = s2 / 32768.f - mean * mean;
  buf[1024 + c] = mean;
  buf[1088 + c] = rsqrtf(var + 1e-5f);
}

// ---------------- gather + BN -> PG pair + CW(slot0, [c-oct][n][8]) ----------------
__global__ __launch_bounds__(256) void build_x0_k(const float* __restrict__ P,
                                                  const float* __restrict__ buf,
                                                  const int* __restrict__ ni,
                                                  const int* __restrict__ perm,
                                                  ushortT* __restrict__ PGh,
                                                  ushortT* __restrict__ PGl,
                                                  ushortT* __restrict__ CW0) {
  __shared__ float vals[64][33];
  __shared__ int qv[32];
  const int b = blockIdx.x >> 5, vc = blockIdx.x & 31;
  const int t = threadIdx.x;
  if (t < 32) {
    int pv = perm[vc * 32 + t];
    qv[t] = ni[2 * pv] * 32 + ni[2 * pv + 1];
  }
  __syncthreads();
  {
    int c = t & 63, vh = t >> 6;
    float mean = buf[1024 + c], rstd = buf[1088 + c];
    const float* pc = &P[((size_t)(b * 64 + c)) << 10];
#pragma unroll
    for (int j = 0; j < 8; ++j) {
      int vl = vh * 8 + j;
      vals[c][vl] = (pc[qv[vl]] - mean) * rstd;
    }
  }
  __syncthreads();
  {
    int c = t & 63, vo = t >> 6;
    u16x8 h8, l8;
#pragma unroll
    for (int j = 0; j < 8; ++j) {
      float f = vals[c][vo * 8 + j];
      unsigned short h = f2bf(f);
      h8[j] = h; l8[j] = f2bf(f - bfu2f(h));
    }
    size_t base = ((size_t)(vc * 4 + vo) * 2048 + b * 64 + c) * 8;
    *(u16x8*)&PGh[base] = h8;
    *(u16x8*)&PGl[base] = l8;
  }
  {
    int co = t & 7, vl = t >> 3;
    u16x8 h8;
#pragma unroll
    for (int j = 0; j < 8; ++j) h8[j] = f2bf(vals[co * 8 + j][vl]);
    *(u16x8*)&CW0[((size_t)co * 32768 + b * 1024 + vc * 32 + vl) * 8] = h8;
  }
}

// ---------------- L split fp32 -> bf16 hi/lo, octet-grouped LG layout ----------
__global__ __launch_bounds__(256) void lsplit_k(const float* __restrict__ L,
                                                ushortT* __restrict__ Lh,
                                                ushortT* __restrict__ Ll, int V) {
  int id = blockIdx.x * 256 + threadIdx.x;
  int n = id & (V - 1), koct = id / V * 8;
  u16x8 h8, l8;
#pragma unroll
  for (int j = 0; j < 8; ++j) {
    float v = L[(size_t)(koct + j) * V + n];
    unsigned short h = f2bf(v);
    h8[j] = h; l8[j] = f2bf(v - bfu2f(h));
  }
  size_t o = (size_t)id * 8;
  *(u16x8*)&Lh[o] = h8;
  *(u16x8*)&Ll[o] = l8;
}

// ---------------- W prep: octet-grouped WB[koct][f][8], k = kq*Cc + c ----------
__global__ __launch_bounds__(256) void wprep_k(const float* __restrict__ W,
                                               ushortT* __restrict__ WAh,
                                               ushortT* __restrict__ WAl, int Cc, int Nf) {
  int d = blockIdx.x * 256 + threadIdx.x;
  if (d >= Nf * 16 * Cc) return;
  int j = d & 7;
  int f = (d >> 3) % Nf;
  int koct = d / (8 * Nf);
  int k = koct * 8 + j;
  int kq = k / Cc, c = k % Cc;
  float v = W[(size_t)f * (Cc * 16) + c * 16 + kq];
  unsigned short h = f2bf(v);
  WAh[d] = h; WAl[d] = f2bf(v - bfu2f(h));
}

// ---------------- gc1 Chebyshev step: 3-deep pipeline, B-sets 3-deep ----------
// At phase tt's vmcnt(12) drain, STAGEA(tt) AND LOADB(tt) (both issued at tt-2)
// are guaranteed complete -> no in-phase register waits on B.
template <int MODE, int SWZ, int KD>
__global__ __launch_bounds__(256) void cheb_step_k(
    int Mld, int mt,
    const ushortT* __restrict__ Ah, const ushortT* __restrict__ Al,
    const ushortT* __restrict__ Lbh, const ushortT* __restrict__ Lbl,
    ushortT* __restrict__ Ph, ushortT* __restrict__ Pl,
    ushortT* __restrict__ CW, int CB, int CSH) {
  constexpr int NPH = KD / 64;
  __shared__ ushortT sA[3][2][8][520];
  int bx, by;
  if (SWZ) {
    const int id = blockIdx.x;
    const int xcd = id & 7, pos = id >> 3;
    bx = (xcd & 3) * 8 + (pos & 7);
    by = (xcd >> 2) * 8 + (pos >> 3);
  } else {
    bx = blockIdx.x % mt;
    by = blockIdx.x / mt;
  }
  const int m0 = bx * 64, n0 = by * 64;
  const int t = threadIdx.x, lane = t & 63;
  const int wr = (t >> 6) >> 1, wc = (t >> 6) & 1;
  const int lm = lane & 15, lq = lane >> 4;
  const size_t bCol = (size_t)(n0 + wc * 32 + lm);

  f32x4 acc[2][2];
#pragma unroll
  for (int mi = 0; mi < 2; ++mi)
#pragma unroll
    for (int nj = 0; nj < 2; ++nj) acc[mi][nj] = (f32x4){0.f, 0.f, 0.f, 0.f};

  bf16x8 Bh[3][2][2], Bl[3][2][2];  // 3-deep [set][ks][nj]

#define STAGEA(buf, slot)                                                          \
  {                                                                                \
    const int koct = (slot) * 8;                                                   \
    _Pragma("unroll") for (int i = 0; i < 2; ++i) {                                \
      const int sl = (t + i * 256) >> 6;                                           \
      const int ln = t & 63;                                                       \
      const size_t ga = ((size_t)(koct + sl) * Mld + m0 + ln) * 8;                 \
      gload16(Ah + ga, &sA[buf][0][sl][0]);                                        \
      gload16(Al + ga, &sA[buf][1][sl][0]);                                        \
    }                                                                              \
  }

#define LOADB(set, slot)                                                           \
  {                                                                                \
    _Pragma("unroll") for (int ks = 0; ks < 2; ++ks)                               \
        _Pragma("unroll") for (int nj = 0; nj < 2; ++nj) {                         \
      size_t o = ((size_t)((slot) * 8 + ks * 4 + lq) * KD + bCol + nj * 16) * 8;   \
      Bh[set][ks][nj] = *(const bf16x8*)(Lbh + o);                                 \
      Bl[set][ks][nj] = *(const bf16x8*)(Lbl + o);                                 \
    }                                                                              \
  }

#define DOMFMA(buf, set)                                                           \
  {                                                                                \
    _Pragma("unroll") for (int ks = 0; ks < 2; ++ks) {                             \
      const int so = ks * 4 + lq;                                                  \
      bf16x8 xah[2], xal[2];                                                       \
      _Pragma("unroll") for (int mi = 0; mi < 2; ++mi) {                           \
        const int r = (wr * 32 + mi * 16 + lm) * 8;                                \
        xah[mi] = *(const bf16x8*)&sA[buf][0][so][r];                              \
        xal[mi] = *(const bf16x8*)&sA[buf][1][so][r];                              \
      }                                                                            \
      _Pragma("unroll") for (int mi = 0; mi < 2; ++mi)                             \
          _Pragma("unroll") for (int nj = 0; nj < 2; ++nj) {                       \
        acc[mi][nj] = __builtin_amdgcn_mfma_f32_16x16x32_bf16(xah[mi], Bh[set][ks][nj], \
                                                              acc[mi][nj], 0, 0, 0);\
        acc[mi][nj] = __builtin_amdgcn_mfma_f32_16x16x32_bf16(xal[mi], Bh[set][ks][nj], \
                                                              acc[mi][nj], 0, 0, 0);\
        acc[mi][nj] = __builtin_amdgcn_mfma_f32_16x16x32_bf16(xah[mi], Bl[set][ks][nj], \
                                                              acc[mi][nj], 0, 0, 0);\
      }                                                                            \
    }                                                                              \
  }

  // prologue ordered so the OLDEST 12 VMEM ops are exactly {LOADB(0), STAGEA(0)}
  LOADB(0, 0);
  STAGEA(0, 0);
  STAGEA(1, 1);
  LOADB(1, 1 % NPH);
#pragma unroll
  for (int tt = 0; tt < NPH; ++tt) {
    asm volatile("s_waitcnt vmcnt(12) lgkmcnt(0)" ::: "memory");
    __builtin_amdgcn_s_barrier();
    STAGEA((tt + 2) % 3, (tt + 2) % NPH);
    LOADB((tt + 2) % 3, (tt + 2) % NPH);
    __builtin_amdgcn_s_setprio(1);
    DOMFMA(tt % 3, tt % 3);
    __builtin_amdgcn_s_setprio(0);
  }
  asm volatile("s_waitcnt vmcnt(0)" ::: "memory");
  __syncthreads();
#undef STAGEA
#undef LOADB
#undef DOMFMA

  float* fs = (float*)&sA[0][0][0][0];
#pragma unroll
  for (int mi = 0; mi < 2; ++mi)
#pragma unroll
    for (int nj = 0; nj < 2; ++nj)
#pragma unroll
      for (int j = 0; j < 4; ++j) {
        int gm_l = wr * 32 + mi * 16 + lq * 4 + j;
        int gn_l = wc * 32 + nj * 16 + lm;
        fs[gm_l * 65 + gn_l] = acc[mi][nj][j];
      }
  __syncthreads();

  const size_t noct0 = (size_t)(n0 >> 3);
#pragma unroll
  for (int r = 0; r < 2; ++r) {
    int id = t + r * 256;
    int gm_l = id >> 3, go = id & 7;
    size_t g = ((noct0 + go) * Mld + (m0 + gm_l)) * 8;
    float nv[8];
#pragma unroll
    for (int i = 0; i < 8; ++i) nv[i] = fs[gm_l * 65 + go * 8 + i];
    if (MODE == 1) {
      u16x8 ph = *(const u16x8*)&Ph[g];
      u16x8 pl = *(const u16x8*)&Pl[g];
#pragma unroll
      for (int i = 0; i < 8; ++i) nv[i] = 2.f * nv[i] - (bfu2f(ph[i]) + bfu2f(pl[i]));
    }
    u16x8 h8, l8;
#pragma unroll
    for (int i = 0; i < 8; ++i) {
      unsigned short h = f2bf(nv[i]);
      h8[i] = h; l8[i] = f2bf(nv[i] - bfu2f(h));
    }
    *(u16x8*)&Ph[g] = h8;
    *(u16x8*)&Pl[g] = l8;
    if (MODE == 1) {
#pragma unroll
      for (int i = 0; i < 8; ++i) fs[gm_l * 65 + go * 8 + i] = nv[i];
    }
  }
  __syncthreads();

  const int cBase = m0 & (CB - 1);
  const int bidx = m0 >> CSH;
  const size_t NNs = (size_t)KD << 5;
#pragma unroll
  for (int r = 0; r < 2; ++r) {
    int id = t + r * 256;
    int gn_l = id & 63, coI = id >> 6;
    u16x8 h8;
#pragma unroll
    for (int i = 0; i < 8; ++i) h8[i] = f2bf(fs[(coI * 8 + i) * 65 + gn_l]);
    size_t cbase = ((size_t)((cBase >> 3) + coI) * NNs + (size_t)bidx * KD + n0 + gn_l) * 8;
    *(u16x8*)&CW[cbase] = h8;
  }
}

// ---------------- gc2 FUSED chain: col-slab persistent, 16 waves ----------
__global__ __launch_bounds__(1024) void cheb2_slab_k(
    const ushortT* __restrict__ PG2h, const ushortT* __restrict__ PG2l,
    const ushortT* __restrict__ Lbh, const ushortT* __restrict__ Lbl,
    ushortT* __restrict__ cw, size_t cwN) {
  __shared__ ushortT stH[2][16][33 * 8];
  __shared__ ushortT stL[2][16][33 * 8];
  const int m0 = blockIdx.x * 16;
  const int t = threadIdx.x, lane = t & 63, w = t >> 6;
  const int lm = lane & 15, lq = lane >> 4;
  const int n0w = w * 16;

  if (t < 512) {
    int m = t >> 5, voct = t & 31;
    size_t g = ((size_t)voct * 4096 + m0 + m) * 8;
    *(u16x8*)&stH[0][m][voct * 8] = *(const u16x8*)&PG2h[g];
    *(u16x8*)&stL[0][m][voct * 8] = *(const u16x8*)&PG2l[g];
  }
  __syncthreads();

  const int cb = (m0 & 127) >> 3;
  const int bi = m0 >> 7;

#pragma unroll 1
  for (int k = 1; k < 16; ++k) {
    const int sa = (k + 1) & 1;
    const int sw = k & 1;
    f32x4 acc = (f32x4){0.f, 0.f, 0.f, 0.f};

#pragma unroll
    for (int ks = 0; ks < 8; ++ks) {
      const int koct = ks * 4 + lq;
      bf16x8 ah = *(const bf16x8*)&stH[sa][lm][koct * 8];
      bf16x8 al = *(const bf16x8*)&stL[sa][lm][koct * 8];
      size_t o = ((size_t)koct * 256 + n0w + lm) * 8;
      bf16x8 bh = *(const bf16x8*)(Lbh + o);
      bf16x8 bl = *(const bf16x8*)(Lbl + o);
      acc = __builtin_amdgcn_mfma_f32_16x16x32_bf16(ah, bh, acc, 0, 0, 0);
      acc = __builtin_amdgcn_mfma_f32_16x16x32_bf16(al, bh, acc, 0, 0, 0);
      acc = __builtin_amdgcn_mfma_f32_16x16x32_bf16(ah, bl, acc, 0, 0, 0);
    }

    {
      const int n = n0w + lm;
#pragma unroll
      for (int j = 0; j < 4; ++j) {
        int m = lq * 4 + j;
        float d = acc[j];
        float nv;
        if (k > 1) nv = 2.f * d - (bfu2f(stH[sw][m][n]) + bfu2f(stL[sw][m][n]));
        else nv = d;
        unsigned short h = f2bf(nv);
        stH[sw][m][n] = h;
        stL[sw][m][n] = f2bf(nv - bfu2f(h));
      }
    }
    __syncthreads();

    ushortT* CWk = cw + (size_t)k * cwN;
    if (t < 512) {
      int fo = t >> 8, v = t & 255;
      u16x8 h8;
#pragma unroll
      for (int j = 0; j < 8; ++j) h8[j] = stH[sw][fo * 8 + j][v];
      *(u16x8*)&CWk[((size_t)(cb + fo) * 8192 + (size_t)bi * 256 + v) * 8] = h8;
    }
  }
}

// ---------------- weight apply: 3-deep pipelined X + 3-deep W sets ----------
template <int Cc, int NSPL>
__global__ __launch_bounds__(256) void wapply_k(
    int NN, int Nf,
    const ushortT* __restrict__ WAh, const ushortT* __restrict__ WAl,
    const ushortT* __restrict__ cwBase, size_t cwN,
    float* __restrict__ OUT, size_t outStride) {
  constexpr int S = Cc / 2;
  constexpr int SPZ = S / NSPL;
  constexpr int ROWU = 129 * 8;
  __shared__ ushortT sX[3][4 * ROWU];
  const int z = blockIdx.z;
  OUT += (size_t)z * outStride;
  const int m0 = blockIdx.x * 64, n0 = blockIdx.y * 128;
  const int t = threadIdx.x, lane = t & 63, wid = t >> 6;
  const int wr = wid >> 1, wc = wid & 1;
  const int lm = lane & 15, lq = lane >> 4;

  const int fIdx = m0 + wr * 32 + lm;
  const int s0 = z * SPZ;

  f32x4 acc[2][4];
#pragma unroll
  for (int mi = 0; mi < 2; ++mi)
#pragma unroll
    for (int nj = 0; nj < 4; ++nj) acc[mi][nj] = (f32x4){0.f, 0.f, 0.f, 0.f};

  bf16x8 wh[3][2], wl[3][2];  // 3-deep [set][mi]

#define STX(buf, s)                                                                \
  {                                                                                \
    const int buf_ = (Cc == 64) ? ((s) >> 1) : ((s) >> 2);                         \
    const int lo_ = (Cc == 64) ? (((s) & 1) * 4) : (((s) & 3) * 4);                \
    const ushortT* xb_ = cwBase + (size_t)buf_ * cwN;                              \
    _Pragma("unroll") for (int i = 0; i < 2; ++i) {                                \
      const int idx = t + i * 256;                                                 \
      const int octrow = idx >> 7, col = idx & 127;                                \
      const int chunk = idx >> 6;                                                  \
      const ushortT* src = xb_ + ((size_t)(lo_ + octrow) * NN + n0 + col) * 8;     \
      gload16(src, &sX[buf][octrow * ROWU + (chunk & 1) * 512]);                   \
    }                                                                              \
  }

#define LDW(set, s)                                                                \
  {                                                                                \
    _Pragma("unroll") for (int mi = 0; mi < 2; ++mi) {                             \
      size_t o = ((size_t)((s)*4 + lq) * Nf + fIdx + mi * 16) * 8;                 \
      wh[set][mi] = *(const bf16x8*)(WAh + o);                                     \
      wl[set][mi] = *(const bf16x8*)(WAl + o);                                     \
    }                                                                              \
  }

#define XMFMA(buf, set)                                                            \
  {                                                                                \
    bf16x8 xf[4];                                                                  \
    _Pragma("unroll") for (int nj = 0; nj < 4; ++nj)                               \
        xf[nj] = *(const bf16x8*)&sX[buf][lq * ROWU + (wc * 64 + lm + nj * 16) * 8];\
    _Pragma("unroll") for (int mi = 0; mi < 2; ++mi)                               \
        _Pragma("unroll") for (int nj = 0; nj < 4; ++nj) {                         \
      acc[mi][nj] = __builtin_amdgcn_mfma_f32_16x16x32_bf16(wh[set][mi], xf[nj],   \
                                                            acc[mi][nj], 0, 0, 0); \
      acc[mi][nj] = __builtin_amdgcn_mfma_f32_16x16x32_bf16(wl[set][mi], xf[nj],   \
                                                            acc[mi][nj], 0, 0, 0); \
    }                                                                              \
  }

  // prologue ordered so the OLDEST 6 VMEM ops are exactly {LDW(0), STX(0)}
  LDW(0, s0);
  STX(0, s0);
  STX(1, s0 + 1);
  LDW(1, s0 + 1 % SPZ);
#pragma unroll
  for (int tt = 0; tt < SPZ; ++tt) {
    asm volatile("s_waitcnt vmcnt(6) lgkmcnt(0)" ::: "memory");
    __builtin_amdgcn_s_barrier();
    STX((tt + 2) % 3, s0 + (tt + 2) % SPZ);
    LDW((tt + 2) % 3, s0 + (tt + 2) % SPZ);
    __builtin_amdgcn_s_setprio(1);
    XMFMA(tt % 3, tt % 3);
    __builtin_amdgcn_s_setprio(0);
  }
#undef STX
#undef LDW
#undef XMFMA

#pragma unroll
  for (int mi = 0; mi < 2; ++mi)
#pragma unroll
    for (int nj = 0; nj < 4; ++nj)
#pragma unroll
      for (int j = 0; j < 4; ++j) {
        int gm = m0 + wr * 32 + mi * 16 + lq * 4 + j;
        int gn = n0 + wc * 64 + nj * 16 + lm;
        OUT[(size_t)gm * NN + gn] = acc[mi][nj][j];
      }
}

// ---------------- gc1 epilogue: sum 2 partials -> PG2 pair + CW2 slot0 --------
__global__ __launch_bounds__(256) void relu_pool1_k(const float* __restrict__ OUT1P,
                                                    const float* __restrict__ b2,
                                                    ushortT* __restrict__ PG2h,
                                                    ushortT* __restrict__ PG2l,
                                                    ushortT* __restrict__ CW0) {
  __shared__ float sval[128][9];
  const int b = blockIdx.x >> 5, vc = blockIdx.x & 31;
  const int t = threadIdx.x;
  const size_t PS = (size_t)128 * 32768;
  {
    int f = t & 127, h = t >> 7;
    float bb = b2[f];
    const float* src = &OUT1P[(size_t)f * 32768 + b * 1024 + vc * 32];
#pragma unroll
    for (int i = 0; i < 4; ++i) {
      int v2l = h * 4 + i;
      float4 r0 = *(const float4*)&src[v2l * 4];
      float4 r1 = *(const float4*)&src[PS + v2l * 4];
      float s0 = r0.x + r1.x, s1 = r0.y + r1.y, s2 = r0.z + r1.z, s3 = r0.w + r1.w;
      float m = fmaxf(fmaxf(s0, s1), fmaxf(s2, s3));
      sval[f][v2l] = fmaxf(m + bb, 0.f);
    }
  }
  __syncthreads();
  if (t < 128) {
    int f = t;
    u16x8 h8, l8;
#pragma unroll
    for (int j = 0; j < 8; ++j) {
      float v = sval[f][j];
      unsigned short h = f2bf(v);
      h8[j] = h; l8[j] = f2bf(v - bfu2f(h));
    }
    size_t base = ((size_t)vc * 4096 + b * 128 + f) * 8;
    *(u16x8*)&PG2h[base] = h8;
    *(u16x8*)&PG2l[base] = l8;
  } else {
    int q = t - 128;
    int co = q & 15, v2l = q >> 4;
    u16x8 h8;
#pragma unroll
    for (int j = 0; j < 8; ++j) h8[j] = f2bf(sval[co * 8 + j][v2l]);
    *(u16x8*)&CW0[((size_t)co * 8192 + b * 256 + vc * 8 + v2l) * 8] = h8;
  }
}

// ---------------- gc2 epilogue: sum 4 partials -> At[b][f*64+v3] --------------
__global__ __launch_bounds__(256) void relu_pool2_k(const float* __restrict__ OUT2P,
                                                    const float* __restrict__ b3,
                                                    float* __restrict__ At) {
  int n = blockIdx.x * 256 + threadIdx.x;  // 524288
  int v3 = n & 63, f = (n >> 6) & 255, b = n >> 14;
  const size_t PS = (size_t)256 * 8192;
  size_t base = ((size_t)f * 32 + b) * 256 + v3 * 4;
  float4 r0 = *(const float4*)&OUT2P[base];
  float4 r1 = *(const float4*)&OUT2P[PS + base];
  float4 r2 = *(const float4*)&OUT2P[2 * PS + base];
  float4 r3 = *(const float4*)&OUT2P[3 * PS + base];
  float s0 = r0.x + r1.x + r2.x + r3.x;
  float s1 = r0.y + r1.y + r2.y + r3.y;
  float s2 = r0.z + r1.z + r2.z + r3.z;
  float s3 = r0.w + r1.w + r2.w + r3.w;
  float m = fmaxf(fmaxf(s0, s1), fmaxf(s2, s3));
  At[(size_t)b * FC1_IN + f * 64 + v3] = fmaxf(m + b3[f], 0.f);
}

// ---------------- fc1: LDS-tiled split-K ----------------
__global__ __launch_bounds__(256) void fc1_part_k(const float* __restrict__ At,
                                                  const float* __restrict__ W1,
                                                  float* __restrict__ part) {
  __shared__ float sWt[64][68];
  __shared__ float sA[64][33];
  const int jt = blockIdx.x, ks = blockIdx.y;
  const int j0 = jt * 64, kb = ks * 512;
  const int t = threadIdx.x;
  const int b = t & 31, jg = t >> 5;
  float acc[8] = {};
  for (int k0 = kb; k0 < kb + 512; k0 += 64) {
    __syncthreads();
    {
      int jr = t >> 2, kq = t & 3;
      const float* wp = &W1[(size_t)(j0 + jr) * FC1_IN + k0 + kq * 16];
#pragma unroll
      for (int i = 0; i < 4; ++i) {
        float4 w4 = *(const float4*)(wp + 4 * i);
        int kk = kq * 16 + 4 * i;
        sWt[kk + 0][jr] = w4.x; sWt[kk + 1][jr] = w4.y;
        sWt[kk + 2][jr] = w4.z; sWt[kk + 3][jr] = w4.w;
      }
    }
    {
      int br = t >> 3, ko = t & 7;
      const float* ap = &At[(size_t)br * FC1_IN + k0 + ko * 8];
      float4 a0 = *(const float4*)ap;
      float4 a1 = *(const float4*)(ap + 4);
      int kk = ko * 8;
      sA[kk + 0][br] = a0.x; sA[kk + 1][br] = a0.y; sA[kk + 2][br] = a0.z; sA[kk + 3][br] = a0.w;
      sA[kk + 4][br] = a1.x; sA[kk + 5][br] = a1.y; sA[kk + 6][br] = a1.z; sA[kk + 7][br] = a1.w;
    }
    __syncthreads();
#pragma unroll 8
    for (int kk = 0; kk < 64; ++kk) {
      float a = sA[kk][b];
      float wv[8];
      *(float4*)wv = *(const float4*)&sWt[kk][jg * 8];
      *(float4*)(wv + 4) = *(const float4*)&sWt[kk][jg * 8 + 4];
#pragma unroll
      for (int i = 0; i < 8; ++i) acc[i] += wv[i] * a;
    }
  }
#pragma unroll
  for (int i = 0; i < 8; ++i)
    part[((size_t)ks * 512 + j0 + jg * 8 + i) * 32 + b] = acc[i];
}

__global__ __launch_bounds__(256) void fc1_combine_k(const float* __restrict__ part,
                                                     const float* __restrict__ b1,
                                                     float* __restrict__ h) {
  int n = blockIdx.x * 256 + threadIdx.x;  // 16384
  int b = n >> 9, j = n & 511;
  float s = b1[j];
#pragma unroll
  for (int ks = 0; ks < 32; ++ks) s += part[((size_t)ks * 512 + j) * 32 + b];
  h[n] = fmaxf(s, 0.f);
}

__global__ __launch_bounds__(64) void fc2_k(const float* __restrict__ h,
                                            const float* __restrict__ W2,
                                            const float* __restrict__ b2f,
                                            float* __restrict__ out) {
  int n = blockIdx.x * 64 + threadIdx.x;  // 320
  if (n >= 320) return;
  int b = n / 10, o = n % 10;
  float s = b2f[o];
  const float* hp = h + b * 512;
  const float* wp = W2 + o * 512;
  for (int j = 0; j < 512; ++j) s += hp[j] * wp[j];
  out[n] = s;
}

// ---------------- launch ----------------
extern "C" void kernel_launch(void* const* d_in, const int* in_sizes, int n_in,
                              void* d_out, int out_size, void* d_ws, size_t ws_size,
                              hipStream_t stream) {
  const float* x      = (const float*)d_in[0];
  const float* conv1w = (const float*)d_in[1];
  const float* conv1b = (const float*)d_in[2];
  const float* L1     = (const float*)d_in[3];
  const float* L2     = (const float*)d_in[4];
  const int*   ni     = (const int*)d_in[5];
  const int*   perm   = (const int*)d_in[6];
  const float* k2w    = (const float*)d_in[7];
  const float* k2b    = (const float*)d_in[8];
  const float* k3w    = (const float*)d_in[9];
  const float* k3b    = (const float*)d_in[10];
  const float* fc1w   = (const float*)d_in[11];
  const float* fc1b   = (const float*)d_in[12];
  const float* fc2w   = (const float*)d_in[13];
  const float* fc2b   = (const float*)d_in[14];
  float* out = (float*)d_out;

  char* ws = (char*)d_ws;
  const size_t MB = 1024 * 1024;
  // ---- phase A/B layout ----
  float*   P    = (float*)(ws + 0);                   // 8MB (dead after build_x0)
  ushortT* cw1  = (ushortT*)(ws + 8 * MB);            // 16 x 4MB = 64MB
  const size_t CW1N = 2u * 1024 * 1024;
  ushortT* pgAh = (ushortT*)(ws + 72 * MB);
  ushortT* pgAl = (ushortT*)(ws + 76 * MB);
  ushortT* pgBh = (ushortT*)(ws + 80 * MB);
  ushortT* pgBl = (ushortT*)(ws + 84 * MB);
  float*   OUT1P = (float*)(ws + 88 * MB);            // 2 x 16MB partials
  ushortT* L1h  = (ushortT*)(ws + 121 * MB);
  ushortT* L1l  = (ushortT*)(ws + 123 * MB);
  ushortT* WA1h = (ushortT*)(ws + 125 * MB);          // 256KB
  ushortT* WA1l = (ushortT*)(ws + 125 * MB + 262144);
  float*   BNB  = (float*)(ws + 126 * MB);            // ~5KB
  // ---- phase C/D layout ----
  ushortT* cw2  = (ushortT*)(ws + 0);                 // 16 x 2MB = 32MB
  const size_t CW2N = 1024u * 1024;
  ushortT* pg2Ah = (ushortT*)(ws + 32 * MB);
  ushortT* pg2Al = (ushortT*)(ws + 34 * MB);
  float*   OUT2P = (float*)(ws + 40 * MB);            // 4 x 8MB partials
  ushortT* L2h  = (ushortT*)(ws + 73 * MB);
  ushortT* L2l  = (ushortT*)(ws + 73 * MB + 131072);
  ushortT* WA2h = (ushortT*)(ws + 74 * MB);           // 1MB
  ushortT* WA2l = (ushortT*)(ws + 75 * MB);
  float*   At   = (float*)(ws + 76 * MB);             // 2MB
  float*   PART = (float*)(ws + 78 * MB);             // 2MB
  float*   H    = (float*)(ws + 80 * MB);             // 64KB

  // ---- phase A ----
  conv_pool_k<<<1024, 256, 0, stream>>>(x, conv1w, conv1b, P);
  bn_part_k<<<dim3(64, 8), 256, 0, stream>>>(P, BNB);
  bn_comb_k<<<1, 64, 0, stream>>>(BNB);
  lsplit_k<<<512, 256, 0, stream>>>(L1, L1h, L1l, 1024);
  wprep_k<<<512, 256, 0, stream>>>(k2w, WA1h, WA1l, 64, 128);
  build_x0_k<<<1024, 256, 0, stream>>>(P, BNB, ni, perm, pgAh, pgAl, cw1 + 0 * CW1N);

  // ---- phase B: gc1 chain (per-step dispatches) + K-split weight-apply ----
  cheb_step_k<0, 1, 1024><<<512, 256, 0, stream>>>(2048, 32, pgAh, pgAl, L1h, L1l,
                                                   pgBh, pgBl, cw1 + 1 * CW1N, 64, 6);
  for (int k = 2; k < 16; ++k) {
    ushortT *ah, *al, *oh, *ol;
    if (k & 1) { ah = pgAh; al = pgAl; oh = pgBh; ol = pgBl; }
    else       { ah = pgBh; al = pgBl; oh = pgAh; ol = pgAl; }
    cheb_step_k<1, 1, 1024><<<512, 256, 0, stream>>>(2048, 32, ah, al, L1h, L1l,
                                                     oh, ol, cw1 + (size_t)k * CW1N, 64, 6);
  }
  wapply_k<64, 2><<<dim3(2, 256, 2), 256, 0, stream>>>(32768, 128, WA1h, WA1l,
                                                       cw1, CW1N, OUT1P, (size_t)128 * 32768);

  // ---- phase C: gc2 (fused slab chain, ONE dispatch, 16 waves/block) ----
  relu_pool1_k<<<1024, 256, 0, stream>>>(OUT1P, k2b, pg2Ah, pg2Al, cw2 + 0 * CW2N);
  lsplit_k<<<32, 256, 0, stream>>>(L2, L2h, L2l, 256);
  wprep_k<<<2048, 256, 0, stream>>>(k3w, WA2h, WA2l, 128, 256);

  cheb2_slab_k<<<256, 1024, 0, stream>>>(pg2Ah, pg2Al, L2h, L2l, cw2, CW2N);

  wapply_k<128, 4><<<dim3(4, 64, 4), 256, 0, stream>>>(8192, 256, WA2h, WA2l,
                                                       cw2, CW2N, OUT2P, (size_t)256 * 8192);

  // ---- phase D: fc ----
  relu_pool2_k<<<2048, 256, 0, stream>>>(OUT2P, k3b, At);
  fc1_part_k<<<dim3(8, 32), 256, 0, stream>>>(At, fc1w, PART);
  fc1_combine_k<<<64, 256, 0, stream>>>(PART, fc1b, H);
  fc2_k<<<5, 64, 0, stream>>>(H, fc2w, fc2b, out);
}